// Round 12
// baseline (948.302 us; speedup 1.0000x reference)
//
#include <hip/hip_runtime.h>
#include <hip/hip_bf16.h>
#include <math.h>

// ---------------- constants ----------------
#define NB 4
#define NN 8192
#define ROWS (NB*NN)          // 32768
#define DIMC 512
#define HEADS 8
#define DT 128
#define DELTA 64
#define FF 2048
#define KCATP 640             // 576 padded to 640; pad cols zeroed on BOTH A and B sides every call

// ---------------- workspace layout (FLOAT units) ----------------
#define OFF_R0     ((size_t)0)          // catA [32768][640]bf16 -> hb [32768][512]bf16
#define OFF_CAW    ((size_t)8388608)    // caw f32 [4][512][512] (tail slack past hb; overlaps catA rows>=26214)
#define OFF_R1     ((size_t)10485760)   // kb(->kx in place) -> qb -> mid-chunk [32768][512]bf16
#define OFF_R2     ((size_t)18874368)   // vb -> cawT
#define OFF_CATWT  ((size_t)27262976)   // bf16 [512][640]
#define OFF_KVT    ((size_t)27426816)   // bf16 [1024][512]
#define OFF_QWT    ((size_t)27688960)   // bf16 [512][512]
#define OFF_F1WT   ((size_t)27820032)   // bf16 [2048][512]
#define OFF_F2WT   ((size_t)28344320)   // bf16 [512][2048]
#define OFF_LXWB   ((size_t)28868608)   // bf16 [512][512]
#define OFF_CW0T   ((size_t)28999680)   // bf16 [512][512]
#define OFF_Y      ((size_t)29130752)
#define OFF_BB     ((size_t)29131264)
#define OFF_PM     ((size_t)29133312)
#define OFF_PS     ((size_t)29264384)
#define OFF_M      ((size_t)29395456)
#define OFF_SINV   ((size_t)29397504)
#define OFF_CTX    ((size_t)29399552)
#define OFF_ZB     ((size_t)29530624)
// end = 29,531,136 floats = 118.1 MB

typedef __attribute__((ext_vector_type(8))) short bf16x8;
typedef __attribute__((ext_vector_type(4))) float f32x4;
typedef __attribute__((ext_vector_type(8))) unsigned short us8;

static __device__ __forceinline__ unsigned short f2b(float x) {
    __hip_bfloat16 h = __float2bfloat16(x);
    return __builtin_bit_cast(unsigned short, h);
}
static __device__ __forceinline__ float b2f(unsigned short u) {
    return __bfloat162float(__builtin_bit_cast(__hip_bfloat16, u));
}
static __device__ __forceinline__ float gelu_tanh(float x) {
    float t = tanhf(0.7978845608028654f * (x + 0.044715f * x * x * x));
    return 0.5f * x * (1.0f + t);
}

#define GLOAD16(g, l) __builtin_amdgcn_global_load_lds( \
    (const __attribute__((address_space(1))) void*)(g), \
    (__attribute__((address_space(3))) void*)(l), 16, 0, 0)

// ---------------- tiny prologue kernels ----------------
__global__ void y_kernel(const float* __restrict__ dt, const float* __restrict__ yyw,
                         const float* __restrict__ yyb, float* __restrict__ y_ws,
                         float* __restrict__ y_out) {
    int idx = blockIdx.x * 128 + threadIdx.x;   // 512
    int b = idx >> 7, j = idx & 127;
    float acc = yyb[j];
    for (int c = 0; c < DT; ++c) acc += dt[b * DT + c] * yyw[c * DT + j];
    y_ws[idx] = acc;
    y_out[idx] = acc;
}

__global__ void bb_kernel(const float* __restrict__ linxb, const float* __restrict__ catw,
                          const float* __restrict__ catb, const float* __restrict__ y,
                          float* __restrict__ bb) {
    int idx = blockIdx.x * 256 + threadIdx.x;   // 2048
    int b = idx >> 9, n = idx & 511;
    float acc = catb[n];
    for (int c = 0; c < DIMC; ++c) acc += linxb[c] * catw[(size_t)c * DIMC + n];
    const float* cw3 = catw + (size_t)(DIMC + DELTA) * DIMC;
    for (int j = 0; j < DT; ++j) acc += y[b * DT + j] * cw3[(size_t)j * DIMC + n];
    bb[idx] = acc;
}

// delta -> catA columns 512..575; ALSO zero pad cols 576..639 (replay safety)
__global__ __launch_bounds__(256) void delta_kernel(
    const float* __restrict__ pos, const float* __restrict__ mask,
    const float* __restrict__ w1, const float* __restrict__ b1,
    const float* __restrict__ w2, const float* __restrict__ b2,
    unsigned short* __restrict__ catA) {
    int lane = threadIdx.x & 63;
    size_t row = (size_t)blockIdx.x * 4 + (threadIdx.x >> 6);
    float mk = mask[row];
    float px = pos[row * 2] * mk, py = pos[row * 2 + 1] * mk;
    float nrm = sqrtf(px * px + py * py) + 1e-7f;
    float ux = px / nrm, uy = py / nrm;
    float t1 = fmaxf(ux * w1[lane] + uy * w1[64 + lane] + b1[lane], 0.0f);
    float acc = b2[lane];
    #pragma unroll
    for (int j = 0; j < 64; ++j) {
        float tv = __shfl(t1, j, 64);
        acc += tv * w2[j * 64 + lane];
    }
    catA[row * KCATP + DIMC + lane] = f2b(acc);
    catA[row * KCATP + 576 + lane] = 0;
}

// zero catWT pad cols 576..639 (B side)
__global__ void zcat_kernel(unsigned short* __restrict__ catWT) {
    int idx = blockIdx.x * 256 + threadIdx.x;   // 32768
    int n = idx >> 6, c = 576 + (idx & 63);
    catWT[(size_t)n * KCATP + c] = 0;
}

// f32 -> bf16 flat convert
__global__ void conv_bf16(const float* __restrict__ in, unsigned short* __restrict__ out, int n8) {
    int i = blockIdx.x * 256 + threadIdx.x;
    if (i >= n8) return;
    const float* p = in + (size_t)i * 8;
    us8 o;
    #pragma unroll
    for (int j = 0; j < 8; ++j) o[j] = f2b(p[j]);
    *(us8*)(out + (size_t)i * 8) = o;
}

// f32 [rows][512] -> bf16 out[row*ldo + c]
__global__ void conv_bf16_strided(const float* __restrict__ in, unsigned short* __restrict__ out,
                                  int ldo) {
    int i = blockIdx.x * 256 + threadIdx.x;
    int row = i >> 6, c8 = (i & 63) * 8;
    const float* p = in + (size_t)row * DIMC + c8;
    us8 o;
    #pragma unroll
    for (int j = 0; j < 8; ++j) o[j] = f2b(p[j]);
    *(us8*)(out + (size_t)row * ldo + c8) = o;
}

// f32 [R][C] -> bf16 out[c*ldo + r]
__global__ __launch_bounds__(256) void transconv(const float* __restrict__ in,
                                                 unsigned short* __restrict__ out,
                                                 int R, int C, int ldo) {
    __shared__ float tile[32][33];
    int bx = blockIdx.x * 32;
    int by = blockIdx.y * 32;
    int tx = threadIdx.x & 31, ty = threadIdx.x >> 5;
    #pragma unroll
    for (int i = 0; i < 4; ++i) {
        int r = ty + i * 8;
        tile[r][tx] = in[(size_t)(by + r) * C + bx + tx];
    }
    __syncthreads();
    #pragma unroll
    for (int i = 0; i < 4; ++i) {
        int r = ty + i * 8;
        out[(size_t)(bx + r) * ldo + by + tx] = f2b(tile[tx][r]);
    }
}

// LayerNorm: f32 in -> bf16 out
__global__ __launch_bounds__(128) void ln_kernel(
    const float* __restrict__ src, unsigned short* __restrict__ dst,
    const float* __restrict__ g, const float* __restrict__ bta) {
    size_t row = blockIdx.x;
    int t = threadIdx.x;
    const float* s = src + row * DIMC;
    float4 x = *(const float4*)(s + t * 4);
    float sum = x.x + x.y + x.z + x.w;
    float sq = x.x * x.x + x.y * x.y + x.z * x.z + x.w * x.w;
    #pragma unroll
    for (int o = 32; o; o >>= 1) { sum += __shfl_down(sum, o, 64); sq += __shfl_down(sq, o, 64); }
    __shared__ float sh[4];
    if ((t & 63) == 0) { sh[(t >> 6) * 2] = sum; sh[(t >> 6) * 2 + 1] = sq; }
    __syncthreads();
    sum = sh[0] + sh[2]; sq = sh[1] + sh[3];
    float mean = sum * (1.0f / DIMC);
    float var = sq * (1.0f / DIMC) - mean * mean;
    float rstd = rsqrtf(fmaxf(var, 0.0f) + 1e-5f);
    float4 gv = *(const float4*)(g + t * 4);
    float4 bv = *(const float4*)(bta + t * 4);
    ushort4 ov;
    ov.x = f2b((x.x - mean) * rstd * gv.x + bv.x);
    ov.y = f2b((x.y - mean) * rstd * gv.y + bv.y);
    ov.z = f2b((x.z - mean) * rstd * gv.z + bv.z);
    ov.w = f2b((x.w - mean) * rstd * gv.w + bv.w);
    *(ushort4*)(dst + row * DIMC + t * 4) = ov;
}

// ================= 256x256 8-phase counted-vmcnt MFMA GEMM =================
// C[M,N] = A[M,K] @ Bt[N,K], bf16. 512 threads = 8 waves (2M x 4N), 128KB dyn LDS.
// Schedule: per K-tile (BK=64, 2 k-subs of 32), 4 phases; counted vmcnt(4) only at
// k-sub boundaries (never 0 mid-loop). First-run-validated in round 5; replay
// failure then was the stale-pad bug (fixed), not this schedule.
// EPI: 1 gelu->bf16; 2 f32 +=; 3 f32 +extra[batch]; 4 bf16; 6 bf16 split store.
template <int EPI>
__global__ __launch_bounds__(512, 1) void gemm256(
    const unsigned short* __restrict__ A, int lda,
    const unsigned short* __restrict__ Bt, int ldb,
    const float* __restrict__ bias,
    const float* __restrict__ extra, int batch_rows,
    void* __restrict__ Cv, void* __restrict__ Cv2,
    int M, int N, int K,
    size_t b_stride, int rows_per_batch) {
    extern __shared__ char lds[];
    const int tid = threadIdx.x;
    const int lane = tid & 63, wv = tid >> 6;
    const int wr = wv >> 2, wc = wv & 3;
    const int lr = lane & 15, lch = lane >> 4;
    const int bm = blockIdx.y * 256, bn = blockIdx.x * 256;

    const unsigned short* Bb = Bt;
    if (rows_per_batch) Bb = Bt + (size_t)(bm / rows_per_batch) * b_stride;

    const int srow = tid >> 2;          // 0..127 (+128)
    const int schunk = tid & 3;

    auto stage_half = [&](int p, int matB, int ks, int kcol) {
        const unsigned short* src = matB ? Bb : A;
        const int ld = matB ? ldb : lda;
        const int rowbase = matB ? bn : bm;
        char* dst = lds + (size_t)p * 65536 + matB * 32768 + ks * 16384;
        #pragma unroll
        for (int i = 0; i < 2; ++i) {
            int row = srow + 128 * i;
            int gc = schunk ^ ((row >> 1) & 3);
            const char* g = (const char*)(src + (size_t)(rowbase + row) * ld + kcol) + gc * 16;
            GLOAD16(g, dst + (size_t)(tid + 512 * i) * 16);
        }
    };

    f32x4 acc[2][4][4] = {};
    const int nt = K >> 6;

    stage_half(0, 0, 0, 0);
    stage_half(0, 1, 0, 0);
    stage_half(0, 0, 1, 32);
    stage_half(0, 1, 1, 32);
    __builtin_amdgcn_sched_barrier(0);
    asm volatile("s_waitcnt vmcnt(4)" ::: "memory");   // A-ks0,B-ks0 landed
    __builtin_amdgcn_sched_barrier(0);
    __builtin_amdgcn_s_barrier();

    for (int t = 0; t < nt; ++t) {
        const int p = t & 1;
        const bool pf = (t + 1 < nt);
        const int kc = (t + 1) << 6;
        bf16x8 bfr[4], afr[4];
        #pragma unroll
        for (int ks = 0; ks < 2; ++ks) {
            #pragma unroll
            for (int mh = 0; mh < 2; ++mh) {
                const int ph = ks * 2 + mh;
                if (mh == 0) {
                    #pragma unroll
                    for (int n = 0; n < 4; ++n) {
                        int bc = wc * 64 + n * 16 + lr;
                        bfr[n] = *(const bf16x8*)(lds + (size_t)p * 65536 + 32768 + ks * 16384
                                 + bc * 64 + ((lch ^ ((bc >> 1) & 3)) << 4));
                    }
                }
                #pragma unroll
                for (int m = 0; m < 4; ++m) {
                    int ar = wr * 128 + mh * 64 + m * 16 + lr;
                    afr[m] = *(const bf16x8*)(lds + (size_t)p * 65536 + ks * 16384
                             + ar * 64 + ((lch ^ ((ar >> 1) & 3)) << 4));
                }
                if (pf) {
                    if (ph == 0)      stage_half(p ^ 1, 0, 0, kc);
                    else if (ph == 1) stage_half(p ^ 1, 1, 0, kc);
                    else if (ph == 2) stage_half(p ^ 1, 0, 1, kc + 32);
                    else              stage_half(p ^ 1, 1, 1, kc + 32);
                }
                __builtin_amdgcn_sched_barrier(0);
                __builtin_amdgcn_s_barrier();
                asm volatile("s_waitcnt lgkmcnt(0)" ::: "memory");
                __builtin_amdgcn_sched_barrier(0);
                __builtin_amdgcn_s_setprio(1);
                #pragma unroll
                for (int m = 0; m < 4; ++m)
                    #pragma unroll
                    for (int n = 0; n < 4; ++n)
                        acc[mh][m][n] = __builtin_amdgcn_mfma_f32_16x16x32_bf16(
                            afr[m], bfr[n], acc[mh][m][n], 0, 0, 0);
                __builtin_amdgcn_s_setprio(0);
                if (ph == 1) {
                    if (pf) asm volatile("s_waitcnt vmcnt(4)" ::: "memory");  // ks1(t) landed
                    else    asm volatile("s_waitcnt vmcnt(0)" ::: "memory");
                    __builtin_amdgcn_sched_barrier(0);
                } else if (ph == 3) {
                    if (pf) {
                        asm volatile("s_waitcnt vmcnt(4)" ::: "memory");      // ks0(t+1) landed
                        __builtin_amdgcn_sched_barrier(0);
                    }
                }
                __builtin_amdgcn_s_barrier();
            }
        }
    }

    const int g4 = lch * 4;
    #pragma unroll
    for (int mh = 0; mh < 2; ++mh)
        #pragma unroll
        for (int m = 0; m < 4; ++m)
            #pragma unroll
            for (int n = 0; n < 4; ++n) {
                int col = bn + wc * 64 + n * 16 + lr;
                #pragma unroll
                for (int r = 0; r < 4; ++r) {
                    int rr = bm + wr * 128 + mh * 64 + m * 16 + g4 + r;
                    float v = acc[mh][m][n][r];
                    if (EPI == 1) {
                        ((unsigned short*)Cv)[(size_t)rr * N + col] = f2b(gelu_tanh(v + bias[col]));
                    } else if (EPI == 2) {
                        ((float*)Cv)[(size_t)rr * N + col] += v + bias[col];
                    } else if (EPI == 3) {
                        ((float*)Cv)[(size_t)rr * N + col] = v + extra[(size_t)(rr / batch_rows) * N + col];
                    } else if (EPI == 4) {
                        ((unsigned short*)Cv)[(size_t)rr * N + col] = f2b(v);
                    } else if (EPI == 6) {
                        unsigned short* dst = (col >> 9) ? (unsigned short*)Cv2 : (unsigned short*)Cv;
                        dst[(size_t)rr * 512 + (col & 511)] = f2b(v);
                    }
                }
            }
}

// ---------------- legacy 128x128 MFMA GEMM (tiny wcomp only) ----------------
#define BM 128
#define BN 128
#define BK 64

template <int EPI>
__global__ __launch_bounds__(256) void gemm_mfma(
    const unsigned short* __restrict__ A, int lda,
    const unsigned short* __restrict__ Bt, int ldb,
    void* __restrict__ Cv, int M, int N, int K, int ldo) {
    __shared__ unsigned short As[2][BM * BK];
    __shared__ unsigned short Bs[2][BN * BK];
    int bm = blockIdx.y * BM, bn = blockIdx.x * BN;
    int tid = threadIdx.x;
    int lane = tid & 63, wv = tid >> 6;
    int wr = (wv >> 1) * 64, wc = (wv & 1) * 64;
    int g16 = (lane >> 4) << 4;
    int lr = lane & 15;
    int sw = (lr & 7) << 4;

    int srow = tid >> 3;
    int skb = (tid & 7) * 16;
    int sxor = skb ^ ((srow & 7) << 4);

    auto stage = [&](int buf, int k0) {
        #pragma unroll
        for (int i = 0; i < 4; ++i) {
            int row = srow + 32 * i;
            GLOAD16((const char*)(A + (size_t)(bm + row) * lda + k0) + sxor,
                    (char*)As[buf] + (size_t)(tid + 256 * i) * 16);
        }
        #pragma unroll
        for (int i = 0; i < 4; ++i) {
            int row = srow + 32 * i;
            GLOAD16((const char*)(Bt + (size_t)(bn + row) * ldb + k0) + sxor,
                    (char*)Bs[buf] + (size_t)(tid + 256 * i) * 16);
        }
    };

    f32x4 acc[4][4] = {};
    int nt = K / BK;
    stage(0, 0);
    __syncthreads();
    for (int t = 0; t < nt; ++t) {
        int cur = t & 1;
        if (t + 1 < nt) stage(cur ^ 1, (t + 1) * BK);
        const char* Ab = (const char*)As[cur];
        const char* Bp = (const char*)Bs[cur];
        #pragma unroll
        for (int s = 0; s < 2; ++s) {
            int koff = s * 64 + g16;
            bf16x8 af[4], bw[4];
            #pragma unroll
            for (int f = 0; f < 4; ++f) {
                int ar = wr + f * 16 + lr;
                af[f] = *(const bf16x8*)(Ab + ar * 128 + (koff ^ sw));
                int br = wc + f * 16 + lr;
                bw[f] = *(const bf16x8*)(Bp + br * 128 + (koff ^ sw));
            }
            #pragma unroll
            for (int f = 0; f < 4; ++f)
                #pragma unroll
                for (int j = 0; j < 4; ++j)
                    acc[f][j] = __builtin_amdgcn_mfma_f32_16x16x32_bf16(
                        af[f], bw[j], acc[f][j], 0, 0, 0);
        }
        __syncthreads();
    }

    int g4 = (lane >> 4) * 4;
    #pragma unroll
    for (int f = 0; f < 4; ++f) {
        #pragma unroll
        for (int j = 0; j < 4; ++j) {
            int col = bn + wc + j * 16 + lr;
            #pragma unroll
            for (int r = 0; r < 4; ++r) {
                int rr = bm + wr + f * 16 + g4 + r;
                float v = acc[f][j][r];
                if (EPI == 4) {
                    ((unsigned short*)Cv)[(size_t)rr * N + col] = f2b(v);
                } else if (EPI == 5) {
                    ((unsigned short*)Cv)[(size_t)col * ldo + rr] = f2b(v);
                }
            }
        }
    }
}

// ---------------- k column-softmax stats ----------------
__global__ __launch_bounds__(256) void ksm_stats1(
    const unsigned short* __restrict__ k, float* __restrict__ pm, float* __restrict__ ps) {
    int b = blockIdx.y, rb = blockIdx.x;
    const unsigned short* kp = k + ((size_t)b * NN + (size_t)rb * 128) * DIMC;
    int t = threadIdx.x;
    float m0 = -1e30f, s0 = 0.f, m1 = -1e30f, s1 = 0.f;
    for (int r = 0; r < 128; ++r) {
        float x0 = b2f(kp[(size_t)r * DIMC + t]);
        float x1 = b2f(kp[(size_t)r * DIMC + t + 256]);
        if (x0 > m0) { s0 = s0 * __expf(m0 - x0) + 1.f; m0 = x0; } else s0 += __expf(x0 - m0);
        if (x1 > m1) { s1 = s1 * __expf(m1 - x1) + 1.f; m1 = x1; } else s1 += __expf(x1 - m1);
    }
    size_t base = ((size_t)b * 64 + rb) * DIMC;
    pm[base + t] = m0; pm[base + t + 256] = m1;
    ps[base + t] = s0; ps[base + t + 256] = s1;
}

__global__ void ksm_stats2(const float* __restrict__ pm, const float* __restrict__ ps,
                           float* __restrict__ Mst, float* __restrict__ Sinv) {
    int idx = blockIdx.x * 256 + threadIdx.x;
    int b = idx >> 9, c = idx & 511;
    float m = -1e30f, s = 0.f;
    for (int rb = 0; rb < 64; ++rb) {
        float mm = pm[((size_t)b * 64 + rb) * DIMC + c];
        float ss = ps[((size_t)b * 64 + rb) * DIMC + c];
        if (mm > m) { s = s * __expf(m - mm) + ss; m = mm; } else s += ss * __expf(mm - m);
    }
    Mst[idx] = m;
    Sinv[idx] = 1.f / s;
}

// ---------------- kexp: kb <- bf16(exp(kb - Mst[col]) * Sinv[col]) in place ----------------
__global__ void kexp_kernel(unsigned short* __restrict__ kb,
                            const float* __restrict__ Mst, const float* __restrict__ Sinv) {
    int i = blockIdx.x * 256 + threadIdx.x;   // ROWS*64
    int row = i >> 6, c8 = (i & 63) * 8;
    int b = row >> 13;
    unsigned short* p = kb + (size_t)row * DIMC + c8;
    us8 v = *(const us8*)p;
    const float* mp = Mst + b * DIMC + c8;
    const float* sp = Sinv + b * DIMC + c8;
    #pragma unroll
    for (int j = 0; j < 8; ++j)
        v[j] = f2b(__expf(b2f(v[j]) - mp[j]) * sp[j]);
    *(us8*)p = v;
}

// ---------------- context = sum_n kx[n,d] * v[n,e]; register outer product ----------------
// grid (16, HEADS, NB), 256 thr = 4 waves over disjoint 128-row n-slices.
// Per lane: 8x8 microtile (d0=(lane&7)*8, e0=(lane>>3)*8), direct global reads
// (8-fold lane duplication served by cache broadcast). LDS only for cross-wave reduce.
__global__ __launch_bounds__(256) void context_kernel(
    const unsigned short* __restrict__ kx, const unsigned short* __restrict__ vb,
    float* __restrict__ ctx) {
    __shared__ float cbuf[4096];
    int b = blockIdx.z, hd = blockIdx.y, rb = blockIdx.x;
    int w = threadIdx.x >> 6, lane = threadIdx.x & 63;
    int d0 = (lane & 7) * 8, e0 = (lane >> 3) * 8;
    size_t row0 = (size_t)b * NN + (size_t)rb * 512 + (size_t)w * 128;
    const unsigned short* kp = kx + row0 * DIMC + hd * 64 + d0;
    const unsigned short* vp = vb + row0 * DIMC + hd * 64 + e0;
    float acc[8][8] = {};
    #pragma unroll 2
    for (int n = 0; n < 128; ++n) {
        us8 k8 = *(const us8*)(kp + (size_t)n * DIMC);
        us8 v8 = *(const us8*)(vp + (size_t)n * DIMC);
        float kf[8], vf[8];
        #pragma unroll
        for (int j = 0; j < 8; ++j) { kf[j] = b2f(k8[j]); vf[j] = b2f(v8[j]); }
        #pragma unroll
        for (int i = 0; i < 8; ++i)
            #pragma unroll
            for (int j = 0; j < 8; ++j)
                acc[i][j] = fmaf(kf[i], vf[j], acc[i][j]);
    }
    // cross-wave reduce in LDS (waves serialized; same lane->cell mapping per wave)
    for (int w2 = 0; w2 < 4; ++w2) {
        if (w == w2) {
            #pragma unroll
            for (int i = 0; i < 8; ++i)
                #pragma unroll
                for (int j = 0; j < 8; ++j) {
                    int idx = (d0 + i) * 64 + e0 + j;
                    cbuf[idx] = (w2 == 0) ? acc[i][j] : cbuf[idx] + acc[i][j];
                }
        }
        __syncthreads();
    }
    size_t cbase = (size_t)(b * HEADS + hd) * 4096;
    #pragma unroll
    for (int q = 0; q < 16; ++q) {
        int idx = threadIdx.x * 16 + q;
        atomicAdd(&ctx[cbase + idx], cbuf[idx]);
    }
}

// ---------------- q feature-softmax in place ----------------
__global__ __launch_bounds__(256) void qsm_kernel(unsigned short* __restrict__ qb) {
    int lane = threadIdx.x & 63;
    size_t row = (size_t)blockIdx.x * 4 + (threadIdx.x >> 6);
    size_t base = row * DIMC;
    #pragma unroll
    for (int h = 0; h < 8; ++h) {
        float v = b2f(qb[base + h * 64 + lane]);
        float m = v;
        #pragma unroll
        for (int o = 32; o; o >>= 1) m = fmaxf(m, __shfl_xor(m, o, 64));
        float e = __expf(v - m);
        float s = e;
        #pragma unroll
        for (int o = 32; o; o >>= 1) s += __shfl_xor(s, o, 64);
        qb[base + h * 64 + lane] = f2b(e * (0.125f / s));
    }
}

// ---------------- caw = ctx @ aow (per batch) ----------------
__global__ __launch_bounds__(256) void caw_kernel(const float* __restrict__ ctx,
                                                  const float* __restrict__ aow,
                                                  float* __restrict__ caw) {
    int nt = blockIdx.x, hd = blockIdx.y, b = blockIdx.z;
    int tid = threadIdx.x, tx = tid & 15, ty = tid >> 4;
    __shared__ float cs[64][68];
    __shared__ float aw[64][68];
    #pragma unroll
    for (int i = 0; i < 4; ++i) {
        int idx = tid + 256 * i;
        int r = idx >> 4, c4 = (idx & 15) * 4;
        *(float4*)&cs[r][c4] = *(const float4*)(ctx + ((size_t)(b * HEADS + hd) * 64 + r) * 64 + c4);
        *(float4*)&aw[r][c4] = *(const float4*)(aow + (size_t)(hd * 64 + r) * DIMC + nt * 64 + c4);
    }
    __syncthreads();
    float acc[4][4] = {};
    for (int e = 0; e < 64; ++e) {
        float av[4];
        #pragma unroll
        for (int i = 0; i < 4; ++i) av[i] = cs[ty * 4 + i][e];
        float4 b4 = *(const float4*)&aw[e][tx * 4];
        float bv[4] = {b4.x, b4.y, b4.z, b4.w};
        #pragma unroll
        for (int i = 0; i < 4; ++i)
            #pragma unroll
            for (int j = 0; j < 4; ++j)
                acc[i][j] = fmaf(av[i], bv[j], acc[i][j]);
    }
    #pragma unroll
    for (int i = 0; i < 4; ++i)
        #pragma unroll
        for (int j = 0; j < 4; ++j)
            caw[(size_t)b * DIMC * DIMC + (size_t)(hd * 64 + ty * 4 + i) * DIMC + nt * 64 + tx * 4 + j]
                = acc[i][j];
}

// ---------------- pos head ----------------
__global__ __launch_bounds__(256) void pos_kernel(
    const float* __restrict__ x, const float* __restrict__ w,
    const float* __restrict__ b2, float* __restrict__ out) {
    int lane = threadIdx.x & 63;
    size_t row = (size_t)blockIdx.x * 4 + (threadIdx.x >> 6);
    const float* xp = x + row * DIMC;
    float acc0 = 0.f, acc1 = 0.f;
    #pragma unroll
    for (int i = 0; i < 2; ++i) {
        float4 xv = *(const float4*)(xp + lane * 8 + i * 4);
        const float* wp = w + (size_t)(lane * 8 + i * 4) * 2;
        float4 w0 = *(const float4*)(wp);
        float4 w1 = *(const float4*)(wp + 4);
        acc0 += xv.x * w0.x + xv.y * w0.z + xv.z * w1.x + xv.w * w1.z;
        acc1 += xv.x * w0.y + xv.y * w0.w + xv.z * w1.y + xv.w * w1.w;
    }
    #pragma unroll
    for (int o = 32; o; o >>= 1) { acc0 += __shfl_down(acc0, o, 64); acc1 += __shfl_down(acc1, o, 64); }
    if (lane == 0) {
        out[row * 2] = acc0 + b2[0];
        out[row * 2 + 1] = acc1 + b2[1];
    }
}

// ---------------- launch ----------------
extern "C" void kernel_launch(void* const* d_in, const int* in_sizes, int n_in,
                              void* d_out, int out_size, void* d_ws, size_t ws_size,
                              hipStream_t stream) {
    (void)in_sizes; (void)n_in; (void)out_size; (void)ws_size;
    const float* nf  = (const float*)d_in[0];
    const float* dt  = (const float*)d_in[1];
    const float* pos = (const float*)d_in[2];
    const float* msk = (const float*)d_in[3];
    const float* yyw = (const float*)d_in[4];
    const float* yyb = (const float*)d_in[5];
    const float* p1w = (const float*)d_in[6];
    const float* p1b = (const float*)d_in[7];
    const float* p2w = (const float*)d_in[8];
    const float* p2b = (const float*)d_in[9];
    const float* lxw = (const float*)d_in[10];
    const float* lxb = (const float*)d_in[11];
    const float* cw  = (const float*)d_in[12];
    const float* cb  = (const float*)d_in[13];
    const float* l1g = (const float*)d_in[14];
    const float* l1b = (const float*)d_in[15];
    const float* qw  = (const float*)d_in[16];
    const float* kw  = (const float*)d_in[17];
    const float* vw  = (const float*)d_in[18];
    const float* aow = (const float*)d_in[19];
    const float* aob = (const float*)d_in[20];
    const float* l2g = (const float*)d_in[21];
    const float* l2b = (const float*)d_in[22];
    const float* f1w = (const float*)d_in[23];
    const float* f1b = (const float*)d_in[24];
    const float* f2w = (const float*)d_in[25];
    const float* f2b_ = (const float*)d_in[26];
    const float* hpw = (const float*)d_in[27];
    const float* hpb = (const float*)d_in[28];

    float* ws = (float*)d_ws;
    unsigned short* catA_u  = (unsigned short*)(ws + OFF_R0);
    unsigned short* hb_u    = (unsigned short*)(ws + OFF_R0);
    float*          caw     = ws + OFF_CAW;
    unsigned short* kb_u    = (unsigned short*)(ws + OFF_R1);
    unsigned short* qb_u    = (unsigned short*)(ws + OFF_R1);
    unsigned short* mid_u   = (unsigned short*)(ws + OFF_R1);
    unsigned short* vb_u    = (unsigned short*)(ws + OFF_R2);
    unsigned short* cawT_u  = (unsigned short*)(ws + OFF_R2);
    unsigned short* catWT_u = (unsigned short*)(ws + OFF_CATWT);
    unsigned short* kvT_u   = (unsigned short*)(ws + OFF_KVT);
    unsigned short* qwT_u   = (unsigned short*)(ws + OFF_QWT);
    unsigned short* f1wT_u  = (unsigned short*)(ws + OFF_F1WT);
    unsigned short* f2wT_u  = (unsigned short*)(ws + OFF_F2WT);
    unsigned short* lxwb_u  = (unsigned short*)(ws + OFF_LXWB);
    unsigned short* cw0T_u  = (unsigned short*)(ws + OFF_CW0T);
    float* yv   = ws + OFF_Y;
    float* bbf  = ws + OFF_BB;
    float* pm   = ws + OFF_PM;
    float* ps2  = ws + OFF_PS;
    float* Mst  = ws + OFF_M;
    float* Sinv = ws + OFF_SINV;
    float* ctx  = ws + OFF_CTX;
    float* zb   = ws + OFF_ZB;

    float* xout = (float*)d_out;
    float* yout = xout + (size_t)ROWS * DIMC;
    float* pout = yout + NB * DT;

    // allow 128KB dynamic LDS for gemm256 (capture-safe: ran fine through replay in r5/r6)
    hipFuncSetAttribute(reinterpret_cast<const void*>(&gemm256<1>),
                        hipFuncAttributeMaxDynamicSharedMemorySize, 131072);
    hipFuncSetAttribute(reinterpret_cast<const void*>(&gemm256<2>),
                        hipFuncAttributeMaxDynamicSharedMemorySize, 131072);
    hipFuncSetAttribute(reinterpret_cast<const void*>(&gemm256<3>),
                        hipFuncAttributeMaxDynamicSharedMemorySize, 131072);
    hipFuncSetAttribute(reinterpret_cast<const void*>(&gemm256<4>),
                        hipFuncAttributeMaxDynamicSharedMemorySize, 131072);
    hipFuncSetAttribute(reinterpret_cast<const void*>(&gemm256<6>),
                        hipFuncAttributeMaxDynamicSharedMemorySize, 131072);

    // prologue scalars + weight conversions
    y_kernel<<<4, 128, 0, stream>>>(dt, yyw, yyb, yv, yout);
    bb_kernel<<<8, 256, 0, stream>>>(lxb, cw, cb, yv, bbf);
    hipMemsetAsync(zb, 0, 512 * sizeof(float), stream);
    conv_bf16<<<128, 256, 0, stream>>>(lxw, lxwb_u, 32768);
    transconv<<<dim3(16, 16), 256, 0, stream>>>(cw, cw0T_u, 512, 512, 512);
    transconv<<<dim3(16, 2), 256, 0, stream>>>(cw + (size_t)DIMC * DIMC, catWT_u + 512, 64, 512, KCATP);
    zcat_kernel<<<128, 256, 0, stream>>>(catWT_u);
    transconv<<<dim3(16, 16), 256, 0, stream>>>(kw, kvT_u, 512, 512, 512);
    transconv<<<dim3(16, 16), 256, 0, stream>>>(vw, kvT_u + (size_t)512 * 512, 512, 512, 512);
    transconv<<<dim3(16, 16), 256, 0, stream>>>(qw, qwT_u, 512, 512, 512);
    transconv<<<dim3(64, 16), 256, 0, stream>>>(f1w, f1wT_u, 512, 2048, 512);
    transconv<<<dim3(16, 64), 256, 0, stream>>>(f2w, f2wT_u, 2048, 512, 2048);
    conv_bf16_strided<<<8192, 256, 0, stream>>>(nf, catA_u, KCATP);
    delta_kernel<<<8192, 256, 0, stream>>>(pos, msk, p1w, p1b, p2w, p2b, catA_u);

    // catWT cols 0..511 = (lxw @ cw0)^T
    gemm_mfma<5><<<dim3(4, 4), 256, 0, stream>>>(
        lxwb_u, 512, cw0T_u, 512, catWT_u, 512, 512, 512, KCATP);

    // cat = catA @ catWT^T + bb[batch] -> xout (f32)
    gemm256<3><<<dim3(2, 128), 512, 131072, stream>>>(
        catA_u, KCATP, catWT_u, KCATP, nullptr, bbf, NN,
        xout, nullptr, ROWS, 512, KCATP, 0, 0);

    // LN1: xout -> hb
    ln_kernel<<<ROWS, 128, 0, stream>>>(xout, hb_u, l1g, l1b);

    // fused k+v projection (N=1024, split store)
    gemm256<6><<<dim3(4, 128), 512, 131072, stream>>>(
        hb_u, 512, kvT_u, 512, nullptr, nullptr, 0,
        kb_u, vb_u, ROWS, 1024, 512, 0, 0);

    // k sequence-softmax stats, then exp in place (kb -> kx)
    ksm_stats1<<<dim3(64, 4), 256, 0, stream>>>(kb_u, pm, ps2);
    ksm_stats2<<<8, 256, 0, stream>>>(pm, ps2, Mst, Sinv);
    kexp_kernel<<<8192, 256, 0, stream>>>(kb_u, Mst, Sinv);

    // context (consumes kx, vb)
    hipMemsetAsync(ctx, 0, (size_t)NB * HEADS * 64 * 64 * sizeof(float), stream);
    context_kernel<<<dim3(16, HEADS, NB), 256, 0, stream>>>(kb_u, vb_u, ctx);

    // q projection into R1 (kx dead), softmax in place
    gemm256<4><<<dim3(2, 128), 512, 131072, stream>>>(
        hb_u, 512, qwT_u, 512, nullptr, nullptr, 0,
        qb_u, nullptr, ROWS, 512, 512, 0, 0);
    qsm_kernel<<<8192, 256, 0, stream>>>(qb_u);

    // compose ctx with attn_out_w per batch; transpose into R2 (vb dead)
    caw_kernel<<<dim3(8, 8, 4), 256, 0, stream>>>(ctx, aow, caw);
    for (int b = 0; b < NB; ++b)
        transconv<<<dim3(16, 16), 256, 0, stream>>>(caw + (size_t)b * 262144,
                                                    cawT_u + (size_t)b * 262144, 512, 512, 512);

    // x += qsm @ caw[b]^T + aob
    gemm256<2><<<dim3(2, 128), 512, 131072, stream>>>(
        qb_u, 512, cawT_u, 512, aob, nullptr, 0,
        xout, nullptr, ROWS, 512, 512, 262144, NN);

    // FF block
    ln_kernel<<<ROWS, 128, 0, stream>>>(xout, hb_u, l2g, l2b);
    for (int cg = 0; cg < 4; ++cg) {
        gemm256<1><<<dim3(2, 128), 512, 131072, stream>>>(
            hb_u, 512, f1wT_u + (size_t)cg * 512 * 512, 512, f1b + cg * 512, nullptr, 0,
            mid_u, nullptr, ROWS, 512, 512, 0, 0);
        gemm256<2><<<dim3(2, 128), 512, 131072, stream>>>(
            mid_u, 512, f2wT_u + (size_t)cg * 512, 2048, (cg == 0 ? f2b_ : zb), nullptr, 0,
            xout, nullptr, ROWS, 512, 512, 0, 0);
    }

    pos_kernel<<<8192, 256, 0, stream>>>(xout, hpw, hpb, pout);
}

// Round 13
// 788.417 us; speedup vs baseline: 1.2028x; 1.2028x over previous
//
#include <hip/hip_runtime.h>
#include <hip/hip_bf16.h>
#include <math.h>

// ---------------- constants ----------------
#define NB 4
#define NN 8192
#define ROWS (NB*NN)          // 32768
#define DIMC 512
#define HEADS 8
#define DT 128
#define DELTA 64
#define FF 2048
#define KCATP 640             // 576 padded to 640; pad cols zeroed on BOTH A and B sides every call

// ---------------- workspace layout (FLOAT units) ----------------
#define OFF_R0     ((size_t)0)          // catA [32768][640]bf16 -> hb [32768][512]bf16
#define OFF_CAW    ((size_t)8388608)    // caw f32 [4][512][512] (tail slack past hb)
#define OFF_R1     ((size_t)10485760)   // kb -> qb -> mid(lo)   [R1:8,388,608 f]
#define OFF_R2     ((size_t)18874368)   // vb -> cawT -> mid(hi) [R2:8,388,608 f]
                                        // mid = [16384][2048]bf16 = 16,777,216 f spans R1+R2 exactly
#define OFF_CATWT  ((size_t)27262976)   // bf16 [512][640]
#define OFF_KVT    ((size_t)27426816)   // bf16 [1024][512]
#define OFF_QWT    ((size_t)27688960)   // bf16 [512][512]
#define OFF_F1WT   ((size_t)27820032)   // bf16 [2048][512]
#define OFF_F2WT   ((size_t)28344320)   // bf16 [512][2048]
#define OFF_LXWB   ((size_t)28868608)   // bf16 [512][512]
#define OFF_CW0T   ((size_t)28999680)   // bf16 [512][512]
#define OFF_Y      ((size_t)29130752)
#define OFF_BB     ((size_t)29131264)
#define OFF_PM     ((size_t)29133312)
#define OFF_PS     ((size_t)29264384)
#define OFF_M      ((size_t)29395456)
#define OFF_SINV   ((size_t)29397504)
#define OFF_CTX    ((size_t)29399552)
// end = 29,530,624 floats = 118.1 MB

typedef __attribute__((ext_vector_type(8))) short bf16x8;
typedef __attribute__((ext_vector_type(4))) float f32x4;
typedef __attribute__((ext_vector_type(8))) unsigned short us8;

static __device__ __forceinline__ unsigned short f2b(float x) {
    __hip_bfloat16 h = __float2bfloat16(x);
    return __builtin_bit_cast(unsigned short, h);
}
static __device__ __forceinline__ float b2f(unsigned short u) {
    return __bfloat162float(__builtin_bit_cast(__hip_bfloat16, u));
}
static __device__ __forceinline__ float gelu_tanh(float x) {
    float t = tanhf(0.7978845608028654f * (x + 0.044715f * x * x * x));
    return 0.5f * x * (1.0f + t);
}

#define GLOAD16(g, l) __builtin_amdgcn_global_load_lds( \
    (const __attribute__((address_space(1))) void*)(g), \
    (__attribute__((address_space(3))) void*)(l), 16, 0, 0)

// ---------------- tiny prologue kernels ----------------
__global__ void y_kernel(const float* __restrict__ dt, const float* __restrict__ yyw,
                         const float* __restrict__ yyb, float* __restrict__ y_ws,
                         float* __restrict__ y_out) {
    int idx = blockIdx.x * 128 + threadIdx.x;   // 512
    int b = idx >> 7, j = idx & 127;
    float acc = yyb[j];
    for (int c = 0; c < DT; ++c) acc += dt[b * DT + c] * yyw[c * DT + j];
    y_ws[idx] = acc;
    y_out[idx] = acc;
}

__global__ void bb_kernel(const float* __restrict__ linxb, const float* __restrict__ catw,
                          const float* __restrict__ catb, const float* __restrict__ y,
                          float* __restrict__ bb) {
    int idx = blockIdx.x * 256 + threadIdx.x;   // 2048
    int b = idx >> 9, n = idx & 511;
    float acc = catb[n];
    for (int c = 0; c < DIMC; ++c) acc += linxb[c] * catw[(size_t)c * DIMC + n];
    const float* cw3 = catw + (size_t)(DIMC + DELTA) * DIMC;
    for (int j = 0; j < DT; ++j) acc += y[b * DT + j] * cw3[(size_t)j * DIMC + n];
    bb[idx] = acc;
}

// delta -> catA columns 512..575; ALSO zero pad cols 576..639 (replay safety)
__global__ __launch_bounds__(256) void delta_kernel(
    const float* __restrict__ pos, const float* __restrict__ mask,
    const float* __restrict__ w1, const float* __restrict__ b1,
    const float* __restrict__ w2, const float* __restrict__ b2,
    unsigned short* __restrict__ catA) {
    int lane = threadIdx.x & 63;
    size_t row = (size_t)blockIdx.x * 4 + (threadIdx.x >> 6);
    float mk = mask[row];
    float px = pos[row * 2] * mk, py = pos[row * 2 + 1] * mk;
    float nrm = sqrtf(px * px + py * py) + 1e-7f;
    float ux = px / nrm, uy = py / nrm;
    float t1 = fmaxf(ux * w1[lane] + uy * w1[64 + lane] + b1[lane], 0.0f);
    float acc = b2[lane];
    #pragma unroll
    for (int j = 0; j < 64; ++j) {
        float tv = __shfl(t1, j, 64);
        acc += tv * w2[j * 64 + lane];
    }
    catA[row * KCATP + DIMC + lane] = f2b(acc);
    catA[row * KCATP + 576 + lane] = 0;
}

// zero catWT pad cols 576..639 (B side)
__global__ void zcat_kernel(unsigned short* __restrict__ catWT) {
    int idx = blockIdx.x * 256 + threadIdx.x;   // 32768
    int n = idx >> 6, c = 576 + (idx & 63);
    catWT[(size_t)n * KCATP + c] = 0;
}

// f32 -> bf16 flat convert
__global__ void conv_bf16(const float* __restrict__ in, unsigned short* __restrict__ out, int n8) {
    int i = blockIdx.x * 256 + threadIdx.x;
    if (i >= n8) return;
    const float* p = in + (size_t)i * 8;
    us8 o;
    #pragma unroll
    for (int j = 0; j < 8; ++j) o[j] = f2b(p[j]);
    *(us8*)(out + (size_t)i * 8) = o;
}

// f32 [rows][512] -> bf16 out[row*ldo + c]
__global__ void conv_bf16_strided(const float* __restrict__ in, unsigned short* __restrict__ out,
                                  int ldo) {
    int i = blockIdx.x * 256 + threadIdx.x;
    int row = i >> 6, c8 = (i & 63) * 8;
    const float* p = in + (size_t)row * DIMC + c8;
    us8 o;
    #pragma unroll
    for (int j = 0; j < 8; ++j) o[j] = f2b(p[j]);
    *(us8*)(out + (size_t)row * ldo + c8) = o;
}

// f32 [R][C] -> bf16 out[c*ldo + r]
__global__ __launch_bounds__(256) void transconv(const float* __restrict__ in,
                                                 unsigned short* __restrict__ out,
                                                 int R, int C, int ldo) {
    __shared__ float tile[32][33];
    int bx = blockIdx.x * 32;
    int by = blockIdx.y * 32;
    int tx = threadIdx.x & 31, ty = threadIdx.x >> 5;
    #pragma unroll
    for (int i = 0; i < 4; ++i) {
        int r = ty + i * 8;
        tile[r][tx] = in[(size_t)(by + r) * C + bx + tx];
    }
    __syncthreads();
    #pragma unroll
    for (int i = 0; i < 4; ++i) {
        int r = ty + i * 8;
        out[(size_t)(bx + r) * ldo + by + tx] = f2b(tile[tx][r]);
    }
}

// LayerNorm: f32 in -> bf16 out
__global__ __launch_bounds__(128) void ln_kernel(
    const float* __restrict__ src, unsigned short* __restrict__ dst,
    const float* __restrict__ g, const float* __restrict__ bta) {
    size_t row = blockIdx.x;
    int t = threadIdx.x;
    const float* s = src + row * DIMC;
    float4 x = *(const float4*)(s + t * 4);
    float sum = x.x + x.y + x.z + x.w;
    float sq = x.x * x.x + x.y * x.y + x.z * x.z + x.w * x.w;
    #pragma unroll
    for (int o = 32; o; o >>= 1) { sum += __shfl_down(sum, o, 64); sq += __shfl_down(sq, o, 64); }
    __shared__ float sh[4];
    if ((t & 63) == 0) { sh[(t >> 6) * 2] = sum; sh[(t >> 6) * 2 + 1] = sq; }
    __syncthreads();
    sum = sh[0] + sh[2]; sq = sh[1] + sh[3];
    float mean = sum * (1.0f / DIMC);
    float var = sq * (1.0f / DIMC) - mean * mean;
    float rstd = rsqrtf(fmaxf(var, 0.0f) + 1e-5f);
    float4 gv = *(const float4*)(g + t * 4);
    float4 bv = *(const float4*)(bta + t * 4);
    ushort4 ov;
    ov.x = f2b((x.x - mean) * rstd * gv.x + bv.x);
    ov.y = f2b((x.y - mean) * rstd * gv.y + bv.y);
    ov.z = f2b((x.z - mean) * rstd * gv.z + bv.z);
    ov.w = f2b((x.w - mean) * rstd * gv.w + bv.w);
    *(ushort4*)(dst + row * DIMC + t * 4) = ov;
}

// ================= 256x256 8-phase counted-vmcnt MFMA GEMM =================
// C[M,N] = A[M,K] @ Bt[N,K], bf16. 512 threads = 8 waves (2M x 4N), 128KB dyn LDS.
// Counted vmcnt(4) only at k-sub boundaries (never 0 mid-loop). Replay-validated r11/r12.
// EPI: 1 gelu->bf16; 2 f32 +=; 3 f32 +extra[batch]; 4 bf16; 6 bf16 split store.
template <int EPI>
__global__ __launch_bounds__(512, 1) void gemm256(
    const unsigned short* __restrict__ A, int lda,
    const unsigned short* __restrict__ Bt, int ldb,
    const float* __restrict__ bias,
    const float* __restrict__ extra, int batch_rows,
    void* __restrict__ Cv, void* __restrict__ Cv2,
    int M, int N, int K,
    size_t b_stride, int rows_per_batch) {
    extern __shared__ char lds[];
    const int tid = threadIdx.x;
    const int lane = tid & 63, wv = tid >> 6;
    const int wr = wv >> 2, wc = wv & 3;
    const int lr = lane & 15, lch = lane >> 4;
    const int bm = blockIdx.y * 256, bn = blockIdx.x * 256;

    const unsigned short* Bb = Bt;
    if (rows_per_batch) Bb = Bt + (size_t)(bm / rows_per_batch) * b_stride;

    const int srow = tid >> 2;          // 0..127 (+128)
    const int schunk = tid & 3;

    auto stage_half = [&](int p, int matB, int ks, int kcol) {
        const unsigned short* src = matB ? Bb : A;
        const int ld = matB ? ldb : lda;
        const int rowbase = matB ? bn : bm;
        char* dst = lds + (size_t)p * 65536 + matB * 32768 + ks * 16384;
        #pragma unroll
        for (int i = 0; i < 2; ++i) {
            int row = srow + 128 * i;
            int gc = schunk ^ ((row >> 1) & 3);
            const char* g = (const char*)(src + (size_t)(rowbase + row) * ld + kcol) + gc * 16;
            GLOAD16(g, dst + (size_t)(tid + 512 * i) * 16);
        }
    };

    f32x4 acc[2][4][4] = {};
    const int nt = K >> 6;

    stage_half(0, 0, 0, 0);
    stage_half(0, 1, 0, 0);
    stage_half(0, 0, 1, 32);
    stage_half(0, 1, 1, 32);
    __builtin_amdgcn_sched_barrier(0);
    asm volatile("s_waitcnt vmcnt(4)" ::: "memory");   // A-ks0,B-ks0 landed
    __builtin_amdgcn_sched_barrier(0);
    __builtin_amdgcn_s_barrier();

    for (int t = 0; t < nt; ++t) {
        const int p = t & 1;
        const bool pf = (t + 1 < nt);
        const int kc = (t + 1) << 6;
        bf16x8 bfr[4], afr[4];
        #pragma unroll
        for (int ks = 0; ks < 2; ++ks) {
            #pragma unroll
            for (int mh = 0; mh < 2; ++mh) {
                const int ph = ks * 2 + mh;
                if (mh == 0) {
                    #pragma unroll
                    for (int n = 0; n < 4; ++n) {
                        int bc = wc * 64 + n * 16 + lr;
                        bfr[n] = *(const bf16x8*)(lds + (size_t)p * 65536 + 32768 + ks * 16384
                                 + bc * 64 + ((lch ^ ((bc >> 1) & 3)) << 4));
                    }
                }
                #pragma unroll
                for (int m = 0; m < 4; ++m) {
                    int ar = wr * 128 + mh * 64 + m * 16 + lr;
                    afr[m] = *(const bf16x8*)(lds + (size_t)p * 65536 + ks * 16384
                             + ar * 64 + ((lch ^ ((ar >> 1) & 3)) << 4));
                }
                if (pf) {
                    if (ph == 0)      stage_half(p ^ 1, 0, 0, kc);
                    else if (ph == 1) stage_half(p ^ 1, 1, 0, kc);
                    else if (ph == 2) stage_half(p ^ 1, 0, 1, kc + 32);
                    else              stage_half(p ^ 1, 1, 1, kc + 32);
                }
                __builtin_amdgcn_sched_barrier(0);
                __builtin_amdgcn_s_barrier();
                asm volatile("s_waitcnt lgkmcnt(0)" ::: "memory");
                __builtin_amdgcn_sched_barrier(0);
                __builtin_amdgcn_s_setprio(1);
                #pragma unroll
                for (int m = 0; m < 4; ++m)
                    #pragma unroll
                    for (int n = 0; n < 4; ++n)
                        acc[mh][m][n] = __builtin_amdgcn_mfma_f32_16x16x32_bf16(
                            afr[m], bfr[n], acc[mh][m][n], 0, 0, 0);
                __builtin_amdgcn_s_setprio(0);
                if (ph == 1) {
                    if (pf) asm volatile("s_waitcnt vmcnt(4)" ::: "memory");  // ks1(t) landed
                    else    asm volatile("s_waitcnt vmcnt(0)" ::: "memory");
                    __builtin_amdgcn_sched_barrier(0);
                } else if (ph == 3) {
                    if (pf) {
                        asm volatile("s_waitcnt vmcnt(4)" ::: "memory");      // ks0(t+1) landed
                        __builtin_amdgcn_sched_barrier(0);
                    }
                }
                __builtin_amdgcn_s_barrier();
            }
        }
    }

    const int g4 = lch * 4;
    #pragma unroll
    for (int mh = 0; mh < 2; ++mh)
        #pragma unroll
        for (int m = 0; m < 4; ++m)
            #pragma unroll
            for (int n = 0; n < 4; ++n) {
                int col = bn + wc * 64 + n * 16 + lr;
                #pragma unroll
                for (int r = 0; r < 4; ++r) {
                    int rr = bm + wr * 128 + mh * 64 + m * 16 + g4 + r;
                    float v = acc[mh][m][n][r];
                    if (EPI == 1) {
                        ((unsigned short*)Cv)[(size_t)rr * N + col] = f2b(gelu_tanh(v + bias[col]));
                    } else if (EPI == 2) {
                        ((float*)Cv)[(size_t)rr * N + col] += v + bias[col];
                    } else if (EPI == 3) {
                        ((float*)Cv)[(size_t)rr * N + col] = v + extra[(size_t)(rr / batch_rows) * N + col];
                    } else if (EPI == 4) {
                        ((unsigned short*)Cv)[(size_t)rr * N + col] = f2b(v);
                    } else if (EPI == 6) {
                        unsigned short* dst = (col >> 9) ? (unsigned short*)Cv2 : (unsigned short*)Cv;
                        dst[(size_t)rr * 512 + (col & 511)] = f2b(v);
                    }
                }
            }
}

// ---------------- legacy 128x128 MFMA GEMM (tiny wcomp only) ----------------
#define BM 128
#define BN 128
#define BK 64

template <int EPI>
__global__ __launch_bounds__(256) void gemm_mfma(
    const unsigned short* __restrict__ A, int lda,
    const unsigned short* __restrict__ Bt, int ldb,
    void* __restrict__ Cv, int M, int N, int K, int ldo) {
    __shared__ unsigned short As[2][BM * BK];
    __shared__ unsigned short Bs[2][BN * BK];
    int bm = blockIdx.y * BM, bn = blockIdx.x * BN;
    int tid = threadIdx.x;
    int lane = tid & 63, wv = tid >> 6;
    int wr = (wv >> 1) * 64, wc = (wv & 1) * 64;
    int g16 = (lane >> 4) << 4;
    int lr = lane & 15;
    int sw = (lr & 7) << 4;

    int srow = tid >> 3;
    int skb = (tid & 7) * 16;
    int sxor = skb ^ ((srow & 7) << 4);

    auto stage = [&](int buf, int k0) {
        #pragma unroll
        for (int i = 0; i < 4; ++i) {
            int row = srow + 32 * i;
            GLOAD16((const char*)(A + (size_t)(bm + row) * lda + k0) + sxor,
                    (char*)As[buf] + (size_t)(tid + 256 * i) * 16);
        }
        #pragma unroll
        for (int i = 0; i < 4; ++i) {
            int row = srow + 32 * i;
            GLOAD16((const char*)(Bt + (size_t)(bn + row) * ldb + k0) + sxor,
                    (char*)Bs[buf] + (size_t)(tid + 256 * i) * 16);
        }
    };

    f32x4 acc[4][4] = {};
    int nt = K / BK;
    stage(0, 0);
    __syncthreads();
    for (int t = 0; t < nt; ++t) {
        int cur = t & 1;
        if (t + 1 < nt) stage(cur ^ 1, (t + 1) * BK);
        const char* Ab = (const char*)As[cur];
        const char* Bp = (const char*)Bs[cur];
        #pragma unroll
        for (int s = 0; s < 2; ++s) {
            int koff = s * 64 + g16;
            bf16x8 af[4], bw[4];
            #pragma unroll
            for (int f = 0; f < 4; ++f) {
                int ar = wr + f * 16 + lr;
                af[f] = *(const bf16x8*)(Ab + ar * 128 + (koff ^ sw));
                int br = wc + f * 16 + lr;
                bw[f] = *(const bf16x8*)(Bp + br * 128 + (koff ^ sw));
            }
            #pragma unroll
            for (int f = 0; f < 4; ++f)
                #pragma unroll
                for (int j = 0; j < 4; ++j)
                    acc[f][j] = __builtin_amdgcn_mfma_f32_16x16x32_bf16(
                        af[f], bw[j], acc[f][j], 0, 0, 0);
        }
        __syncthreads();
    }

    int g4 = (lane >> 4) * 4;
    #pragma unroll
    for (int f = 0; f < 4; ++f) {
        #pragma unroll
        for (int j = 0; j < 4; ++j) {
            int col = bn + wc + j * 16 + lr;
            #pragma unroll
            for (int r = 0; r < 4; ++r) {
                int rr = bm + wr + f * 16 + g4 + r;
                float v = acc[f][j][r];
                if (EPI == 4) {
                    ((unsigned short*)Cv)[(size_t)rr * N + col] = f2b(v);
                } else if (EPI == 5) {
                    ((unsigned short*)Cv)[(size_t)col * ldo + rr] = f2b(v);
                }
            }
        }
    }
}

// ---------------- k column-softmax stats ----------------
__global__ __launch_bounds__(256) void ksm_stats1(
    const unsigned short* __restrict__ k, float* __restrict__ pm, float* __restrict__ ps) {
    int b = blockIdx.y, rb = blockIdx.x;
    const unsigned short* kp = k + ((size_t)b * NN + (size_t)rb * 128) * DIMC;
    int t = threadIdx.x;
    float m0 = -1e30f, s0 = 0.f, m1 = -1e30f, s1 = 0.f;
    for (int r = 0; r < 128; ++r) {
        float x0 = b2f(kp[(size_t)r * DIMC + t]);
        float x1 = b2f(kp[(size_t)r * DIMC + t + 256]);
        if (x0 > m0) { s0 = s0 * __expf(m0 - x0) + 1.f; m0 = x0; } else s0 += __expf(x0 - m0);
        if (x1 > m1) { s1 = s1 * __expf(m1 - x1) + 1.f; m1 = x1; } else s1 += __expf(x1 - m1);
    }
    size_t base = ((size_t)b * 64 + rb) * DIMC;
    pm[base + t] = m0; pm[base + t + 256] = m1;
    ps[base + t] = s0; ps[base + t + 256] = s1;
}

__global__ void ksm_stats2(const float* __restrict__ pm, const float* __restrict__ ps,
                           float* __restrict__ Mst, float* __restrict__ Sinv) {
    int idx = blockIdx.x * 256 + threadIdx.x;
    int b = idx >> 9, c = idx & 511;
    float m = -1e30f, s = 0.f;
    for (int rb = 0; rb < 64; ++rb) {
        float mm = pm[((size_t)b * 64 + rb) * DIMC + c];
        float ss = ps[((size_t)b * 64 + rb) * DIMC + c];
        if (mm > m) { s = s * __expf(m - mm) + ss; m = mm; } else s += ss * __expf(mm - m);
    }
    Mst[idx] = m;
    Sinv[idx] = 1.f / s;
}

// ---------------- context = sum_n expk[n,d] * v[n,e] (round-11 LDS version, 62us) ----------------
__global__ __launch_bounds__(256) void context_kernel(
    const unsigned short* __restrict__ kb, const unsigned short* __restrict__ vb,
    const float* __restrict__ Mst, const float* __restrict__ Sinv,
    float* __restrict__ ctx) {
    int b = blockIdx.z, hd = blockIdx.y, rb = blockIdx.x;
    int tid = threadIdx.x, tx = tid & 15, ty = tid >> 4;
    __shared__ float kx[64][68];
    __shared__ float vx[64][68];
    int r0t = tid >> 3;
    int c8 = (tid & 7) * 8;
    int cb = hd * 64 + c8;
    float mv[8], sv[8];
    #pragma unroll
    for (int j = 0; j < 8; ++j) { mv[j] = Mst[b * DIMC + cb + j]; sv[j] = Sinv[b * DIMC + cb + j]; }
    float cacc[4][4] = {};
    for (int sub = 0; sub < 8; ++sub) {
        size_t row0 = (size_t)b * NN + (size_t)rb * 512 + sub * 64;
        #pragma unroll
        for (int i = 0; i < 2; ++i) {
            int r = r0t + i * 32;
            us8 kv = *(const us8*)(kb + (row0 + r) * DIMC + cb);
            us8 vv = *(const us8*)(vb + (row0 + r) * DIMC + cb);
            #pragma unroll
            for (int j = 0; j < 8; ++j) {
                kx[r][c8 + j] = __expf(b2f(kv[j]) - mv[j]) * sv[j];
                vx[r][c8 + j] = b2f(vv[j]);
            }
        }
        __syncthreads();
        #pragma unroll 4
        for (int r = 0; r < 64; ++r) {
            float4 a4 = *(const float4*)&kx[r][ty * 4];
            float4 b4 = *(const float4*)&vx[r][tx * 4];
            float av[4] = {a4.x, a4.y, a4.z, a4.w};
            float bv[4] = {b4.x, b4.y, b4.z, b4.w};
            #pragma unroll
            for (int i = 0; i < 4; ++i)
                #pragma unroll
                for (int j = 0; j < 4; ++j)
                    cacc[i][j] = fmaf(av[i], bv[j], cacc[i][j]);
        }
        __syncthreads();
    }
    size_t cbase = (size_t)(b * HEADS + hd) * 64 * 64;
    #pragma unroll
    for (int i = 0; i < 4; ++i)
        #pragma unroll
        for (int j = 0; j < 4; ++j)
            atomicAdd(&ctx[cbase + (size_t)(ty * 4 + i) * 64 + tx * 4 + j], cacc[i][j]);
}

// ---------------- q feature-softmax in place ----------------
__global__ __launch_bounds__(256) void qsm_kernel(unsigned short* __restrict__ qb) {
    int lane = threadIdx.x & 63;
    size_t row = (size_t)blockIdx.x * 4 + (threadIdx.x >> 6);
    size_t base = row * DIMC;
    #pragma unroll
    for (int h = 0; h < 8; ++h) {
        float v = b2f(qb[base + h * 64 + lane]);
        float m = v;
        #pragma unroll
        for (int o = 32; o; o >>= 1) m = fmaxf(m, __shfl_xor(m, o, 64));
        float e = __expf(v - m);
        float s = e;
        #pragma unroll
        for (int o = 32; o; o >>= 1) s += __shfl_xor(s, o, 64);
        qb[base + h * 64 + lane] = f2b(e * (0.125f / s));
    }
}

// ---------------- caw = ctx @ aow (per batch) ----------------
__global__ __launch_bounds__(256) void caw_kernel(const float* __restrict__ ctx,
                                                  const float* __restrict__ aow,
                                                  float* __restrict__ caw) {
    int nt = blockIdx.x, hd = blockIdx.y, b = blockIdx.z;
    int tid = threadIdx.x, tx = tid & 15, ty = tid >> 4;
    __shared__ float cs[64][68];
    __shared__ float aw[64][68];
    #pragma unroll
    for (int i = 0; i < 4; ++i) {
        int idx = tid + 256 * i;
        int r = idx >> 4, c4 = (idx & 15) * 4;
        *(float4*)&cs[r][c4] = *(const float4*)(ctx + ((size_t)(b * HEADS + hd) * 64 + r) * 64 + c4);
        *(float4*)&aw[r][c4] = *(const float4*)(aow + (size_t)(hd * 64 + r) * DIMC + nt * 64 + c4);
    }
    __syncthreads();
    float acc[4][4] = {};
    for (int e = 0; e < 64; ++e) {
        float av[4];
        #pragma unroll
        for (int i = 0; i < 4; ++i) av[i] = cs[ty * 4 + i][e];
        float4 b4 = *(const float4*)&aw[e][tx * 4];
        float bv[4] = {b4.x, b4.y, b4.z, b4.w};
        #pragma unroll
        for (int i = 0; i < 4; ++i)
            #pragma unroll
            for (int j = 0; j < 4; ++j)
                acc[i][j] = fmaf(av[i], bv[j], acc[i][j]);
    }
    #pragma unroll
    for (int i = 0; i < 4; ++i)
        #pragma unroll
        for (int j = 0; j < 4; ++j)
            caw[(size_t)b * DIMC * DIMC + (size_t)(hd * 64 + ty * 4 + i) * DIMC + nt * 64 + tx * 4 + j]
                = acc[i][j];
}

// ---------------- pos head ----------------
__global__ __launch_bounds__(256) void pos_kernel(
    const float* __restrict__ x, const float* __restrict__ w,
    const float* __restrict__ b2, float* __restrict__ out) {
    int lane = threadIdx.x & 63;
    size_t row = (size_t)blockIdx.x * 4 + (threadIdx.x >> 6);
    const float* xp = x + row * DIMC;
    float acc0 = 0.f, acc1 = 0.f;
    #pragma unroll
    for (int i = 0; i < 2; ++i) {
        float4 xv = *(const float4*)(xp + lane * 8 + i * 4);
        const float* wp = w + (size_t)(lane * 8 + i * 4) * 2;
        float4 w0 = *(const float4*)(wp);
        float4 w1 = *(const float4*)(wp + 4);
        acc0 += xv.x * w0.x + xv.y * w0.z + xv.z * w1.x + xv.w * w1.z;
        acc1 += xv.x * w0.y + xv.y * w0.w + xv.z * w1.y + xv.w * w1.w;
    }
    #pragma unroll
    for (int o = 32; o; o >>= 1) { acc0 += __shfl_down(acc0, o, 64); acc1 += __shfl_down(acc1, o, 64); }
    if (lane == 0) {
        out[row * 2] = acc0 + b2[0];
        out[row * 2 + 1] = acc1 + b2[1];
    }
}

// ---------------- launch ----------------
extern "C" void kernel_launch(void* const* d_in, const int* in_sizes, int n_in,
                              void* d_out, int out_size, void* d_ws, size_t ws_size,
                              hipStream_t stream) {
    (void)in_sizes; (void)n_in; (void)out_size; (void)ws_size;
    const float* nf  = (const float*)d_in[0];
    const float* dt  = (const float*)d_in[1];
    const float* pos = (const float*)d_in[2];
    const float* msk = (const float*)d_in[3];
    const float* yyw = (const float*)d_in[4];
    const float* yyb = (const float*)d_in[5];
    const float* p1w = (const float*)d_in[6];
    const float* p1b = (const float*)d_in[7];
    const float* p2w = (const float*)d_in[8];
    const float* p2b = (const float*)d_in[9];
    const float* lxw = (const float*)d_in[10];
    const float* lxb = (const float*)d_in[11];
    const float* cw  = (const float*)d_in[12];
    const float* cb  = (const float*)d_in[13];
    const float* l1g = (const float*)d_in[14];
    const float* l1b = (const float*)d_in[15];
    const float* qw  = (const float*)d_in[16];
    const float* kw  = (const float*)d_in[17];
    const float* vw  = (const float*)d_in[18];
    const float* aow = (const float*)d_in[19];
    const float* aob = (const float*)d_in[20];
    const float* l2g = (const float*)d_in[21];
    const float* l2b = (const float*)d_in[22];
    const float* f1w = (const float*)d_in[23];
    const float* f1b = (const float*)d_in[24];
    const float* f2w = (const float*)d_in[25];
    const float* f2b_ = (const float*)d_in[26];
    const float* hpw = (const float*)d_in[27];
    const float* hpb = (const float*)d_in[28];

    float* ws = (float*)d_ws;
    unsigned short* catA_u  = (unsigned short*)(ws + OFF_R0);
    unsigned short* hb_u    = (unsigned short*)(ws + OFF_R0);
    float*          caw     = ws + OFF_CAW;
    unsigned short* kb_u    = (unsigned short*)(ws + OFF_R1);
    unsigned short* qb_u    = (unsigned short*)(ws + OFF_R1);
    unsigned short* mid_u   = (unsigned short*)(ws + OFF_R1);   // [16384][2048] bf16 spans R1+R2
    unsigned short* vb_u    = (unsigned short*)(ws + OFF_R2);
    unsigned short* cawT_u  = (unsigned short*)(ws + OFF_R2);
    unsigned short* catWT_u = (unsigned short*)(ws + OFF_CATWT);
    unsigned short* kvT_u   = (unsigned short*)(ws + OFF_KVT);
    unsigned short* qwT_u   = (unsigned short*)(ws + OFF_QWT);
    unsigned short* f1wT_u  = (unsigned short*)(ws + OFF_F1WT);
    unsigned short* f2wT_u  = (unsigned short*)(ws + OFF_F2WT);
    unsigned short* lxwb_u  = (unsigned short*)(ws + OFF_LXWB);
    unsigned short* cw0T_u  = (unsigned short*)(ws + OFF_CW0T);
    float* yv   = ws + OFF_Y;
    float* bbf  = ws + OFF_BB;
    float* pm   = ws + OFF_PM;
    float* ps2  = ws + OFF_PS;
    float* Mst  = ws + OFF_M;
    float* Sinv = ws + OFF_SINV;
    float* ctx  = ws + OFF_CTX;

    float* xout = (float*)d_out;
    float* yout = xout + (size_t)ROWS * DIMC;
    float* pout = yout + NB * DT;

    // allow 128KB dynamic LDS for gemm256 (capture-safe: replay-validated r11/r12)
    hipFuncSetAttribute(reinterpret_cast<const void*>(&gemm256<1>),
                        hipFuncAttributeMaxDynamicSharedMemorySize, 131072);
    hipFuncSetAttribute(reinterpret_cast<const void*>(&gemm256<2>),
                        hipFuncAttributeMaxDynamicSharedMemorySize, 131072);
    hipFuncSetAttribute(reinterpret_cast<const void*>(&gemm256<3>),
                        hipFuncAttributeMaxDynamicSharedMemorySize, 131072);
    hipFuncSetAttribute(reinterpret_cast<const void*>(&gemm256<4>),
                        hipFuncAttributeMaxDynamicSharedMemorySize, 131072);
    hipFuncSetAttribute(reinterpret_cast<const void*>(&gemm256<6>),
                        hipFuncAttributeMaxDynamicSharedMemorySize, 131072);

    // prologue scalars + weight conversions
    y_kernel<<<4, 128, 0, stream>>>(dt, yyw, yyb, yv, yout);
    bb_kernel<<<8, 256, 0, stream>>>(lxb, cw, cb, yv, bbf);
    conv_bf16<<<128, 256, 0, stream>>>(lxw, lxwb_u, 32768);
    transconv<<<dim3(16, 16), 256, 0, stream>>>(cw, cw0T_u, 512, 512, 512);
    transconv<<<dim3(16, 2), 256, 0, stream>>>(cw + (size_t)DIMC * DIMC, catWT_u + 512, 64, 512, KCATP);
    zcat_kernel<<<128, 256, 0, stream>>>(catWT_u);
    transconv<<<dim3(16, 16), 256, 0, stream>>>(kw, kvT_u, 512, 512, 512);
    transconv<<<dim3(16, 16), 256, 0, stream>>>(vw, kvT_u + (size_t)512 * 512, 512, 512, 512);
    transconv<<<dim3(16, 16), 256, 0, stream>>>(qw, qwT_u, 512, 512, 512);
    transconv<<<dim3(64, 16), 256, 0, stream>>>(f1w, f1wT_u, 512, 2048, 512);
    transconv<<<dim3(16, 64), 256, 0, stream>>>(f2w, f2wT_u, 2048, 512, 2048);
    conv_bf16_strided<<<8192, 256, 0, stream>>>(nf, catA_u, KCATP);
    delta_kernel<<<8192, 256, 0, stream>>>(pos, msk, p1w, p1b, p2w, p2b, catA_u);

    // catWT cols 0..511 = (lxw @ cw0)^T
    gemm_mfma<5><<<dim3(4, 4), 256, 0, stream>>>(
        lxwb_u, 512, cw0T_u, 512, catWT_u, 512, 512, 512, KCATP);

    // cat = catA @ catWT^T + bb[batch] -> xout (f32)
    gemm256<3><<<dim3(2, 128), 512, 131072, stream>>>(
        catA_u, KCATP, catWT_u, KCATP, nullptr, bbf, NN,
        xout, nullptr, ROWS, 512, KCATP, 0, 0);

    // LN1: xout -> hb
    ln_kernel<<<ROWS, 128, 0, stream>>>(xout, hb_u, l1g, l1b);

    // fused k+v projection (N=1024, split store)
    gemm256<6><<<dim3(4, 128), 512, 131072, stream>>>(
        hb_u, 512, kvT_u, 512, nullptr, nullptr, 0,
        kb_u, vb_u, ROWS, 1024, 512, 0, 0);

    // k sequence-softmax stats
    ksm_stats1<<<dim3(64, 4), 256, 0, stream>>>(kb_u, pm, ps2);
    ksm_stats2<<<8, 256, 0, stream>>>(pm, ps2, Mst, Sinv);

    // context (consumes kb, vb)
    hipMemsetAsync(ctx, 0, (size_t)NB * HEADS * 64 * 64 * sizeof(float), stream);
    context_kernel<<<dim3(16, HEADS, NB), 256, 0, stream>>>(kb_u, vb_u, Mst, Sinv, ctx);

    // q projection into R1 (kb dead), softmax in place
    gemm256<4><<<dim3(2, 128), 512, 131072, stream>>>(
        hb_u, 512, qwT_u, 512, nullptr, nullptr, 0,
        qb_u, nullptr, ROWS, 512, 512, 0, 0);
    qsm_kernel<<<8192, 256, 0, stream>>>(qb_u);

    // compose ctx with attn_out_w per batch; transpose into R2 (vb dead)
    caw_kernel<<<dim3(8, 8, 4), 256, 0, stream>>>(ctx, aow, caw);
    for (int b = 0; b < NB; ++b)
        transconv<<<dim3(16, 16), 256, 0, stream>>>(caw + (size_t)b * 262144,
                                                    cawT_u + (size_t)b * 262144, 512, 512, 512);

    // x += qsm @ caw[b]^T + aob
    gemm256<2><<<dim3(2, 128), 512, 131072, stream>>>(
        qb_u, 512, cawT_u, 512, aob, nullptr, 0,
        xout, nullptr, ROWS, 512, 512, 262144, NN);

    // FF block: LN2 then per-2-batch {ff1 N=2048 -> mid(R1+R2); ff2 K=2048 nt=32 -> xout}
    // (qb and cawT are dead; mid = [16384][2048]bf16 = 67MB spans R1+R2 exactly)
    ln_kernel<<<ROWS, 128, 0, stream>>>(xout, hb_u, l2g, l2b);
    for (int bp = 0; bp < 2; ++bp) {
        const unsigned short* hbp = hb_u + (size_t)bp * 16384 * DIMC;
        gemm256<1><<<dim3(8, 64), 512, 131072, stream>>>(
            hbp, 512, f1wT_u, 512, f1b, nullptr, 0,
            mid_u, nullptr, 16384, FF, 512, 0, 0);
        gemm256<2><<<dim3(2, 64), 512, 131072, stream>>>(
            mid_u, 2048, f2wT_u, 2048, f2b_, nullptr, 0,
            xout + (size_t)bp * 16384 * DIMC, nullptr, 16384, 512, 2048, 0, 0);
    }

    pos_kernel<<<8192, 256, 0, stream>>>(xout, hpw, hpb, pout);
}

// Round 14
// 701.033 us; speedup vs baseline: 1.3527x; 1.1246x over previous
//
#include <hip/hip_runtime.h>
#include <hip/hip_bf16.h>
#include <math.h>

// ---------------- constants ----------------
#define NB 4
#define NN 8192
#define ROWS (NB*NN)          // 32768
#define DIMC 512
#define HEADS 8
#define DT 128
#define DELTA 64
#define FF 2048
#define KCATP 640             // 576 padded to 640; pad cols zeroed on BOTH A and B sides every call

// ---------------- workspace layout (FLOAT units) ----------------
#define OFF_R0     ((size_t)0)          // catA [32768][640]bf16 -> hb [32768][512]bf16
#define OFF_CAW    ((size_t)8388608)    // caw f32 [4][512][512] (tail slack past hb)
#define OFF_R1     ((size_t)10485760)   // kb -> qb -> mid(lo)   [R1:8,388,608 f]
#define OFF_R2     ((size_t)18874368)   // vb -> cawT -> mid(hi) [R2:8,388,608 f]
                                        // mid = [16384][2048]bf16 spans R1+R2 exactly
#define OFF_CATWT  ((size_t)27262976)   // bf16 [512][640]
#define OFF_KVT    ((size_t)27426816)   // bf16 [1024][512]
#define OFF_QWT    ((size_t)27688960)   // bf16 [512][512]
#define OFF_F1WT   ((size_t)27820032)   // bf16 [2048][512]
#define OFF_F2WT   ((size_t)28344320)   // bf16 [512][2048]
#define OFF_LXWB   ((size_t)28868608)   // bf16 [512][512]
#define OFF_CW0T   ((size_t)28999680)   // bf16 [512][512]
#define OFF_Y      ((size_t)29130752)
#define OFF_BB     ((size_t)29131264)
#define OFF_PM     ((size_t)29133312)
#define OFF_PS     ((size_t)29264384)
#define OFF_M      ((size_t)29395456)
#define OFF_SINV   ((size_t)29397504)
#define OFF_CTX    ((size_t)29399552)
// end = 29,530,624 floats = 118.1 MB

typedef __attribute__((ext_vector_type(8))) short bf16x8;
typedef __attribute__((ext_vector_type(4))) float f32x4;
typedef __attribute__((ext_vector_type(8))) unsigned short us8;

static __device__ __forceinline__ unsigned short f2b(float x) {
    __hip_bfloat16 h = __float2bfloat16(x);
    return __builtin_bit_cast(unsigned short, h);
}
static __device__ __forceinline__ float b2f(unsigned short u) {
    return __bfloat162float(__builtin_bit_cast(__hip_bfloat16, u));
}
static __device__ __forceinline__ float gelu_tanh(float x) {
    float t = tanhf(0.7978845608028654f * (x + 0.044715f * x * x * x));
    return 0.5f * x * (1.0f + t);
}

#define GLOAD16(g, l) __builtin_amdgcn_global_load_lds( \
    (const __attribute__((address_space(1))) void*)(g), \
    (__attribute__((address_space(3))) void*)(l), 16, 0, 0)

// ---------------- tiny prologue kernels ----------------
__global__ void y_kernel(const float* __restrict__ dt, const float* __restrict__ yyw,
                         const float* __restrict__ yyb, float* __restrict__ y_ws,
                         float* __restrict__ y_out) {
    int idx = blockIdx.x * 128 + threadIdx.x;   // 512
    int b = idx >> 7, j = idx & 127;
    float acc = yyb[j];
    for (int c = 0; c < DT; ++c) acc += dt[b * DT + c] * yyw[c * DT + j];
    y_ws[idx] = acc;
    y_out[idx] = acc;
}

__global__ void bb_kernel(const float* __restrict__ linxb, const float* __restrict__ catw,
                          const float* __restrict__ catb, const float* __restrict__ y,
                          float* __restrict__ bb) {
    int idx = blockIdx.x * 256 + threadIdx.x;   // 2048
    int b = idx >> 9, n = idx & 511;
    float acc = catb[n];
    for (int c = 0; c < DIMC; ++c) acc += linxb[c] * catw[(size_t)c * DIMC + n];
    const float* cw3 = catw + (size_t)(DIMC + DELTA) * DIMC;
    for (int j = 0; j < DT; ++j) acc += y[b * DT + j] * cw3[(size_t)j * DIMC + n];
    bb[idx] = acc;
}

// delta -> catA columns 512..575; ALSO zero pad cols 576..639 (replay safety)
__global__ __launch_bounds__(256) void delta_kernel(
    const float* __restrict__ pos, const float* __restrict__ mask,
    const float* __restrict__ w1, const float* __restrict__ b1,
    const float* __restrict__ w2, const float* __restrict__ b2,
    unsigned short* __restrict__ catA) {
    int lane = threadIdx.x & 63;
    size_t row = (size_t)blockIdx.x * 4 + (threadIdx.x >> 6);
    float mk = mask[row];
    float px = pos[row * 2] * mk, py = pos[row * 2 + 1] * mk;
    float nrm = sqrtf(px * px + py * py) + 1e-7f;
    float ux = px / nrm, uy = py / nrm;
    float t1 = fmaxf(ux * w1[lane] + uy * w1[64 + lane] + b1[lane], 0.0f);
    float acc = b2[lane];
    #pragma unroll
    for (int j = 0; j < 64; ++j) {
        float tv = __shfl(t1, j, 64);
        acc += tv * w2[j * 64 + lane];
    }
    catA[row * KCATP + DIMC + lane] = f2b(acc);
    catA[row * KCATP + 576 + lane] = 0;
}

// zero catWT pad cols 576..639 (B side)
__global__ void zcat_kernel(unsigned short* __restrict__ catWT) {
    int idx = blockIdx.x * 256 + threadIdx.x;   // 32768
    int n = idx >> 6, c = 576 + (idx & 63);
    catWT[(size_t)n * KCATP + c] = 0;
}

// f32 -> bf16 flat convert
__global__ void conv_bf16(const float* __restrict__ in, unsigned short* __restrict__ out, int n8) {
    int i = blockIdx.x * 256 + threadIdx.x;
    if (i >= n8) return;
    const float* p = in + (size_t)i * 8;
    us8 o;
    #pragma unroll
    for (int j = 0; j < 8; ++j) o[j] = f2b(p[j]);
    *(us8*)(out + (size_t)i * 8) = o;
}

// f32 [rows][512] -> bf16 out[row*ldo + c]
__global__ void conv_bf16_strided(const float* __restrict__ in, unsigned short* __restrict__ out,
                                  int ldo) {
    int i = blockIdx.x * 256 + threadIdx.x;
    int row = i >> 6, c8 = (i & 63) * 8;
    const float* p = in + (size_t)row * DIMC + c8;
    us8 o;
    #pragma unroll
    for (int j = 0; j < 8; ++j) o[j] = f2b(p[j]);
    *(us8*)(out + (size_t)row * ldo + c8) = o;
}

// f32 [R][C] -> bf16 out[c*ldo + r]
__global__ __launch_bounds__(256) void transconv(const float* __restrict__ in,
                                                 unsigned short* __restrict__ out,
                                                 int R, int C, int ldo) {
    __shared__ float tile[32][33];
    int bx = blockIdx.x * 32;
    int by = blockIdx.y * 32;
    int tx = threadIdx.x & 31, ty = threadIdx.x >> 5;
    #pragma unroll
    for (int i = 0; i < 4; ++i) {
        int r = ty + i * 8;
        tile[r][tx] = in[(size_t)(by + r) * C + bx + tx];
    }
    __syncthreads();
    #pragma unroll
    for (int i = 0; i < 4; ++i) {
        int r = ty + i * 8;
        out[(size_t)(bx + r) * ldo + by + tx] = f2b(tile[tx][r]);
    }
}

// LayerNorm: f32 in -> bf16 out
__global__ __launch_bounds__(128) void ln_kernel(
    const float* __restrict__ src, unsigned short* __restrict__ dst,
    const float* __restrict__ g, const float* __restrict__ bta) {
    size_t row = blockIdx.x;
    int t = threadIdx.x;
    const float* s = src + row * DIMC;
    float4 x = *(const float4*)(s + t * 4);
    float sum = x.x + x.y + x.z + x.w;
    float sq = x.x * x.x + x.y * x.y + x.z * x.z + x.w * x.w;
    #pragma unroll
    for (int o = 32; o; o >>= 1) { sum += __shfl_down(sum, o, 64); sq += __shfl_down(sq, o, 64); }
    __shared__ float sh[4];
    if ((t & 63) == 0) { sh[(t >> 6) * 2] = sum; sh[(t >> 6) * 2 + 1] = sq; }
    __syncthreads();
    sum = sh[0] + sh[2]; sq = sh[1] + sh[3];
    float mean = sum * (1.0f / DIMC);
    float var = sq * (1.0f / DIMC) - mean * mean;
    float rstd = rsqrtf(fmaxf(var, 0.0f) + 1e-5f);
    float4 gv = *(const float4*)(g + t * 4);
    float4 bv = *(const float4*)(bta + t * 4);
    ushort4 ov;
    ov.x = f2b((x.x - mean) * rstd * gv.x + bv.x);
    ov.y = f2b((x.y - mean) * rstd * gv.y + bv.y);
    ov.z = f2b((x.z - mean) * rstd * gv.z + bv.z);
    ov.w = f2b((x.w - mean) * rstd * gv.w + bv.w);
    *(ushort4*)(dst + row * DIMC + t * 4) = ov;
}

// ================= 256-wide 8-phase counted-vmcnt MFMA GEMM =================
// C[M,N] = A[M,K] @ Bt[N,K], bf16. 512 threads = 8 waves, BN=256, BM=128*MH.
// MH=2: waves 2x4 (per-wave 128x64), 4 phases/tile, vmcnt(4)  [replay-proven r11-r13]
// MH=1: waves 2x4 (per-wave 64x64),  2 phases/tile, vmcnt(3)  [A-half=1 load, B-half=2;
//        per-phase stage=3 loads; waits: ks0-end {ks1(t):3,+3 prefetch}->vmcnt(3);
//        ks1-end {ks0(t+1):3,ks1(t+1):3}->vmcnt(3); prologue 6 loads -> vmcnt(3)]
// EPI: 1 gelu->bf16; 2 f32 +=; 3 f32 +extra[batch]; 6 bf16 split store;
//      7 bf16 head-softmax (feature softmax over the wave's 64-col head) * DH^-0.5.
template <int EPI, int MH>
__global__ __launch_bounds__(512, 1) void gemm256(
    const unsigned short* __restrict__ A, int lda,
    const unsigned short* __restrict__ Bt, int ldb,
    const float* __restrict__ bias,
    const float* __restrict__ extra, int batch_rows,
    void* __restrict__ Cv, void* __restrict__ Cv2,
    int M, int N, int K,
    size_t b_stride, int rows_per_batch) {
    extern __shared__ char lds[];
    constexpr int AH = 8192 * MH;          // A half-tile bytes
    constexpr int SLOT = 2 * AH + 32768;   // per-buffer slot bytes
    const int tid = threadIdx.x;
    const int lane = tid & 63, wv = tid >> 6;
    const int wr = wv >> 2, wc = wv & 3;
    const int lr = lane & 15, lch = lane >> 4;
    const int bm = blockIdx.y * (128 * MH), bn = blockIdx.x * 256;

    const unsigned short* Bb = Bt;
    if (rows_per_batch) Bb = Bt + (size_t)(bm / rows_per_batch) * b_stride;

    const int srow = tid >> 2;          // 0..127 (+128)
    const int schunk = tid & 3;

    auto stage_A = [&](int p, int ks, int kcol) {
        char* dst = lds + (size_t)p * SLOT + ks * AH;
        #pragma unroll
        for (int i = 0; i < MH; ++i) {
            int row = srow + 128 * i;
            int gc = schunk ^ ((row >> 1) & 3);
            GLOAD16((const char*)(A + (size_t)(bm + row) * lda + kcol) + gc * 16,
                    dst + (size_t)(tid + 512 * i) * 16);
        }
    };
    auto stage_B = [&](int p, int ks, int kcol) {
        char* dst = lds + (size_t)p * SLOT + 2 * AH + ks * 16384;
        #pragma unroll
        for (int i = 0; i < 2; ++i) {
            int row = srow + 128 * i;
            int gc = schunk ^ ((row >> 1) & 3);
            GLOAD16((const char*)(Bb + (size_t)(bn + row) * ldb + kcol) + gc * 16,
                    dst + (size_t)(tid + 512 * i) * 16);
        }
    };

    f32x4 acc[MH][4][4] = {};
    const int nt = K >> 6;

    stage_A(0, 0, 0);
    stage_B(0, 0, 0);
    stage_A(0, 1, 32);
    stage_B(0, 1, 32);
    __builtin_amdgcn_sched_barrier(0);
    if constexpr (MH == 2) asm volatile("s_waitcnt vmcnt(4)" ::: "memory");
    else                   asm volatile("s_waitcnt vmcnt(3)" ::: "memory");
    __builtin_amdgcn_sched_barrier(0);
    __builtin_amdgcn_s_barrier();

    for (int t = 0; t < nt; ++t) {
        const int p = t & 1;
        const bool pf = (t + 1 < nt);
        const int kc = (t + 1) << 6;
        if constexpr (MH == 2) {
            bf16x8 bfr[4], afr[4];
            #pragma unroll
            for (int ks = 0; ks < 2; ++ks) {
                #pragma unroll
                for (int mh = 0; mh < 2; ++mh) {
                    const int ph = ks * 2 + mh;
                    if (mh == 0) {
                        #pragma unroll
                        for (int n = 0; n < 4; ++n) {
                            int bc = wc * 64 + n * 16 + lr;
                            bfr[n] = *(const bf16x8*)(lds + (size_t)p * SLOT + 2 * AH + ks * 16384
                                     + bc * 64 + ((lch ^ ((bc >> 1) & 3)) << 4));
                        }
                    }
                    #pragma unroll
                    for (int m = 0; m < 4; ++m) {
                        int ar = wr * 128 + mh * 64 + m * 16 + lr;
                        afr[m] = *(const bf16x8*)(lds + (size_t)p * SLOT + ks * AH
                                 + ar * 64 + ((lch ^ ((ar >> 1) & 3)) << 4));
                    }
                    if (pf) {
                        if (ph == 0)      stage_A(p ^ 1, 0, kc);
                        else if (ph == 1) stage_B(p ^ 1, 0, kc);
                        else if (ph == 2) stage_A(p ^ 1, 1, kc + 32);
                        else              stage_B(p ^ 1, 1, kc + 32);
                    }
                    __builtin_amdgcn_sched_barrier(0);
                    __builtin_amdgcn_s_barrier();
                    asm volatile("s_waitcnt lgkmcnt(0)" ::: "memory");
                    __builtin_amdgcn_sched_barrier(0);
                    __builtin_amdgcn_s_setprio(1);
                    #pragma unroll
                    for (int m = 0; m < 4; ++m)
                        #pragma unroll
                        for (int n = 0; n < 4; ++n)
                            acc[mh][m][n] = __builtin_amdgcn_mfma_f32_16x16x32_bf16(
                                afr[m], bfr[n], acc[mh][m][n], 0, 0, 0);
                    __builtin_amdgcn_s_setprio(0);
                    if (ph == 1) {
                        if (pf) asm volatile("s_waitcnt vmcnt(4)" ::: "memory");
                        else    asm volatile("s_waitcnt vmcnt(0)" ::: "memory");
                        __builtin_amdgcn_sched_barrier(0);
                    } else if (ph == 3) {
                        if (pf) {
                            asm volatile("s_waitcnt vmcnt(4)" ::: "memory");
                            __builtin_amdgcn_sched_barrier(0);
                        }
                    }
                    __builtin_amdgcn_s_barrier();
                }
            }
        } else {  // MH == 1: 2 phases per tile
            #pragma unroll
            for (int ks = 0; ks < 2; ++ks) {
                bf16x8 bfr[4], afr[4];
                #pragma unroll
                for (int n = 0; n < 4; ++n) {
                    int bc = wc * 64 + n * 16 + lr;
                    bfr[n] = *(const bf16x8*)(lds + (size_t)p * SLOT + 2 * AH + ks * 16384
                             + bc * 64 + ((lch ^ ((bc >> 1) & 3)) << 4));
                }
                #pragma unroll
                for (int m = 0; m < 4; ++m) {
                    int ar = wr * 64 + m * 16 + lr;
                    afr[m] = *(const bf16x8*)(lds + (size_t)p * SLOT + ks * AH
                             + ar * 64 + ((lch ^ ((ar >> 1) & 3)) << 4));
                }
                if (pf) {
                    stage_A(p ^ 1, ks, kc + 32 * ks);
                    stage_B(p ^ 1, ks, kc + 32 * ks);
                }
                __builtin_amdgcn_sched_barrier(0);
                __builtin_amdgcn_s_barrier();
                asm volatile("s_waitcnt lgkmcnt(0)" ::: "memory");
                __builtin_amdgcn_sched_barrier(0);
                __builtin_amdgcn_s_setprio(1);
                #pragma unroll
                for (int m = 0; m < 4; ++m)
                    #pragma unroll
                    for (int n = 0; n < 4; ++n)
                        acc[0][m][n] = __builtin_amdgcn_mfma_f32_16x16x32_bf16(
                            afr[m], bfr[n], acc[0][m][n], 0, 0, 0);
                __builtin_amdgcn_s_setprio(0);
                if (ks == 0) {
                    if (pf) asm volatile("s_waitcnt vmcnt(3)" ::: "memory");
                    else    asm volatile("s_waitcnt vmcnt(0)" ::: "memory");
                    __builtin_amdgcn_sched_barrier(0);
                } else {
                    if (pf) {
                        asm volatile("s_waitcnt vmcnt(3)" ::: "memory");
                        __builtin_amdgcn_sched_barrier(0);
                    }
                }
                __builtin_amdgcn_s_barrier();
            }
        }
    }

    const int g4 = lch * 4;
    if constexpr (EPI == 7) {
        // head-feature softmax: wave's 64-col span = one head; row's 64 values live in
        // 16 same-lch lanes x 4 n-regs -> in-register + shfl_xor(1,2,4,8) reduce.
        #pragma unroll
        for (int mh = 0; mh < MH; ++mh)
            #pragma unroll
            for (int m = 0; m < 4; ++m)
                #pragma unroll
                for (int r = 0; r < 4; ++r) {
                    float v0 = acc[mh][m][0][r], v1 = acc[mh][m][1][r];
                    float v2 = acc[mh][m][2][r], v3 = acc[mh][m][3][r];
                    float mx = fmaxf(fmaxf(v0, v1), fmaxf(v2, v3));
                    #pragma unroll
                    for (int o = 1; o < 16; o <<= 1) mx = fmaxf(mx, __shfl_xor(mx, o, 64));
                    float e0 = __expf(v0 - mx), e1 = __expf(v1 - mx);
                    float e2 = __expf(v2 - mx), e3 = __expf(v3 - mx);
                    float s = e0 + e1 + e2 + e3;
                    #pragma unroll
                    for (int o = 1; o < 16; o <<= 1) s += __shfl_xor(s, o, 64);
                    float sc = 0.125f / s;
                    int rr = bm + wr * (64 * MH) + mh * 64 + m * 16 + g4 + r;
                    unsigned short* dst = (unsigned short*)Cv + (size_t)rr * N + bn + wc * 64 + lr;
                    dst[0]  = f2b(e0 * sc);
                    dst[16] = f2b(e1 * sc);
                    dst[32] = f2b(e2 * sc);
                    dst[48] = f2b(e3 * sc);
                }
    } else {
        #pragma unroll
        for (int mh = 0; mh < MH; ++mh)
            #pragma unroll
            for (int m = 0; m < 4; ++m)
                #pragma unroll
                for (int n = 0; n < 4; ++n) {
                    int col = bn + wc * 64 + n * 16 + lr;
                    #pragma unroll
                    for (int r = 0; r < 4; ++r) {
                        int rr = bm + wr * (64 * MH) + mh * 64 + m * 16 + g4 + r;
                        float v = acc[mh][m][n][r];
                        if (EPI == 1) {
                            ((unsigned short*)Cv)[(size_t)rr * N + col] = f2b(gelu_tanh(v + bias[col]));
                        } else if (EPI == 2) {
                            ((float*)Cv)[(size_t)rr * N + col] += v + bias[col];
                        } else if (EPI == 3) {
                            ((float*)Cv)[(size_t)rr * N + col] = v + extra[(size_t)(rr / batch_rows) * N + col];
                        } else if (EPI == 6) {
                            unsigned short* dst = (col >> 9) ? (unsigned short*)Cv2 : (unsigned short*)Cv;
                            dst[(size_t)rr * 512 + (col & 511)] = f2b(v);
                        }
                    }
                }
    }
}

// ---------------- legacy 128x128 MFMA GEMM (tiny wcomp only) ----------------
#define BM 128
#define BN 128
#define BK 64

template <int EPI>
__global__ __launch_bounds__(256) void gemm_mfma(
    const unsigned short* __restrict__ A, int lda,
    const unsigned short* __restrict__ Bt, int ldb,
    void* __restrict__ Cv, int M, int N, int K, int ldo) {
    __shared__ unsigned short As[2][BM * BK];
    __shared__ unsigned short Bs[2][BN * BK];
    int bm = blockIdx.y * BM, bn = blockIdx.x * BN;
    int tid = threadIdx.x;
    int lane = tid & 63, wv = tid >> 6;
    int wr = (wv >> 1) * 64, wc = (wv & 1) * 64;
    int g16 = (lane >> 4) << 4;
    int lr = lane & 15;
    int sw = (lr & 7) << 4;

    int srow = tid >> 3;
    int skb = (tid & 7) * 16;
    int sxor = skb ^ ((srow & 7) << 4);

    auto stage = [&](int buf, int k0) {
        #pragma unroll
        for (int i = 0; i < 4; ++i) {
            int row = srow + 32 * i;
            GLOAD16((const char*)(A + (size_t)(bm + row) * lda + k0) + sxor,
                    (char*)As[buf] + (size_t)(tid + 256 * i) * 16);
        }
        #pragma unroll
        for (int i = 0; i < 4; ++i) {
            int row = srow + 32 * i;
            GLOAD16((const char*)(Bt + (size_t)(bn + row) * ldb + k0) + sxor,
                    (char*)Bs[buf] + (size_t)(tid + 256 * i) * 16);
        }
    };

    f32x4 acc[4][4] = {};
    int nt = K / BK;
    stage(0, 0);
    __syncthreads();
    for (int t = 0; t < nt; ++t) {
        int cur = t & 1;
        if (t + 1 < nt) stage(cur ^ 1, (t + 1) * BK);
        const char* Ab = (const char*)As[cur];
        const char* Bp = (const char*)Bs[cur];
        #pragma unroll
        for (int s = 0; s < 2; ++s) {
            int koff = s * 64 + g16;
            bf16x8 af[4], bw[4];
            #pragma unroll
            for (int f = 0; f < 4; ++f) {
                int ar = wr + f * 16 + lr;
                af[f] = *(const bf16x8*)(Ab + ar * 128 + (koff ^ sw));
                int br = wc + f * 16 + lr;
                bw[f] = *(const bf16x8*)(Bp + br * 128 + (koff ^ sw));
            }
            #pragma unroll
            for (int f = 0; f < 4; ++f)
                #pragma unroll
                for (int j = 0; j < 4; ++j)
                    acc[f][j] = __builtin_amdgcn_mfma_f32_16x16x32_bf16(
                        af[f], bw[j], acc[f][j], 0, 0, 0);
        }
        __syncthreads();
    }

    int g4 = (lane >> 4) * 4;
    #pragma unroll
    for (int f = 0; f < 4; ++f) {
        #pragma unroll
        for (int j = 0; j < 4; ++j) {
            int col = bn + wc + j * 16 + lr;
            #pragma unroll
            for (int r = 0; r < 4; ++r) {
                int rr = bm + wr + f * 16 + g4 + r;
                float v = acc[f][j][r];
                if (EPI == 4) {
                    ((unsigned short*)Cv)[(size_t)rr * N + col] = f2b(v);
                } else if (EPI == 5) {
                    ((unsigned short*)Cv)[(size_t)col * ldo + rr] = f2b(v);
                }
            }
        }
    }
}

// ---------------- k column-softmax stats ----------------
__global__ __launch_bounds__(256) void ksm_stats1(
    const unsigned short* __restrict__ k, float* __restrict__ pm, float* __restrict__ ps) {
    int b = blockIdx.y, rb = blockIdx.x;
    const unsigned short* kp = k + ((size_t)b * NN + (size_t)rb * 128) * DIMC;
    int t = threadIdx.x;
    float m0 = -1e30f, s0 = 0.f, m1 = -1e30f, s1 = 0.f;
    for (int r = 0; r < 128; ++r) {
        float x0 = b2f(kp[(size_t)r * DIMC + t]);
        float x1 = b2f(kp[(size_t)r * DIMC + t + 256]);
        if (x0 > m0) { s0 = s0 * __expf(m0 - x0) + 1.f; m0 = x0; } else s0 += __expf(x0 - m0);
        if (x1 > m1) { s1 = s1 * __expf(m1 - x1) + 1.f; m1 = x1; } else s1 += __expf(x1 - m1);
    }
    size_t base = ((size_t)b * 64 + rb) * DIMC;
    pm[base + t] = m0; pm[base + t + 256] = m1;
    ps[base + t] = s0; ps[base + t + 256] = s1;
}

__global__ void ksm_stats2(const float* __restrict__ pm, const float* __restrict__ ps,
                           float* __restrict__ Mst, float* __restrict__ Sinv) {
    int idx = blockIdx.x * 256 + threadIdx.x;
    int b = idx >> 9, c = idx & 511;
    float m = -1e30f, s = 0.f;
    for (int rb = 0; rb < 64; ++rb) {
        float mm = pm[((size_t)b * 64 + rb) * DIMC + c];
        float ss = ps[((size_t)b * 64 + rb) * DIMC + c];
        if (mm > m) { s = s * __expf(m - mm) + ss; m = mm; } else s += ss * __expf(mm - m);
    }
    Mst[idx] = m;
    Sinv[idx] = 1.f / s;
}

// ---------------- context = sum_n expk[n,d] * v[n,e] (LDS version, ~62us) ----------------
__global__ __launch_bounds__(256) void context_kernel(
    const unsigned short* __restrict__ kb, const unsigned short* __restrict__ vb,
    const float* __restrict__ Mst, const float* __restrict__ Sinv,
    float* __restrict__ ctx) {
    int b = blockIdx.z, hd = blockIdx.y, rb = blockIdx.x;
    int tid = threadIdx.x, tx = tid & 15, ty = tid >> 4;
    __shared__ float kx[64][68];
    __shared__ float vx[64][68];
    int r0t = tid >> 3;
    int c8 = (tid & 7) * 8;
    int cb = hd * 64 + c8;
    float mv[8], sv[8];
    #pragma unroll
    for (int j = 0; j < 8; ++j) { mv[j] = Mst[b * DIMC + cb + j]; sv[j] = Sinv[b * DIMC + cb + j]; }
    float cacc[4][4] = {};
    for (int sub = 0; sub < 8; ++sub) {
        size_t row0 = (size_t)b * NN + (size_t)rb * 512 + sub * 64;
        #pragma unroll
        for (int i = 0; i < 2; ++i) {
            int r = r0t + i * 32;
            us8 kv = *(const us8*)(kb + (row0 + r) * DIMC + cb);
            us8 vv = *(const us8*)(vb + (row0 + r) * DIMC + cb);
            #pragma unroll
            for (int j = 0; j < 8; ++j) {
                kx[r][c8 + j] = __expf(b2f(kv[j]) - mv[j]) * sv[j];
                vx[r][c8 + j] = b2f(vv[j]);
            }
        }
        __syncthreads();
        #pragma unroll 4
        for (int r = 0; r < 64; ++r) {
            float4 a4 = *(const float4*)&kx[r][ty * 4];
            float4 b4 = *(const float4*)&vx[r][tx * 4];
            float av[4] = {a4.x, a4.y, a4.z, a4.w};
            float bv[4] = {b4.x, b4.y, b4.z, b4.w};
            #pragma unroll
            for (int i = 0; i < 4; ++i)
                #pragma unroll
                for (int j = 0; j < 4; ++j)
                    cacc[i][j] = fmaf(av[i], bv[j], cacc[i][j]);
        }
        __syncthreads();
    }
    size_t cbase = (size_t)(b * HEADS + hd) * 64 * 64;
    #pragma unroll
    for (int i = 0; i < 4; ++i)
        #pragma unroll
        for (int j = 0; j < 4; ++j)
            atomicAdd(&ctx[cbase + (size_t)(ty * 4 + i) * 64 + tx * 4 + j], cacc[i][j]);
}

// ---------------- caw = ctx @ aow (per batch) ----------------
__global__ __launch_bounds__(256) void caw_kernel(const float* __restrict__ ctx,
                                                  const float* __restrict__ aow,
                                                  float* __restrict__ caw) {
    int nt = blockIdx.x, hd = blockIdx.y, b = blockIdx.z;
    int tid = threadIdx.x, tx = tid & 15, ty = tid >> 4;
    __shared__ float cs[64][68];
    __shared__ float aw[64][68];
    #pragma unroll
    for (int i = 0; i < 4; ++i) {
        int idx = tid + 256 * i;
        int r = idx >> 4, c4 = (idx & 15) * 4;
        *(float4*)&cs[r][c4] = *(const float4*)(ctx + ((size_t)(b * HEADS + hd) * 64 + r) * 64 + c4);
        *(float4*)&aw[r][c4] = *(const float4*)(aow + (size_t)(hd * 64 + r) * DIMC + nt * 64 + c4);
    }
    __syncthreads();
    float acc[4][4] = {};
    for (int e = 0; e < 64; ++e) {
        float av[4];
        #pragma unroll
        for (int i = 0; i < 4; ++i) av[i] = cs[ty * 4 + i][e];
        float4 b4 = *(const float4*)&aw[e][tx * 4];
        float bv[4] = {b4.x, b4.y, b4.z, b4.w};
        #pragma unroll
        for (int i = 0; i < 4; ++i)
            #pragma unroll
            for (int j = 0; j < 4; ++j)
                acc[i][j] = fmaf(av[i], bv[j], acc[i][j]);
    }
    #pragma unroll
    for (int i = 0; i < 4; ++i)
        #pragma unroll
        for (int j = 0; j < 4; ++j)
            caw[(size_t)b * DIMC * DIMC + (size_t)(hd * 64 + ty * 4 + i) * DIMC + nt * 64 + tx * 4 + j]
                = acc[i][j];
}

// ---------------- pos head ----------------
__global__ __launch_bounds__(256) void pos_kernel(
    const float* __restrict__ x, const float* __restrict__ w,
    const float* __restrict__ b2, float* __restrict__ out) {
    int lane = threadIdx.x & 63;
    size_t row = (size_t)blockIdx.x * 4 + (threadIdx.x >> 6);
    const float* xp = x + row * DIMC;
    float acc0 = 0.f, acc1 = 0.f;
    #pragma unroll
    for (int i = 0; i < 2; ++i) {
        float4 xv = *(const float4*)(xp + lane * 8 + i * 4);
        const float* wp = w + (size_t)(lane * 8 + i * 4) * 2;
        float4 w0 = *(const float4*)(wp);
        float4 w1 = *(const float4*)(wp + 4);
        acc0 += xv.x * w0.x + xv.y * w0.z + xv.z * w1.x + xv.w * w1.z;
        acc1 += xv.x * w0.y + xv.y * w0.w + xv.z * w1.y + xv.w * w1.w;
    }
    #pragma unroll
    for (int o = 32; o; o >>= 1) { acc0 += __shfl_down(acc0, o, 64); acc1 += __shfl_down(acc1, o, 64); }
    if (lane == 0) {
        out[row * 2] = acc0 + b2[0];
        out[row * 2 + 1] = acc1 + b2[1];
    }
}

// ---------------- launch ----------------
extern "C" void kernel_launch(void* const* d_in, const int* in_sizes, int n_in,
                              void* d_out, int out_size, void* d_ws, size_t ws_size,
                              hipStream_t stream) {
    (void)in_sizes; (void)n_in; (void)out_size; (void)ws_size;
    const float* nf  = (const float*)d_in[0];
    const float* dt  = (const float*)d_in[1];
    const float* pos = (const float*)d_in[2];
    const float* msk = (const float*)d_in[3];
    const float* yyw = (const float*)d_in[4];
    const float* yyb = (const float*)d_in[5];
    const float* p1w = (const float*)d_in[6];
    const float* p1b = (const float*)d_in[7];
    const float* p2w = (const float*)d_in[8];
    const float* p2b = (const float*)d_in[9];
    const float* lxw = (const float*)d_in[10];
    const float* lxb = (const float*)d_in[11];
    const float* cw  = (const float*)d_in[12];
    const float* cb  = (const float*)d_in[13];
    const float* l1g = (const float*)d_in[14];
    const float* l1b = (const float*)d_in[15];
    const float* qw  = (const float*)d_in[16];
    const float* kw  = (const float*)d_in[17];
    const float* vw  = (const float*)d_in[18];
    const float* aow = (const float*)d_in[19];
    const float* aob = (const float*)d_in[20];
    const float* l2g = (const float*)d_in[21];
    const float* l2b = (const float*)d_in[22];
    const float* f1w = (const float*)d_in[23];
    const float* f1b = (const float*)d_in[24];
    const float* f2w = (const float*)d_in[25];
    const float* f2b_ = (const float*)d_in[26];
    const float* hpw = (const float*)d_in[27];
    const float* hpb = (const float*)d_in[28];

    float* ws = (float*)d_ws;
    unsigned short* catA_u  = (unsigned short*)(ws + OFF_R0);
    unsigned short* hb_u    = (unsigned short*)(ws + OFF_R0);
    float*          caw     = ws + OFF_CAW;
    unsigned short* kb_u    = (unsigned short*)(ws + OFF_R1);
    unsigned short* qb_u    = (unsigned short*)(ws + OFF_R1);
    unsigned short* mid_u   = (unsigned short*)(ws + OFF_R1);   // [16384][2048] bf16 spans R1+R2
    unsigned short* vb_u    = (unsigned short*)(ws + OFF_R2);
    unsigned short* cawT_u  = (unsigned short*)(ws + OFF_R2);
    unsigned short* catWT_u = (unsigned short*)(ws + OFF_CATWT);
    unsigned short* kvT_u   = (unsigned short*)(ws + OFF_KVT);
    unsigned short* qwT_u   = (unsigned short*)(ws + OFF_QWT);
    unsigned short* f1wT_u  = (unsigned short*)(ws + OFF_F1WT);
    unsigned short* f2wT_u  = (unsigned short*)(ws + OFF_F2WT);
    unsigned short* lxwb_u  = (unsigned short*)(ws + OFF_LXWB);
    unsigned short* cw0T_u  = (unsigned short*)(ws + OFF_CW0T);
    float* yv   = ws + OFF_Y;
    float* bbf  = ws + OFF_BB;
    float* pm   = ws + OFF_PM;
    float* ps2  = ws + OFF_PS;
    float* Mst  = ws + OFF_M;
    float* Sinv = ws + OFF_SINV;
    float* ctx  = ws + OFF_CTX;

    float* xout = (float*)d_out;
    float* yout = xout + (size_t)ROWS * DIMC;
    float* pout = yout + NB * DT;

    // allow dynamic LDS for gemm256 (capture-safe: replay-validated r11-r13)
    hipFuncSetAttribute(reinterpret_cast<const void*>(&gemm256<1, 2>),
                        hipFuncAttributeMaxDynamicSharedMemorySize, 131072);
    hipFuncSetAttribute(reinterpret_cast<const void*>(&gemm256<2, 2>),
                        hipFuncAttributeMaxDynamicSharedMemorySize, 131072);
    hipFuncSetAttribute(reinterpret_cast<const void*>(&gemm256<3, 2>),
                        hipFuncAttributeMaxDynamicSharedMemorySize, 131072);
    hipFuncSetAttribute(reinterpret_cast<const void*>(&gemm256<6, 2>),
                        hipFuncAttributeMaxDynamicSharedMemorySize, 131072);
    hipFuncSetAttribute(reinterpret_cast<const void*>(&gemm256<7, 2>),
                        hipFuncAttributeMaxDynamicSharedMemorySize, 131072);
    hipFuncSetAttribute(reinterpret_cast<const void*>(&gemm256<2, 1>),
                        hipFuncAttributeMaxDynamicSharedMemorySize, 98304);

    // prologue scalars + weight conversions
    y_kernel<<<4, 128, 0, stream>>>(dt, yyw, yyb, yv, yout);
    bb_kernel<<<8, 256, 0, stream>>>(lxb, cw, cb, yv, bbf);
    conv_bf16<<<128, 256, 0, stream>>>(lxw, lxwb_u, 32768);
    transconv<<<dim3(16, 16), 256, 0, stream>>>(cw, cw0T_u, 512, 512, 512);
    transconv<<<dim3(16, 2), 256, 0, stream>>>(cw + (size_t)DIMC * DIMC, catWT_u + 512, 64, 512, KCATP);
    zcat_kernel<<<128, 256, 0, stream>>>(catWT_u);
    transconv<<<dim3(16, 16), 256, 0, stream>>>(kw, kvT_u, 512, 512, 512);
    transconv<<<dim3(16, 16), 256, 0, stream>>>(vw, kvT_u + (size_t)512 * 512, 512, 512, 512);
    transconv<<<dim3(16, 16), 256, 0, stream>>>(qw, qwT_u, 512, 512, 512);
    transconv<<<dim3(64, 16), 256, 0, stream>>>(f1w, f1wT_u, 512, 2048, 512);
    transconv<<<dim3(16, 64), 256, 0, stream>>>(f2w, f2wT_u, 2048, 512, 2048);
    conv_bf16_strided<<<8192, 256, 0, stream>>>(nf, catA_u, KCATP);
    delta_kernel<<<8192, 256, 0, stream>>>(pos, msk, p1w, p1b, p2w, p2b, catA_u);

    // catWT cols 0..511 = (lxw @ cw0)^T
    gemm_mfma<5><<<dim3(4, 4), 256, 0, stream>>>(
        lxwb_u, 512, cw0T_u, 512, catWT_u, 512, 512, 512, KCATP);

    // cat = catA @ catWT^T + bb[batch] -> xout (f32)
    gemm256<3, 2><<<dim3(2, 128), 512, 131072, stream>>>(
        catA_u, KCATP, catWT_u, KCATP, nullptr, bbf, NN,
        xout, nullptr, ROWS, 512, KCATP, 0, 0);

    // LN1: xout -> hb
    ln_kernel<<<ROWS, 128, 0, stream>>>(xout, hb_u, l1g, l1b);

    // fused k+v projection (N=1024, split store)
    gemm256<6, 2><<<dim3(4, 128), 512, 131072, stream>>>(
        hb_u, 512, kvT_u, 512, nullptr, nullptr, 0,
        kb_u, vb_u, ROWS, 1024, 512, 0, 0);

    // k sequence-softmax stats
    ksm_stats1<<<dim3(64, 4), 256, 0, stream>>>(kb_u, pm, ps2);
    ksm_stats2<<<8, 256, 0, stream>>>(pm, ps2, Mst, Sinv);

    // context (consumes kb, vb)
    hipMemsetAsync(ctx, 0, (size_t)NB * HEADS * 64 * 64 * sizeof(float), stream);
    context_kernel<<<dim3(16, HEADS, NB), 256, 0, stream>>>(kb_u, vb_u, Mst, Sinv, ctx);

    // q projection + fused feature-softmax epilogue -> qb (R1; kb dead)
    gemm256<7, 2><<<dim3(2, 128), 512, 131072, stream>>>(
        hb_u, 512, qwT_u, 512, nullptr, nullptr, 0,
        qb_u, nullptr, ROWS, 512, 512, 0, 0);

    // compose ctx with attn_out_w per batch; transpose into R2 (vb dead)
    caw_kernel<<<dim3(8, 8, 4), 256, 0, stream>>>(ctx, aow, caw);
    for (int b = 0; b < NB; ++b)
        transconv<<<dim3(16, 16), 256, 0, stream>>>(caw + (size_t)b * 262144,
                                                    cawT_u + (size_t)b * 262144, 512, 512, 512);

    // x += qsm @ caw[b]^T + aob
    gemm256<2, 2><<<dim3(2, 128), 512, 131072, stream>>>(
        qb_u, 512, cawT_u, 512, aob, nullptr, 0,
        xout, nullptr, ROWS, 512, 512, 262144, NN);

    // FF block: LN2 then per-2-batch {ff1 N=2048 -> mid(R1+R2); ff2 MH=1, 256 blocks}
    ln_kernel<<<ROWS, 128, 0, stream>>>(xout, hb_u, l2g, l2b);
    for (int bp = 0; bp < 2; ++bp) {
        const unsigned short* hbp = hb_u + (size_t)bp * 16384 * DIMC;
        gemm256<1, 2><<<dim3(8, 64), 512, 131072, stream>>>(
            hbp, 512, f1wT_u, 512, f1b, nullptr, 0,
            mid_u, nullptr, 16384, FF, 512, 0, 0);
        gemm256<2, 1><<<dim3(2, 128), 512, 98304, stream>>>(
            mid_u, 2048, f2wT_u, 2048, f2b_, nullptr, 0,
            xout + (size_t)bp * 16384 * DIMC, nullptr, 16384, 512, 2048, 0, 0);
    }

    pos_kernel<<<8192, 256, 0, stream>>>(xout, hpw, hpb, pout);
}

// Round 15
// 665.151 us; speedup vs baseline: 1.4257x; 1.0539x over previous
//
#include <hip/hip_runtime.h>
#include <hip/hip_bf16.h>
#include <math.h>

// ---------------- constants ----------------
#define NB 4
#define NN 8192
#define ROWS (NB*NN)          // 32768
#define DIMC 512
#define HEADS 8
#define DT 128
#define DELTA 64
#define FF 2048
#define KCATP 640             // 576 padded to 640; pad cols zeroed on BOTH A and B sides every call

// ---------------- workspace layout (FLOAT units) ----------------
#define OFF_R0     ((size_t)0)          // catA [32768][640]bf16 -> hb [32768][512]bf16
#define OFF_CAW    ((size_t)8388608)    // caw f32 [4][512][512] (tail slack past hb)
#define OFF_R1     ((size_t)10485760)   // kb -> qb -> mid(lo)   [R1:8,388,608 f]
#define OFF_R2     ((size_t)18874368)   // vb -> cawT -> mid(hi) [R2:8,388,608 f]
                                        // mid = [16384][2048]bf16 spans R1+R2 exactly
#define OFF_CATWT  ((size_t)27262976)   // bf16 [512][640]
#define OFF_KVT    ((size_t)27426816)   // bf16 [1024][512]
#define OFF_QWT    ((size_t)27688960)   // bf16 [512][512]
#define OFF_F1WT   ((size_t)27820032)   // bf16 [2048][512]
#define OFF_F2WT   ((size_t)28344320)   // bf16 [512][2048]
#define OFF_LXWB   ((size_t)28868608)   // bf16 [512][512]
#define OFF_CW0T   ((size_t)28999680)   // bf16 [512][512]
#define OFF_Y      ((size_t)29130752)
#define OFF_BB     ((size_t)29131264)
#define OFF_PM     ((size_t)29133312)
#define OFF_PS     ((size_t)29264384)
#define OFF_M      ((size_t)29395456)
#define OFF_SINV   ((size_t)29397504)
#define OFF_CTX    ((size_t)29399552)
// end = 29,530,624 floats = 118.1 MB

typedef __attribute__((ext_vector_type(8))) short bf16x8;
typedef __attribute__((ext_vector_type(4))) float f32x4;
typedef __attribute__((ext_vector_type(8))) unsigned short us8;

static __device__ __forceinline__ unsigned short f2b(float x) {
    __hip_bfloat16 h = __float2bfloat16(x);
    return __builtin_bit_cast(unsigned short, h);
}
static __device__ __forceinline__ float b2f(unsigned short u) {
    return __bfloat162float(__builtin_bit_cast(__hip_bfloat16, u));
}
// gelu(tanh approx) = 0.5x(1+tanh(z)) = x - x/(e^{2z}+1); overflow-safe:
// t=exp(2z)->inf => x - 0 = x;  t->0 => x - x = 0.  Single v_exp_f32 vs libm tanhf.
static __device__ __forceinline__ float gelu_tanh(float x) {
    float z2 = 1.5957691216057308f * (x + 0.044715f * x * x * x);  // 2*0.79788456*(...)
    float t = __expf(z2);
    return x - x / (t + 1.0f);
}

#define GLOAD16(g, l) __builtin_amdgcn_global_load_lds( \
    (const __attribute__((address_space(1))) void*)(g), \
    (__attribute__((address_space(3))) void*)(l), 16, 0, 0)

// ---------------- tiny prologue kernels ----------------
__global__ void y_kernel(const float* __restrict__ dt, const float* __restrict__ yyw,
                         const float* __restrict__ yyb, float* __restrict__ y_ws,
                         float* __restrict__ y_out) {
    int idx = blockIdx.x * 128 + threadIdx.x;   // 512
    int b = idx >> 7, j = idx & 127;
    float acc = yyb[j];
    for (int c = 0; c < DT; ++c) acc += dt[b * DT + c] * yyw[c * DT + j];
    y_ws[idx] = acc;
    y_out[idx] = acc;
}

__global__ void bb_kernel(const float* __restrict__ linxb, const float* __restrict__ catw,
                          const float* __restrict__ catb, const float* __restrict__ y,
                          float* __restrict__ bb) {
    int idx = blockIdx.x * 256 + threadIdx.x;   // 2048
    int b = idx >> 9, n = idx & 511;
    float acc = catb[n];
    for (int c = 0; c < DIMC; ++c) acc += linxb[c] * catw[(size_t)c * DIMC + n];
    const float* cw3 = catw + (size_t)(DIMC + DELTA) * DIMC;
    for (int j = 0; j < DT; ++j) acc += y[b * DT + j] * cw3[(size_t)j * DIMC + n];
    bb[idx] = acc;
}

// delta -> catA columns 512..575; ALSO zero pad cols 576..639 (replay safety)
__global__ __launch_bounds__(256) void delta_kernel(
    const float* __restrict__ pos, const float* __restrict__ mask,
    const float* __restrict__ w1, const float* __restrict__ b1,
    const float* __restrict__ w2, const float* __restrict__ b2,
    unsigned short* __restrict__ catA) {
    int lane = threadIdx.x & 63;
    size_t row = (size_t)blockIdx.x * 4 + (threadIdx.x >> 6);
    float mk = mask[row];
    float px = pos[row * 2] * mk, py = pos[row * 2 + 1] * mk;
    float nrm = sqrtf(px * px + py * py) + 1e-7f;
    float ux = px / nrm, uy = py / nrm;
    float t1 = fmaxf(ux * w1[lane] + uy * w1[64 + lane] + b1[lane], 0.0f);
    float acc = b2[lane];
    #pragma unroll
    for (int j = 0; j < 64; ++j) {
        float tv = __shfl(t1, j, 64);
        acc += tv * w2[j * 64 + lane];
    }
    catA[row * KCATP + DIMC + lane] = f2b(acc);
    catA[row * KCATP + 576 + lane] = 0;
}

// zero catWT pad cols 576..639 (B side)
__global__ void zcat_kernel(unsigned short* __restrict__ catWT) {
    int idx = blockIdx.x * 256 + threadIdx.x;   // 32768
    int n = idx >> 6, c = 576 + (idx & 63);
    catWT[(size_t)n * KCATP + c] = 0;
}

// f32 -> bf16 flat convert
__global__ void conv_bf16(const float* __restrict__ in, unsigned short* __restrict__ out, int n8) {
    int i = blockIdx.x * 256 + threadIdx.x;
    if (i >= n8) return;
    const float* p = in + (size_t)i * 8;
    us8 o;
    #pragma unroll
    for (int j = 0; j < 8; ++j) o[j] = f2b(p[j]);
    *(us8*)(out + (size_t)i * 8) = o;
}

// f32 [rows][512] -> bf16 out[row*ldo + c]
__global__ void conv_bf16_strided(const float* __restrict__ in, unsigned short* __restrict__ out,
                                  int ldo) {
    int i = blockIdx.x * 256 + threadIdx.x;
    int row = i >> 6, c8 = (i & 63) * 8;
    const float* p = in + (size_t)row * DIMC + c8;
    us8 o;
    #pragma unroll
    for (int j = 0; j < 8; ++j) o[j] = f2b(p[j]);
    *(us8*)(out + (size_t)row * ldo + c8) = o;
}

// f32 [R][C] -> bf16 out[c*ldo + r]
__global__ __launch_bounds__(256) void transconv(const float* __restrict__ in,
                                                 unsigned short* __restrict__ out,
                                                 int R, int C, int ldo) {
    __shared__ float tile[32][33];
    int bx = blockIdx.x * 32;
    int by = blockIdx.y * 32;
    int tx = threadIdx.x & 31, ty = threadIdx.x >> 5;
    #pragma unroll
    for (int i = 0; i < 4; ++i) {
        int r = ty + i * 8;
        tile[r][tx] = in[(size_t)(by + r) * C + bx + tx];
    }
    __syncthreads();
    #pragma unroll
    for (int i = 0; i < 4; ++i) {
        int r = ty + i * 8;
        out[(size_t)(bx + r) * ldo + by + tx] = f2b(tile[tx][r]);
    }
}

// LayerNorm: f32 in -> bf16 out
__global__ __launch_bounds__(128) void ln_kernel(
    const float* __restrict__ src, unsigned short* __restrict__ dst,
    const float* __restrict__ g, const float* __restrict__ bta) {
    size_t row = blockIdx.x;
    int t = threadIdx.x;
    const float* s = src + row * DIMC;
    float4 x = *(const float4*)(s + t * 4);
    float sum = x.x + x.y + x.z + x.w;
    float sq = x.x * x.x + x.y * x.y + x.z * x.z + x.w * x.w;
    #pragma unroll
    for (int o = 32; o; o >>= 1) { sum += __shfl_down(sum, o, 64); sq += __shfl_down(sq, o, 64); }
    __shared__ float sh[4];
    if ((t & 63) == 0) { sh[(t >> 6) * 2] = sum; sh[(t >> 6) * 2 + 1] = sq; }
    __syncthreads();
    sum = sh[0] + sh[2]; sq = sh[1] + sh[3];
    float mean = sum * (1.0f / DIMC);
    float var = sq * (1.0f / DIMC) - mean * mean;
    float rstd = rsqrtf(fmaxf(var, 0.0f) + 1e-5f);
    float4 gv = *(const float4*)(g + t * 4);
    float4 bv = *(const float4*)(bta + t * 4);
    ushort4 ov;
    ov.x = f2b((x.x - mean) * rstd * gv.x + bv.x);
    ov.y = f2b((x.y - mean) * rstd * gv.y + bv.y);
    ov.z = f2b((x.z - mean) * rstd * gv.z + bv.z);
    ov.w = f2b((x.w - mean) * rstd * gv.w + bv.w);
    *(ushort4*)(dst + row * DIMC + t * 4) = ov;
}

// ================= 256-wide 8-phase counted-vmcnt MFMA GEMM =================
// C[M,N] = A[M,K] @ Bt[N,K], bf16. 512 threads = 8 waves, BN=256, BM=128*MH.
// MH=2: 4 phases/tile, vmcnt(4) [replay-proven r11-r14]; MH=1: 2 phases/tile, vmcnt(3).
// SWZ=1: XCD-chunked block remap (each XCD owns a contiguous by-chunk x all bx) --
//        keeps the shared A row-panel inside one per-XCD L2. Bijective for any grid
//        with (gridDim.x*gridDim.y)%8==0 and gridDim.y%8==0.
// EPI: 1 gelu->bf16; 2 f32 +=; 3 f32 +extra[batch]; 6 bf16 split store;
//      7 bf16 head-softmax (feature softmax over the wave's 64-col head) * DH^-0.5.
template <int EPI, int MH, int SWZ>
__global__ __launch_bounds__(512, 1) void gemm256(
    const unsigned short* __restrict__ A, int lda,
    const unsigned short* __restrict__ Bt, int ldb,
    const float* __restrict__ bias,
    const float* __restrict__ extra, int batch_rows,
    void* __restrict__ Cv, void* __restrict__ Cv2,
    int M, int N, int K,
    size_t b_stride, int rows_per_batch) {
    extern __shared__ char lds[];
    constexpr int AH = 8192 * MH;          // A half-tile bytes
    constexpr int SLOT = 2 * AH + 32768;   // per-buffer slot bytes
    const int tid = threadIdx.x;
    const int lane = tid & 63, wv = tid >> 6;
    const int wr = wv >> 2, wc = wv & 3;
    const int lr = lane & 15, lch = lane >> 4;

    int bxi = blockIdx.x, byi = blockIdx.y;
    if constexpr (SWZ) {
        int l = byi * gridDim.x + bxi;
        int xcd = l & 7, j = l >> 3;
        byi = xcd * (gridDim.y >> 3) + j / gridDim.x;
        bxi = j % gridDim.x;
    }
    const int bm = byi * (128 * MH), bn = bxi * 256;

    const unsigned short* Bb = Bt;
    if (rows_per_batch) Bb = Bt + (size_t)(bm / rows_per_batch) * b_stride;

    const int srow = tid >> 2;          // 0..127 (+128)
    const int schunk = tid & 3;

    auto stage_A = [&](int p, int ks, int kcol) {
        char* dst = lds + (size_t)p * SLOT + ks * AH;
        #pragma unroll
        for (int i = 0; i < MH; ++i) {
            int row = srow + 128 * i;
            int gc = schunk ^ ((row >> 1) & 3);
            GLOAD16((const char*)(A + (size_t)(bm + row) * lda + kcol) + gc * 16,
                    dst + (size_t)(tid + 512 * i) * 16);
        }
    };
    auto stage_B = [&](int p, int ks, int kcol) {
        char* dst = lds + (size_t)p * SLOT + 2 * AH + ks * 16384;
        #pragma unroll
        for (int i = 0; i < 2; ++i) {
            int row = srow + 128 * i;
            int gc = schunk ^ ((row >> 1) & 3);
            GLOAD16((const char*)(Bb + (size_t)(bn + row) * ldb + kcol) + gc * 16,
                    dst + (size_t)(tid + 512 * i) * 16);
        }
    };

    f32x4 acc[MH][4][4] = {};
    const int nt = K >> 6;

    stage_A(0, 0, 0);
    stage_B(0, 0, 0);
    stage_A(0, 1, 32);
    stage_B(0, 1, 32);
    __builtin_amdgcn_sched_barrier(0);
    if constexpr (MH == 2) asm volatile("s_waitcnt vmcnt(4)" ::: "memory");
    else                   asm volatile("s_waitcnt vmcnt(3)" ::: "memory");
    __builtin_amdgcn_sched_barrier(0);
    __builtin_amdgcn_s_barrier();

    for (int t = 0; t < nt; ++t) {
        const int p = t & 1;
        const bool pf = (t + 1 < nt);
        const int kc = (t + 1) << 6;
        if constexpr (MH == 2) {
            bf16x8 bfr[4], afr[4];
            #pragma unroll
            for (int ks = 0; ks < 2; ++ks) {
                #pragma unroll
                for (int mh = 0; mh < 2; ++mh) {
                    const int ph = ks * 2 + mh;
                    if (mh == 0) {
                        #pragma unroll
                        for (int n = 0; n < 4; ++n) {
                            int bc = wc * 64 + n * 16 + lr;
                            bfr[n] = *(const bf16x8*)(lds + (size_t)p * SLOT + 2 * AH + ks * 16384
                                     + bc * 64 + ((lch ^ ((bc >> 1) & 3)) << 4));
                        }
                    }
                    #pragma unroll
                    for (int m = 0; m < 4; ++m) {
                        int ar = wr * 128 + mh * 64 + m * 16 + lr;
                        afr[m] = *(const bf16x8*)(lds + (size_t)p * SLOT + ks * AH
                                 + ar * 64 + ((lch ^ ((ar >> 1) & 3)) << 4));
                    }
                    if (pf) {
                        if (ph == 0)      stage_A(p ^ 1, 0, kc);
                        else if (ph == 1) stage_B(p ^ 1, 0, kc);
                        else if (ph == 2) stage_A(p ^ 1, 1, kc + 32);
                        else              stage_B(p ^ 1, 1, kc + 32);
                    }
                    __builtin_amdgcn_sched_barrier(0);
                    __builtin_amdgcn_s_barrier();
                    asm volatile("s_waitcnt lgkmcnt(0)" ::: "memory");
                    __builtin_amdgcn_sched_barrier(0);
                    __builtin_amdgcn_s_setprio(1);
                    #pragma unroll
                    for (int m = 0; m < 4; ++m)
                        #pragma unroll
                        for (int n = 0; n < 4; ++n)
                            acc[mh][m][n] = __builtin_amdgcn_mfma_f32_16x16x32_bf16(
                                afr[m], bfr[n], acc[mh][m][n], 0, 0, 0);
                    __builtin_amdgcn_s_setprio(0);
                    if (ph == 1) {
                        if (pf) asm volatile("s_waitcnt vmcnt(4)" ::: "memory");
                        else    asm volatile("s_waitcnt vmcnt(0)" ::: "memory");
                        __builtin_amdgcn_sched_barrier(0);
                    } else if (ph == 3) {
                        if (pf) {
                            asm volatile("s_waitcnt vmcnt(4)" ::: "memory");
                            __builtin_amdgcn_sched_barrier(0);
                        }
                    }
                    __builtin_amdgcn_s_barrier();
                }
            }
        } else {  // MH == 1: 2 phases per tile
            #pragma unroll
            for (int ks = 0; ks < 2; ++ks) {
                bf16x8 bfr[4], afr[4];
                #pragma unroll
                for (int n = 0; n < 4; ++n) {
                    int bc = wc * 64 + n * 16 + lr;
                    bfr[n] = *(const bf16x8*)(lds + (size_t)p * SLOT + 2 * AH + ks * 16384
                             + bc * 64 + ((lch ^ ((bc >> 1) & 3)) << 4));
                }
                #pragma unroll
                for (int m = 0; m < 4; ++m) {
                    int ar = wr * 64 + m * 16 + lr;
                    afr[m] = *(const bf16x8*)(lds + (size_t)p * SLOT + ks * AH
                             + ar * 64 + ((lch ^ ((ar >> 1) & 3)) << 4));
                }
                if (pf) {
                    stage_A(p ^ 1, ks, kc + 32 * ks);
                    stage_B(p ^ 1, ks, kc + 32 * ks);
                }
                __builtin_amdgcn_sched_barrier(0);
                __builtin_amdgcn_s_barrier();
                asm volatile("s_waitcnt lgkmcnt(0)" ::: "memory");
                __builtin_amdgcn_sched_barrier(0);
                __builtin_amdgcn_s_setprio(1);
                #pragma unroll
                for (int m = 0; m < 4; ++m)
                    #pragma unroll
                    for (int n = 0; n < 4; ++n)
                        acc[0][m][n] = __builtin_amdgcn_mfma_f32_16x16x32_bf16(
                            afr[m], bfr[n], acc[0][m][n], 0, 0, 0);
                __builtin_amdgcn_s_setprio(0);
                if (ks == 0) {
                    if (pf) asm volatile("s_waitcnt vmcnt(3)" ::: "memory");
                    else    asm volatile("s_waitcnt vmcnt(0)" ::: "memory");
                    __builtin_amdgcn_sched_barrier(0);
                } else {
                    if (pf) {
                        asm volatile("s_waitcnt vmcnt(3)" ::: "memory");
                        __builtin_amdgcn_sched_barrier(0);
                    }
                }
                __builtin_amdgcn_s_barrier();
            }
        }
    }

    const int g4 = lch * 4;
    if constexpr (EPI == 7) {
        #pragma unroll
        for (int mh = 0; mh < MH; ++mh)
            #pragma unroll
            for (int m = 0; m < 4; ++m)
                #pragma unroll
                for (int r = 0; r < 4; ++r) {
                    float v0 = acc[mh][m][0][r], v1 = acc[mh][m][1][r];
                    float v2 = acc[mh][m][2][r], v3 = acc[mh][m][3][r];
                    float mx = fmaxf(fmaxf(v0, v1), fmaxf(v2, v3));
                    #pragma unroll
                    for (int o = 1; o < 16; o <<= 1) mx = fmaxf(mx, __shfl_xor(mx, o, 64));
                    float e0 = __expf(v0 - mx), e1 = __expf(v1 - mx);
                    float e2 = __expf(v2 - mx), e3 = __expf(v3 - mx);
                    float s = e0 + e1 + e2 + e3;
                    #pragma unroll
                    for (int o = 1; o < 16; o <<= 1) s += __shfl_xor(s, o, 64);
                    float sc = 0.125f / s;
                    int rr = bm + wr * (64 * MH) + mh * 64 + m * 16 + g4 + r;
                    unsigned short* dst = (unsigned short*)Cv + (size_t)rr * N + bn + wc * 64 + lr;
                    dst[0]  = f2b(e0 * sc);
                    dst[16] = f2b(e1 * sc);
                    dst[32] = f2b(e2 * sc);
                    dst[48] = f2b(e3 * sc);
                }
    } else {
        #pragma unroll
        for (int mh = 0; mh < MH; ++mh)
            #pragma unroll
            for (int m = 0; m < 4; ++m)
                #pragma unroll
                for (int n = 0; n < 4; ++n) {
                    int col = bn + wc * 64 + n * 16 + lr;
                    #pragma unroll
                    for (int r = 0; r < 4; ++r) {
                        int rr = bm + wr * (64 * MH) + mh * 64 + m * 16 + g4 + r;
                        float v = acc[mh][m][n][r];
                        if (EPI == 1) {
                            ((unsigned short*)Cv)[(size_t)rr * N + col] = f2b(gelu_tanh(v + bias[col]));
                        } else if (EPI == 2) {
                            ((float*)Cv)[(size_t)rr * N + col] += v + bias[col];
                        } else if (EPI == 3) {
                            ((float*)Cv)[(size_t)rr * N + col] = v + extra[(size_t)(rr / batch_rows) * N + col];
                        } else if (EPI == 6) {
                            unsigned short* dst = (col >> 9) ? (unsigned short*)Cv2 : (unsigned short*)Cv;
                            dst[(size_t)rr * 512 + (col & 511)] = f2b(v);
                        }
                    }
                }
    }
}

// ---------------- legacy 128x128 MFMA GEMM (tiny wcomp only) ----------------
#define BM 128
#define BN 128
#define BK 64

template <int EPI>
__global__ __launch_bounds__(256) void gemm_mfma(
    const unsigned short* __restrict__ A, int lda,
    const unsigned short* __restrict__ Bt, int ldb,
    void* __restrict__ Cv, int M, int N, int K, int ldo) {
    __shared__ unsigned short As[2][BM * BK];
    __shared__ unsigned short Bs[2][BN * BK];
    int bm = blockIdx.y * BM, bn = blockIdx.x * BN;
    int tid = threadIdx.x;
    int lane = tid & 63, wv = tid >> 6;
    int wr = (wv >> 1) * 64, wc = (wv & 1) * 64;
    int g16 = (lane >> 4) << 4;
    int lr = lane & 15;
    int sw = (lr & 7) << 4;

    int srow = tid >> 3;
    int skb = (tid & 7) * 16;
    int sxor = skb ^ ((srow & 7) << 4);

    auto stage = [&](int buf, int k0) {
        #pragma unroll
        for (int i = 0; i < 4; ++i) {
            int row = srow + 32 * i;
            GLOAD16((const char*)(A + (size_t)(bm + row) * lda + k0) + sxor,
                    (char*)As[buf] + (size_t)(tid + 256 * i) * 16);
        }
        #pragma unroll
        for (int i = 0; i < 4; ++i) {
            int row = srow + 32 * i;
            GLOAD16((const char*)(Bt + (size_t)(bn + row) * ldb + k0) + sxor,
                    (char*)Bs[buf] + (size_t)(tid + 256 * i) * 16);
        }
    };

    f32x4 acc[4][4] = {};
    int nt = K / BK;
    stage(0, 0);
    __syncthreads();
    for (int t = 0; t < nt; ++t) {
        int cur = t & 1;
        if (t + 1 < nt) stage(cur ^ 1, (t + 1) * BK);
        const char* Ab = (const char*)As[cur];
        const char* Bp = (const char*)Bs[cur];
        #pragma unroll
        for (int s = 0; s < 2; ++s) {
            int koff = s * 64 + g16;
            bf16x8 af[4], bw[4];
            #pragma unroll
            for (int f = 0; f < 4; ++f) {
                int ar = wr + f * 16 + lr;
                af[f] = *(const bf16x8*)(Ab + ar * 128 + (koff ^ sw));
                int br = wc + f * 16 + lr;
                bw[f] = *(const bf16x8*)(Bp + br * 128 + (koff ^ sw));
            }
            #pragma unroll
            for (int f = 0; f < 4; ++f)
                #pragma unroll
                for (int j = 0; j < 4; ++j)
                    acc[f][j] = __builtin_amdgcn_mfma_f32_16x16x32_bf16(
                        af[f], bw[j], acc[f][j], 0, 0, 0);
        }
        __syncthreads();
    }

    int g4 = (lane >> 4) * 4;
    #pragma unroll
    for (int f = 0; f < 4; ++f) {
        #pragma unroll
        for (int j = 0; j < 4; ++j) {
            int col = bn + wc + j * 16 + lr;
            #pragma unroll
            for (int r = 0; r < 4; ++r) {
                int rr = bm + wr + f * 16 + g4 + r;
                float v = acc[f][j][r];
                if (EPI == 4) {
                    ((unsigned short*)Cv)[(size_t)rr * N + col] = f2b(v);
                } else if (EPI == 5) {
                    ((unsigned short*)Cv)[(size_t)col * ldo + rr] = f2b(v);
                }
            }
        }
    }
}

// ---------------- k column-softmax stats ----------------
__global__ __launch_bounds__(256) void ksm_stats1(
    const unsigned short* __restrict__ k, float* __restrict__ pm, float* __restrict__ ps) {
    int b = blockIdx.y, rb = blockIdx.x;
    const unsigned short* kp = k + ((size_t)b * NN + (size_t)rb * 128) * DIMC;
    int t = threadIdx.x;
    float m0 = -1e30f, s0 = 0.f, m1 = -1e30f, s1 = 0.f;
    for (int r = 0; r < 128; ++r) {
        float x0 = b2f(kp[(size_t)r * DIMC + t]);
        float x1 = b2f(kp[(size_t)r * DIMC + t + 256]);
        if (x0 > m0) { s0 = s0 * __expf(m0 - x0) + 1.f; m0 = x0; } else s0 += __expf(x0 - m0);
        if (x1 > m1) { s1 = s1 * __expf(m1 - x1) + 1.f; m1 = x1; } else s1 += __expf(x1 - m1);
    }
    size_t base = ((size_t)b * 64 + rb) * DIMC;
    pm[base + t] = m0; pm[base + t + 256] = m1;
    ps[base + t] = s0; ps[base + t + 256] = s1;
}

__global__ void ksm_stats2(const float* __restrict__ pm, const float* __restrict__ ps,
                           float* __restrict__ Mst, float* __restrict__ Sinv) {
    int idx = blockIdx.x * 256 + threadIdx.x;
    int b = idx >> 9, c = idx & 511;
    float m = -1e30f, s = 0.f;
    for (int rb = 0; rb < 64; ++rb) {
        float mm = pm[((size_t)b * 64 + rb) * DIMC + c];
        float ss = ps[((size_t)b * 64 + rb) * DIMC + c];
        if (mm > m) { s = s * __expf(m - mm) + ss; m = mm; } else s += ss * __expf(mm - m);
    }
    Mst[idx] = m;
    Sinv[idx] = 1.f / s;
}

// ---------------- context = sum_n expk[n,d] * v[n,e] (LDS version, ~62us) ----------------
__global__ __launch_bounds__(256) void context_kernel(
    const unsigned short* __restrict__ kb, const unsigned short* __restrict__ vb,
    const float* __restrict__ Mst, const float* __restrict__ Sinv,
    float* __restrict__ ctx) {
    int b = blockIdx.z, hd = blockIdx.y, rb = blockIdx.x;
    int tid = threadIdx.x, tx = tid & 15, ty = tid >> 4;
    __shared__ float kx[64][68];
    __shared__ float vx[64][68];
    int r0t = tid >> 3;
    int c8 = (tid & 7) * 8;
    int cb = hd * 64 + c8;
    float mv[8], sv[8];
    #pragma unroll
    for (int j = 0; j < 8; ++j) { mv[j] = Mst[b * DIMC + cb + j]; sv[j] = Sinv[b * DIMC + cb + j]; }
    float cacc[4][4] = {};
    for (int sub = 0; sub < 8; ++sub) {
        size_t row0 = (size_t)b * NN + (size_t)rb * 512 + sub * 64;
        #pragma unroll
        for (int i = 0; i < 2; ++i) {
            int r = r0t + i * 32;
            us8 kv = *(const us8*)(kb + (row0 + r) * DIMC + cb);
            us8 vv = *(const us8*)(vb + (row0 + r) * DIMC + cb);
            #pragma unroll
            for (int j = 0; j < 8; ++j) {
                kx[r][c8 + j] = __expf(b2f(kv[j]) - mv[j]) * sv[j];
                vx[r][c8 + j] = b2f(vv[j]);
            }
        }
        __syncthreads();
        #pragma unroll 4
        for (int r = 0; r < 64; ++r) {
            float4 a4 = *(const float4*)&kx[r][ty * 4];
            float4 b4 = *(const float4*)&vx[r][tx * 4];
            float av[4] = {a4.x, a4.y, a4.z, a4.w};
            float bv[4] = {b4.x, b4.y, b4.z, b4.w};
            #pragma unroll
            for (int i = 0; i < 4; ++i)
                #pragma unroll
                for (int j = 0; j < 4; ++j)
                    cacc[i][j] = fmaf(av[i], bv[j], cacc[i][j]);
        }
        __syncthreads();
    }
    size_t cbase = (size_t)(b * HEADS + hd) * 64 * 64;
    #pragma unroll
    for (int i = 0; i < 4; ++i)
        #pragma unroll
        for (int j = 0; j < 4; ++j)
            atomicAdd(&ctx[cbase + (size_t)(ty * 4 + i) * 64 + tx * 4 + j], cacc[i][j]);
}

// ---------------- caw = ctx @ aow (per batch) ----------------
__global__ __launch_bounds__(256) void caw_kernel(const float* __restrict__ ctx,
                                                  const float* __restrict__ aow,
                                                  float* __restrict__ caw) {
    int nt = blockIdx.x, hd = blockIdx.y, b = blockIdx.z;
    int tid = threadIdx.x, tx = tid & 15, ty = tid >> 4;
    __shared__ float cs[64][68];
    __shared__ float aw[64][68];
    #pragma unroll
    for (int i = 0; i < 4; ++i) {
        int idx = tid + 256 * i;
        int r = idx >> 4, c4 = (idx & 15) * 4;
        *(float4*)&cs[r][c4] = *(const float4*)(ctx + ((size_t)(b * HEADS + hd) * 64 + r) * 64 + c4);
        *(float4*)&aw[r][c4] = *(const float4*)(aow + (size_t)(hd * 64 + r) * DIMC + nt * 64 + c4);
    }
    __syncthreads();
    float acc[4][4] = {};
    for (int e = 0; e < 64; ++e) {
        float av[4];
        #pragma unroll
        for (int i = 0; i < 4; ++i) av[i] = cs[ty * 4 + i][e];
        float4 b4 = *(const float4*)&aw[e][tx * 4];
        float bv[4] = {b4.x, b4.y, b4.z, b4.w};
        #pragma unroll
        for (int i = 0; i < 4; ++i)
            #pragma unroll
            for (int j = 0; j < 4; ++j)
                acc[i][j] = fmaf(av[i], bv[j], acc[i][j]);
    }
    #pragma unroll
    for (int i = 0; i < 4; ++i)
        #pragma unroll
        for (int j = 0; j < 4; ++j)
            caw[(size_t)b * DIMC * DIMC + (size_t)(hd * 64 + ty * 4 + i) * DIMC + nt * 64 + tx * 4 + j]
                = acc[i][j];
}

// ---------------- pos head ----------------
__global__ __launch_bounds__(256) void pos_kernel(
    const float* __restrict__ x, const float* __restrict__ w,
    const float* __restrict__ b2, float* __restrict__ out) {
    int lane = threadIdx.x & 63;
    size_t row = (size_t)blockIdx.x * 4 + (threadIdx.x >> 6);
    const float* xp = x + row * DIMC;
    float acc0 = 0.f, acc1 = 0.f;
    #pragma unroll
    for (int i = 0; i < 2; ++i) {
        float4 xv = *(const float4*)(xp + lane * 8 + i * 4);
        const float* wp = w + (size_t)(lane * 8 + i * 4) * 2;
        float4 w0 = *(const float4*)(wp);
        float4 w1 = *(const float4*)(wp + 4);
        acc0 += xv.x * w0.x + xv.y * w0.z + xv.z * w1.x + xv.w * w1.z;
        acc1 += xv.x * w0.y + xv.y * w0.w + xv.z * w1.y + xv.w * w1.w;
    }
    #pragma unroll
    for (int o = 32; o; o >>= 1) { acc0 += __shfl_down(acc0, o, 64); acc1 += __shfl_down(acc1, o, 64); }
    if (lane == 0) {
        out[row * 2] = acc0 + b2[0];
        out[row * 2 + 1] = acc1 + b2[1];
    }
}

// ---------------- launch ----------------
extern "C" void kernel_launch(void* const* d_in, const int* in_sizes, int n_in,
                              void* d_out, int out_size, void* d_ws, size_t ws_size,
                              hipStream_t stream) {
    (void)in_sizes; (void)n_in; (void)out_size; (void)ws_size;
    const float* nf  = (const float*)d_in[0];
    const float* dt  = (const float*)d_in[1];
    const float* pos = (const float*)d_in[2];
    const float* msk = (const float*)d_in[3];
    const float* yyw = (const float*)d_in[4];
    const float* yyb = (const float*)d_in[5];
    const float* p1w = (const float*)d_in[6];
    const float* p1b = (const float*)d_in[7];
    const float* p2w = (const float*)d_in[8];
    const float* p2b = (const float*)d_in[9];
    const float* lxw = (const float*)d_in[10];
    const float* lxb = (const float*)d_in[11];
    const float* cw  = (const float*)d_in[12];
    const float* cb  = (const float*)d_in[13];
    const float* l1g = (const float*)d_in[14];
    const float* l1b = (const float*)d_in[15];
    const float* qw  = (const float*)d_in[16];
    const float* kw  = (const float*)d_in[17];
    const float* vw  = (const float*)d_in[18];
    const float* aow = (const float*)d_in[19];
    const float* aob = (const float*)d_in[20];
    const float* l2g = (const float*)d_in[21];
    const float* l2b = (const float*)d_in[22];
    const float* f1w = (const float*)d_in[23];
    const float* f1b = (const float*)d_in[24];
    const float* f2w = (const float*)d_in[25];
    const float* f2b_ = (const float*)d_in[26];
    const float* hpw = (const float*)d_in[27];
    const float* hpb = (const float*)d_in[28];

    float* ws = (float*)d_ws;
    unsigned short* catA_u  = (unsigned short*)(ws + OFF_R0);
    unsigned short* hb_u    = (unsigned short*)(ws + OFF_R0);
    float*          caw     = ws + OFF_CAW;
    unsigned short* kb_u    = (unsigned short*)(ws + OFF_R1);
    unsigned short* qb_u    = (unsigned short*)(ws + OFF_R1);
    unsigned short* mid_u   = (unsigned short*)(ws + OFF_R1);   // [16384][2048] bf16 spans R1+R2
    unsigned short* vb_u    = (unsigned short*)(ws + OFF_R2);
    unsigned short* cawT_u  = (unsigned short*)(ws + OFF_R2);
    unsigned short* catWT_u = (unsigned short*)(ws + OFF_CATWT);
    unsigned short* kvT_u   = (unsigned short*)(ws + OFF_KVT);
    unsigned short* qwT_u   = (unsigned short*)(ws + OFF_QWT);
    unsigned short* f1wT_u  = (unsigned short*)(ws + OFF_F1WT);
    unsigned short* f2wT_u  = (unsigned short*)(ws + OFF_F2WT);
    unsigned short* lxwb_u  = (unsigned short*)(ws + OFF_LXWB);
    unsigned short* cw0T_u  = (unsigned short*)(ws + OFF_CW0T);
    float* yv   = ws + OFF_Y;
    float* bbf  = ws + OFF_BB;
    float* pm   = ws + OFF_PM;
    float* ps2  = ws + OFF_PS;
    float* Mst  = ws + OFF_M;
    float* Sinv = ws + OFF_SINV;
    float* ctx  = ws + OFF_CTX;

    float* xout = (float*)d_out;
    float* yout = xout + (size_t)ROWS * DIMC;
    float* pout = yout + NB * DT;

    // allow dynamic LDS for gemm256 (capture-safe: replay-validated r11-r14)
    hipFuncSetAttribute(reinterpret_cast<const void*>(&gemm256<1, 2, 1>),
                        hipFuncAttributeMaxDynamicSharedMemorySize, 131072);
    hipFuncSetAttribute(reinterpret_cast<const void*>(&gemm256<2, 2, 0>),
                        hipFuncAttributeMaxDynamicSharedMemorySize, 131072);
    hipFuncSetAttribute(reinterpret_cast<const void*>(&gemm256<3, 2, 0>),
                        hipFuncAttributeMaxDynamicSharedMemorySize, 131072);
    hipFuncSetAttribute(reinterpret_cast<const void*>(&gemm256<6, 2, 0>),
                        hipFuncAttributeMaxDynamicSharedMemorySize, 131072);
    hipFuncSetAttribute(reinterpret_cast<const void*>(&gemm256<7, 2, 0>),
                        hipFuncAttributeMaxDynamicSharedMemorySize, 131072);
    hipFuncSetAttribute(reinterpret_cast<const void*>(&gemm256<2, 1, 0>),
                        hipFuncAttributeMaxDynamicSharedMemorySize, 98304);

    // prologue scalars + weight conversions
    y_kernel<<<4, 128, 0, stream>>>(dt, yyw, yyb, yv, yout);
    bb_kernel<<<8, 256, 0, stream>>>(lxb, cw, cb, yv, bbf);
    conv_bf16<<<128, 256, 0, stream>>>(lxw, lxwb_u, 32768);
    transconv<<<dim3(16, 16), 256, 0, stream>>>(cw, cw0T_u, 512, 512, 512);
    transconv<<<dim3(16, 2), 256, 0, stream>>>(cw + (size_t)DIMC * DIMC, catWT_u + 512, 64, 512, KCATP);
    zcat_kernel<<<128, 256, 0, stream>>>(catWT_u);
    transconv<<<dim3(16, 16), 256, 0, stream>>>(kw, kvT_u, 512, 512, 512);
    transconv<<<dim3(16, 16), 256, 0, stream>>>(vw, kvT_u + (size_t)512 * 512, 512, 512, 512);
    transconv<<<dim3(16, 16), 256, 0, stream>>>(qw, qwT_u, 512, 512, 512);
    transconv<<<dim3(64, 16), 256, 0, stream>>>(f1w, f1wT_u, 512, 2048, 512);
    transconv<<<dim3(16, 64), 256, 0, stream>>>(f2w, f2wT_u, 2048, 512, 2048);
    conv_bf16_strided<<<8192, 256, 0, stream>>>(nf, catA_u, KCATP);
    delta_kernel<<<8192, 256, 0, stream>>>(pos, msk, p1w, p1b, p2w, p2b, catA_u);

    // catWT cols 0..511 = (lxw @ cw0)^T
    gemm_mfma<5><<<dim3(4, 4), 256, 0, stream>>>(
        lxwb_u, 512, cw0T_u, 512, catWT_u, 512, 512, 512, KCATP);

    // cat = catA @ catWT^T + bb[batch] -> xout (f32)
    gemm256<3, 2, 0><<<dim3(2, 128), 512, 131072, stream>>>(
        catA_u, KCATP, catWT_u, KCATP, nullptr, bbf, NN,
        xout, nullptr, ROWS, 512, KCATP, 0, 0);

    // LN1: xout -> hb
    ln_kernel<<<ROWS, 128, 0, stream>>>(xout, hb_u, l1g, l1b);

    // fused k+v projection (N=1024, split store)
    gemm256<6, 2, 0><<<dim3(4, 128), 512, 131072, stream>>>(
        hb_u, 512, kvT_u, 512, nullptr, nullptr, 0,
        kb_u, vb_u, ROWS, 1024, 512, 0, 0);

    // k sequence-softmax stats
    ksm_stats1<<<dim3(64, 4), 256, 0, stream>>>(kb_u, pm, ps2);
    ksm_stats2<<<8, 256, 0, stream>>>(pm, ps2, Mst, Sinv);

    // context (consumes kb, vb)
    hipMemsetAsync(ctx, 0, (size_t)NB * HEADS * 64 * 64 * sizeof(float), stream);
    context_kernel<<<dim3(16, HEADS, NB), 256, 0, stream>>>(kb_u, vb_u, Mst, Sinv, ctx);

    // q projection + fused feature-softmax epilogue -> qb (R1; kb dead)
    gemm256<7, 2, 0><<<dim3(2, 128), 512, 131072, stream>>>(
        hb_u, 512, qwT_u, 512, nullptr, nullptr, 0,
        qb_u, nullptr, ROWS, 512, 512, 0, 0);

    // compose ctx with attn_out_w per batch; transpose into R2 (vb dead)
    caw_kernel<<<dim3(8, 8, 4), 256, 0, stream>>>(ctx, aow, caw);
    for (int b = 0; b < NB; ++b)
        transconv<<<dim3(16, 16), 256, 0, stream>>>(caw + (size_t)b * 262144,
                                                    cawT_u + (size_t)b * 262144, 512, 512, 512);

    // x += qsm @ caw[b]^T + aob
    gemm256<2, 2, 0><<<dim3(2, 128), 512, 131072, stream>>>(
        qb_u, 512, cawT_u, 512, aob, nullptr, 0,
        xout, nullptr, ROWS, 512, 512, 262144, NN);

    // FF block: LN2 then per-2-batch {ff1 N=2048 (XCD-swizzled) -> mid; ff2 MH=1}
    ln_kernel<<<ROWS, 128, 0, stream>>>(xout, hb_u, l2g, l2b);
    for (int bp = 0; bp < 2; ++bp) {
        const unsigned short* hbp = hb_u + (size_t)bp * 16384 * DIMC;
        gemm256<1, 2, 1><<<dim3(8, 64), 512, 131072, stream>>>(
            hbp, 512, f1wT_u, 512, f1b, nullptr, 0,
            mid_u, nullptr, 16384, FF, 512, 0, 0);
        gemm256<2, 1, 0><<<dim3(2, 128), 512, 98304, stream>>>(
            mid_u, 2048, f2wT_u, 2048, f2b_, nullptr, 0,
            xout + (size_t)bp * 16384 * DIMC, nullptr, 16384, 512, 2048, 0, 0);
    }

    pos_kernel<<<8192, 256, 0, stream>>>(xout, hpw, hpb, pout);
}

// Round 16
// 643.175 us; speedup vs baseline: 1.4744x; 1.0342x over previous
//
#include <hip/hip_runtime.h>
#include <hip/hip_bf16.h>
#include <math.h>

// ---------------- constants ----------------
#define NB 4
#define NN 8192
#define ROWS (NB*NN)          // 32768
#define DIMC 512
#define HEADS 8
#define DT 128
#define DELTA 64
#define FF 2048
#define KCATP 640             // 576 padded to 640; pad cols zeroed on BOTH A and B sides every call

// ---------------- workspace layout (FLOAT units) ----------------
#define OFF_R0     ((size_t)0)          // catA [32768][640]bf16 -> hb [32768][512]bf16
#define OFF_CAW    ((size_t)8388608)    // caw f32 [4][512][512] (tail slack past hb)
#define OFF_R1     ((size_t)10485760)   // kb -> qb -> mid(lo)   [R1:8,388,608 f]
#define OFF_R2     ((size_t)18874368)   // vb -> cawT -> mid(hi) [R2:8,388,608 f]
#define OFF_CATWT  ((size_t)27262976)   // bf16 [512][640]
#define OFF_KVT    ((size_t)27426816)   // bf16 [1024][512]
#define OFF_QWT    ((size_t)27688960)   // bf16 [512][512]
#define OFF_F1WT   ((size_t)27820032)   // bf16 [2048][512]
#define OFF_F2WT   ((size_t)28344320)   // bf16 [512][2048]
#define OFF_LXWB   ((size_t)28868608)   // bf16 [512][512]
#define OFF_CW0T   ((size_t)28999680)   // bf16 [512][512]
#define OFF_Y      ((size_t)29130752)
#define OFF_BB     ((size_t)29131264)
#define OFF_PM     ((size_t)29133312)
#define OFF_PS     ((size_t)29264384)
#define OFF_M      ((size_t)29395456)
#define OFF_SINV   ((size_t)29397504)
#define OFF_CTX    ((size_t)29399552)
// end = 29,530,624 floats = 118.1 MB

typedef __attribute__((ext_vector_type(8))) short bf16x8;
typedef __attribute__((ext_vector_type(4))) float f32x4;
typedef __attribute__((ext_vector_type(8))) unsigned short us8;

static __device__ __forceinline__ unsigned short f2b(float x) {
    __hip_bfloat16 h = __float2bfloat16(x);
    return __builtin_bit_cast(unsigned short, h);
}
static __device__ __forceinline__ float b2f(unsigned short u) {
    return __bfloat162float(__builtin_bit_cast(__hip_bfloat16, u));
}
// gelu(tanh approx) = x - x/(e^{2z}+1); overflow-safe, single v_exp_f32.
static __device__ __forceinline__ float gelu_tanh(float x) {
    float z2 = 1.5957691216057308f * (x + 0.044715f * x * x * x);
    float t = __expf(z2);
    return x - x / (t + 1.0f);
}

#define GLOAD16(g, l) __builtin_amdgcn_global_load_lds( \
    (const __attribute__((address_space(1))) void*)(g), \
    (__attribute__((address_space(3))) void*)(l), 16, 0, 0)

// ---------------- tiny prologue kernels ----------------
__global__ void y_kernel(const float* __restrict__ dt, const float* __restrict__ yyw,
                         const float* __restrict__ yyb, float* __restrict__ y_ws,
                         float* __restrict__ y_out) {
    int idx = blockIdx.x * 128 + threadIdx.x;   // 512
    int b = idx >> 7, j = idx & 127;
    float acc = yyb[j];
    for (int c = 0; c < DT; ++c) acc += dt[b * DT + c] * yyw[c * DT + j];
    y_ws[idx] = acc;
    y_out[idx] = acc;
}

__global__ void bb_kernel(const float* __restrict__ linxb, const float* __restrict__ catw,
                          const float* __restrict__ catb, const float* __restrict__ y,
                          float* __restrict__ bb) {
    int idx = blockIdx.x * 256 + threadIdx.x;   // 2048
    int b = idx >> 9, n = idx & 511;
    float acc = catb[n];
    for (int c = 0; c < DIMC; ++c) acc += linxb[c] * catw[(size_t)c * DIMC + n];
    const float* cw3 = catw + (size_t)(DIMC + DELTA) * DIMC;
    for (int j = 0; j < DT; ++j) acc += y[b * DT + j] * cw3[(size_t)j * DIMC + n];
    bb[idx] = acc;
}

// delta -> catA columns 512..575; ALSO zero pad cols 576..639 (replay safety)
__global__ __launch_bounds__(256) void delta_kernel(
    const float* __restrict__ pos, const float* __restrict__ mask,
    const float* __restrict__ w1, const float* __restrict__ b1,
    const float* __restrict__ w2, const float* __restrict__ b2,
    unsigned short* __restrict__ catA) {
    int lane = threadIdx.x & 63;
    size_t row = (size_t)blockIdx.x * 4 + (threadIdx.x >> 6);
    float mk = mask[row];
    float px = pos[row * 2] * mk, py = pos[row * 2 + 1] * mk;
    float nrm = sqrtf(px * px + py * py) + 1e-7f;
    float ux = px / nrm, uy = py / nrm;
    float t1 = fmaxf(ux * w1[lane] + uy * w1[64 + lane] + b1[lane], 0.0f);
    float acc = b2[lane];
    #pragma unroll
    for (int j = 0; j < 64; ++j) {
        float tv = __shfl(t1, j, 64);
        acc += tv * w2[j * 64 + lane];
    }
    catA[row * KCATP + DIMC + lane] = f2b(acc);
    catA[row * KCATP + 576 + lane] = 0;
}

// zero catWT pad cols 576..639 (B side)
__global__ void zcat_kernel(unsigned short* __restrict__ catWT) {
    int idx = blockIdx.x * 256 + threadIdx.x;   // 32768
    int n = idx >> 6, c = 576 + (idx & 63);
    catWT[(size_t)n * KCATP + c] = 0;
}

// f32 -> bf16 flat convert
__global__ void conv_bf16(const float* __restrict__ in, unsigned short* __restrict__ out, int n8) {
    int i = blockIdx.x * 256 + threadIdx.x;
    if (i >= n8) return;
    const float* p = in + (size_t)i * 8;
    us8 o;
    #pragma unroll
    for (int j = 0; j < 8; ++j) o[j] = f2b(p[j]);
    *(us8*)(out + (size_t)i * 8) = o;
}

// f32 [rows][512] -> bf16 out[row*ldo + c]
__global__ void conv_bf16_strided(const float* __restrict__ in, unsigned short* __restrict__ out,
                                  int ldo) {
    int i = blockIdx.x * 256 + threadIdx.x;
    int row = i >> 6, c8 = (i & 63) * 8;
    const float* p = in + (size_t)row * DIMC + c8;
    us8 o;
    #pragma unroll
    for (int j = 0; j < 8; ++j) o[j] = f2b(p[j]);
    *(us8*)(out + (size_t)row * ldo + c8) = o;
}

// f32 [R][C] -> bf16 out[c*ldo + r]
__global__ __launch_bounds__(256) void transconv(const float* __restrict__ in,
                                                 unsigned short* __restrict__ out,
                                                 int R, int C, int ldo) {
    __shared__ float tile[32][33];
    int bx = blockIdx.x * 32;
    int by = blockIdx.y * 32;
    int tx = threadIdx.x & 31, ty = threadIdx.x >> 5;
    #pragma unroll
    for (int i = 0; i < 4; ++i) {
        int r = ty + i * 8;
        tile[r][tx] = in[(size_t)(by + r) * C + bx + tx];
    }
    __syncthreads();
    #pragma unroll
    for (int i = 0; i < 4; ++i) {
        int r = ty + i * 8;
        out[(size_t)(bx + r) * ldo + by + tx] = f2b(tile[tx][r]);
    }
}

// LayerNorm: f32 in -> bf16 out
__global__ __launch_bounds__(128) void ln_kernel(
    const float* __restrict__ src, unsigned short* __restrict__ dst,
    const float* __restrict__ g, const float* __restrict__ bta) {
    size_t row = blockIdx.x;
    int t = threadIdx.x;
    const float* s = src + row * DIMC;
    float4 x = *(const float4*)(s + t * 4);
    float sum = x.x + x.y + x.z + x.w;
    float sq = x.x * x.x + x.y * x.y + x.z * x.z + x.w * x.w;
    #pragma unroll
    for (int o = 32; o; o >>= 1) { sum += __shfl_down(sum, o, 64); sq += __shfl_down(sq, o, 64); }
    __shared__ float sh[4];
    if ((t & 63) == 0) { sh[(t >> 6) * 2] = sum; sh[(t >> 6) * 2 + 1] = sq; }
    __syncthreads();
    sum = sh[0] + sh[2]; sq = sh[1] + sh[3];
    float mean = sum * (1.0f / DIMC);
    float var = sq * (1.0f / DIMC) - mean * mean;
    float rstd = rsqrtf(fmaxf(var, 0.0f) + 1e-5f);
    float4 gv = *(const float4*)(g + t * 4);
    float4 bv = *(const float4*)(bta + t * 4);
    ushort4 ov;
    ov.x = f2b((x.x - mean) * rstd * gv.x + bv.x);
    ov.y = f2b((x.y - mean) * rstd * gv.y + bv.y);
    ov.z = f2b((x.z - mean) * rstd * gv.z + bv.z);
    ov.w = f2b((x.w - mean) * rstd * gv.w + bv.w);
    *(ushort4*)(dst + row * DIMC + t * 4) = ov;
}

// ================= 256x128 MFMA GEMM, BK=32, 3-slot rotating LDS (72KB -> 2 blocks/CU) =================
// C[M,N] = A[M,K] @ Bt[N,K], bf16. 512 threads = 8 waves (4 row-groups x 2 col-groups),
// per-wave 64x64, acc 4x4 f32x4 (64 regs). Depth-2 prefetch, counted vmcnt(3):
//   per tile: 8 ds_read | stage(t+2): A 2 loads + B 1 load | lgkmcnt(0) | 16 MFMA |
//             vmcnt(3) [t+1's 3 loads drained, t+2's stay in flight] | ONE s_barrier.
// Safety invariants: all waves' ds_reads of slot s complete (own lgkmcnt(0)) before any
// wave passes end-of-s barrier; stage at t targets slot (t+2)%3 == (t-1)%3, last read at t-1.
// SWZ=1: XCD-chunked block remap (needs gridDim.y%8==0).
// EPI: 1 gelu->bf16; 2 f32 +=; 3 f32 +extra[batch]; 6 bf16 split store; 7 bf16 head-softmax.
template <int EPI, int SWZ>
__global__ __launch_bounds__(512, 4) void gemm256(
    const unsigned short* __restrict__ A, int lda,
    const unsigned short* __restrict__ Bt, int ldb,
    const float* __restrict__ bias,
    const float* __restrict__ extra, int batch_rows,
    void* __restrict__ Cv, void* __restrict__ Cv2,
    int M, int N, int K,
    size_t b_stride, int rows_per_batch) {
    extern __shared__ char lds[];
    // slot layout: [A: 16KB][B: 8KB], slot s at lds + s*24576
    const int tid = threadIdx.x;
    const int lane = tid & 63, wv = tid >> 6;
    const int wr = wv >> 1, wc = wv & 1;     // 4 x 2 waves
    const int lr = lane & 15, lch = lane >> 4;

    int bxi = blockIdx.x, byi = blockIdx.y;
    if constexpr (SWZ) {
        int l = byi * gridDim.x + bxi;
        int xcd = l & 7, j = l >> 3;
        byi = xcd * (gridDim.y >> 3) + j / gridDim.x;
        bxi = j % gridDim.x;
    }
    const int bm = byi * 256, bn = bxi * 128;

    const unsigned short* Bb = Bt;
    if (rows_per_batch) Bb = Bt + (size_t)(bm / rows_per_batch) * b_stride;

    const int srow = tid >> 2;          // 0..127 (+128 for A's 2nd load)
    const int schunk = tid & 3;

    // stage tile t (32 k-cols starting at kcol) into slot s: A 2 loads, B 1 load
    auto stage = [&](int s, int kcol) {
        char* dstA = lds + (size_t)s * 24576;
        #pragma unroll
        for (int i = 0; i < 2; ++i) {
            int row = srow + 128 * i;
            int gc = schunk ^ ((row >> 1) & 3);
            GLOAD16((const char*)(A + (size_t)(bm + row) * lda + kcol) + gc * 16,
                    dstA + (size_t)(tid + 512 * i) * 16);
        }
        char* dstB = lds + (size_t)s * 24576 + 16384;
        {
            int row = srow;
            int gc = schunk ^ ((row >> 1) & 3);
            GLOAD16((const char*)(Bb + (size_t)(bn + row) * ldb + kcol) + gc * 16,
                    dstB + (size_t)tid * 16);
        }
    };

    f32x4 acc[4][4] = {};
    const int nt = K >> 5;

    stage(0, 0);
    stage(1, 32);
    __builtin_amdgcn_sched_barrier(0);
    asm volatile("s_waitcnt vmcnt(3)" ::: "memory");   // tile 0's 3 loads landed
    __builtin_amdgcn_sched_barrier(0);
    __builtin_amdgcn_s_barrier();

    int slot = 0;
    for (int t = 0; t < nt; ++t) {
        const char* base = lds + (size_t)slot * 24576;
        bf16x8 afr[4], bfr[4];
        #pragma unroll
        for (int n = 0; n < 4; ++n) {
            int bc = wc * 64 + n * 16 + lr;
            bfr[n] = *(const bf16x8*)(base + 16384 + bc * 64 + ((lch ^ ((bc >> 1) & 3)) << 4));
        }
        #pragma unroll
        for (int m = 0; m < 4; ++m) {
            int ar = wr * 64 + m * 16 + lr;
            afr[m] = *(const bf16x8*)(base + ar * 64 + ((lch ^ ((ar >> 1) & 3)) << 4));
        }
        const bool pf2 = (t + 2 < nt);
        if (pf2) {
            int s2 = slot >= 1 ? slot - 1 : 2;   // (t+2)%3
            stage(s2, (t + 2) << 5);
        }
        __builtin_amdgcn_sched_barrier(0);
        asm volatile("s_waitcnt lgkmcnt(0)" ::: "memory");
        __builtin_amdgcn_sched_barrier(0);
        __builtin_amdgcn_s_setprio(1);
        #pragma unroll
        for (int m = 0; m < 4; ++m)
            #pragma unroll
            for (int n = 0; n < 4; ++n)
                acc[m][n] = __builtin_amdgcn_mfma_f32_16x16x32_bf16(
                    afr[m], bfr[n], acc[m][n], 0, 0, 0);
        __builtin_amdgcn_s_setprio(0);
        if (t + 1 < nt) {
            if (pf2) asm volatile("s_waitcnt vmcnt(3)" ::: "memory");  // t+1 landed
            else     asm volatile("s_waitcnt vmcnt(0)" ::: "memory");
            __builtin_amdgcn_sched_barrier(0);
        }
        __builtin_amdgcn_s_barrier();
        slot = slot < 2 ? slot + 1 : 0;
    }

    const int g4 = lch * 4;
    if constexpr (EPI == 7) {
        // feature softmax over the wave's 64-col head span
        #pragma unroll
        for (int m = 0; m < 4; ++m)
            #pragma unroll
            for (int r = 0; r < 4; ++r) {
                float v0 = acc[m][0][r], v1 = acc[m][1][r];
                float v2 = acc[m][2][r], v3 = acc[m][3][r];
                float mx = fmaxf(fmaxf(v0, v1), fmaxf(v2, v3));
                #pragma unroll
                for (int o = 1; o < 16; o <<= 1) mx = fmaxf(mx, __shfl_xor(mx, o, 64));
                float e0 = __expf(v0 - mx), e1 = __expf(v1 - mx);
                float e2 = __expf(v2 - mx), e3 = __expf(v3 - mx);
                float s = e0 + e1 + e2 + e3;
                #pragma unroll
                for (int o = 1; o < 16; o <<= 1) s += __shfl_xor(s, o, 64);
                float sc = 0.125f / s;
                int rr = bm + wr * 64 + m * 16 + g4 + r;
                unsigned short* dst = (unsigned short*)Cv + (size_t)rr * N + bn + wc * 64 + lr;
                dst[0]  = f2b(e0 * sc);
                dst[16] = f2b(e1 * sc);
                dst[32] = f2b(e2 * sc);
                dst[48] = f2b(e3 * sc);
            }
    } else {
        #pragma unroll
        for (int m = 0; m < 4; ++m)
            #pragma unroll
            for (int n = 0; n < 4; ++n) {
                int col = bn + wc * 64 + n * 16 + lr;
                #pragma unroll
                for (int r = 0; r < 4; ++r) {
                    int rr = bm + wr * 64 + m * 16 + g4 + r;
                    float v = acc[m][n][r];
                    if (EPI == 1) {
                        ((unsigned short*)Cv)[(size_t)rr * N + col] = f2b(gelu_tanh(v + bias[col]));
                    } else if (EPI == 2) {
                        ((float*)Cv)[(size_t)rr * N + col] += v + bias[col];
                    } else if (EPI == 3) {
                        ((float*)Cv)[(size_t)rr * N + col] = v + extra[(size_t)(rr / batch_rows) * N + col];
                    } else if (EPI == 6) {
                        unsigned short* dst = (col >> 9) ? (unsigned short*)Cv2 : (unsigned short*)Cv;
                        dst[(size_t)rr * 512 + (col & 511)] = f2b(v);
                    }
                }
            }
    }
}

// ---------------- legacy 128x128 MFMA GEMM (tiny wcomp only) ----------------
#define BM 128
#define BN 128
#define BK 64

template <int EPI>
__global__ __launch_bounds__(256) void gemm_mfma(
    const unsigned short* __restrict__ A, int lda,
    const unsigned short* __restrict__ Bt, int ldb,
    void* __restrict__ Cv, int M, int N, int K, int ldo) {
    __shared__ unsigned short As[2][BM * BK];
    __shared__ unsigned short Bs[2][BN * BK];
    int bm = blockIdx.y * BM, bn = blockIdx.x * BN;
    int tid = threadIdx.x;
    int lane = tid & 63, wv = tid >> 6;
    int wr = (wv >> 1) * 64, wc = (wv & 1) * 64;
    int g16 = (lane >> 4) << 4;
    int lr = lane & 15;
    int sw = (lr & 7) << 4;

    int srow = tid >> 3;
    int skb = (tid & 7) * 16;
    int sxor = skb ^ ((srow & 7) << 4);

    auto stage = [&](int buf, int k0) {
        #pragma unroll
        for (int i = 0; i < 4; ++i) {
            int row = srow + 32 * i;
            GLOAD16((const char*)(A + (size_t)(bm + row) * lda + k0) + sxor,
                    (char*)As[buf] + (size_t)(tid + 256 * i) * 16);
        }
        #pragma unroll
        for (int i = 0; i < 4; ++i) {
            int row = srow + 32 * i;
            GLOAD16((const char*)(Bt + (size_t)(bn + row) * ldb + k0) + sxor,
                    (char*)Bs[buf] + (size_t)(tid + 256 * i) * 16);
        }
    };

    f32x4 acc[4][4] = {};
    int nt = K / BK;
    stage(0, 0);
    __syncthreads();
    for (int t = 0; t < nt; ++t) {
        int cur = t & 1;
        if (t + 1 < nt) stage(cur ^ 1, (t + 1) * BK);
        const char* Ab = (const char*)As[cur];
        const char* Bp = (const char*)Bs[cur];
        #pragma unroll
        for (int s = 0; s < 2; ++s) {
            int koff = s * 64 + g16;
            bf16x8 af[4], bw[4];
            #pragma unroll
            for (int f = 0; f < 4; ++f) {
                int ar = wr + f * 16 + lr;
                af[f] = *(const bf16x8*)(Ab + ar * 128 + (koff ^ sw));
                int br = wc + f * 16 + lr;
                bw[f] = *(const bf16x8*)(Bp + br * 128 + (koff ^ sw));
            }
            #pragma unroll
            for (int f = 0; f < 4; ++f)
                #pragma unroll
                for (int j = 0; j < 4; ++j)
                    acc[f][j] = __builtin_amdgcn_mfma_f32_16x16x32_bf16(
                        af[f], bw[j], acc[f][j], 0, 0, 0);
        }
        __syncthreads();
    }

    int g4 = (lane >> 4) * 4;
    #pragma unroll
    for (int f = 0; f < 4; ++f) {
        #pragma unroll
        for (int j = 0; j < 4; ++j) {
            int col = bn + wc + j * 16 + lr;
            #pragma unroll
            for (int r = 0; r < 4; ++r) {
                int rr = bm + wr + f * 16 + g4 + r;
                float v = acc[f][j][r];
                if (EPI == 4) {
                    ((unsigned short*)Cv)[(size_t)rr * N + col] = f2b(v);
                } else if (EPI == 5) {
                    ((unsigned short*)Cv)[(size_t)col * ldo + rr] = f2b(v);
                }
            }
        }
    }
}

// ---------------- k column-softmax stats (branchless online update) ----------------
__global__ __launch_bounds__(256) void ksm_stats1(
    const unsigned short* __restrict__ k, float* __restrict__ pm, float* __restrict__ ps) {
    int b = blockIdx.y, rb = blockIdx.x;
    const unsigned short* kp = k + ((size_t)b * NN + (size_t)rb * 128) * DIMC;
    int t = threadIdx.x;
    float m0 = -1e30f, s0 = 0.f, m1 = -1e30f, s1 = 0.f;
    for (int r = 0; r < 128; ++r) {
        float x0 = b2f(kp[(size_t)r * DIMC + t]);
        float x1 = b2f(kp[(size_t)r * DIMC + t + 256]);
        float n0 = fmaxf(m0, x0), n1 = fmaxf(m1, x1);
        s0 = s0 * __expf(m0 - n0) + __expf(x0 - n0);
        s1 = s1 * __expf(m1 - n1) + __expf(x1 - n1);
        m0 = n0; m1 = n1;
    }
    size_t base = ((size_t)b * 64 + rb) * DIMC;
    pm[base + t] = m0; pm[base + t + 256] = m1;
    ps[base + t] = s0; ps[base + t + 256] = s1;
}

__global__ void ksm_stats2(const float* __restrict__ pm, const float* __restrict__ ps,
                           float* __restrict__ Mst, float* __restrict__ Sinv) {
    int idx = blockIdx.x * 256 + threadIdx.x;
    int b = idx >> 9, c = idx & 511;
    float m = -1e30f, s = 0.f;
    for (int rb = 0; rb < 64; ++rb) {
        float mm = pm[((size_t)b * 64 + rb) * DIMC + c];
        float ss = ps[((size_t)b * 64 + rb) * DIMC + c];
        if (mm > m) { s = s * __expf(m - mm) + ss; m = mm; } else s += ss * __expf(mm - m);
    }
    Mst[idx] = m;
    Sinv[idx] = 1.f / s;
}

// ---------------- context = sum_n expk[n,d] * v[n,e] (LDS version) ----------------
__global__ __launch_bounds__(256) void context_kernel(
    const unsigned short* __restrict__ kb, const unsigned short* __restrict__ vb,
    const float* __restrict__ Mst, const float* __restrict__ Sinv,
    float* __restrict__ ctx) {
    int b = blockIdx.z, hd = blockIdx.y, rb = blockIdx.x;
    int tid = threadIdx.x, tx = tid & 15, ty = tid >> 4;
    __shared__ float kx[64][68];
    __shared__ float vx[64][68];
    int r0t = tid >> 3;
    int c8 = (tid & 7) * 8;
    int cb = hd * 64 + c8;
    float mv[8], sv[8];
    #pragma unroll
    for (int j = 0; j < 8; ++j) { mv[j] = Mst[b * DIMC + cb + j]; sv[j] = Sinv[b * DIMC + cb + j]; }
    float cacc[4][4] = {};
    for (int sub = 0; sub < 8; ++sub) {
        size_t row0 = (size_t)b * NN + (size_t)rb * 512 + sub * 64;
        #pragma unroll
        for (int i = 0; i < 2; ++i) {
            int r = r0t + i * 32;
            us8 kv = *(const us8*)(kb + (row0 + r) * DIMC + cb);
            us8 vv = *(const us8*)(vb + (row0 + r) * DIMC + cb);
            #pragma unroll
            for (int j = 0; j < 8; ++j) {
                kx[r][c8 + j] = __expf(b2f(kv[j]) - mv[j]) * sv[j];
                vx[r][c8 + j] = b2f(vv[j]);
            }
        }
        __syncthreads();
        #pragma unroll 4
        for (int r = 0; r < 64; ++r) {
            float4 a4 = *(const float4*)&kx[r][ty * 4];
            float4 b4 = *(const float4*)&vx[r][tx * 4];
            float av[4] = {a4.x, a4.y, a4.z, a4.w};
            float bv[4] = {b4.x, b4.y, b4.z, b4.w};
            #pragma unroll
            for (int i = 0; i < 4; ++i)
                #pragma unroll
                for (int j = 0; j < 4; ++j)
                    cacc[i][j] = fmaf(av[i], bv[j], cacc[i][j]);
        }
        __syncthreads();
    }
    size_t cbase = (size_t)(b * HEADS + hd) * 64 * 64;
    #pragma unroll
    for (int i = 0; i < 4; ++i)
        #pragma unroll
        for (int j = 0; j < 4; ++j)
            atomicAdd(&ctx[cbase + (size_t)(ty * 4 + i) * 64 + tx * 4 + j], cacc[i][j]);
}

// ---------------- caw = ctx @ aow (per batch) ----------------
__global__ __launch_bounds__(256) void caw_kernel(const float* __restrict__ ctx,
                                                  const float* __restrict__ aow,
                                                  float* __restrict__ caw) {
    int nt = blockIdx.x, hd = blockIdx.y, b = blockIdx.z;
    int tid = threadIdx.x, tx = tid & 15, ty = tid >> 4;
    __shared__ float cs[64][68];
    __shared__ float aw[64][68];
    #pragma unroll
    for (int i = 0; i < 4; ++i) {
        int idx = tid + 256 * i;
        int r = idx >> 4, c4 = (idx & 15) * 4;
        *(float4*)&cs[r][c4] = *(const float4*)(ctx + ((size_t)(b * HEADS + hd) * 64 + r) * 64 + c4);
        *(float4*)&aw[r][c4] = *(const float4*)(aow + (size_t)(hd * 64 + r) * DIMC + nt * 64 + c4);
    }
    __syncthreads();
    float acc[4][4] = {};
    for (int e = 0; e < 64; ++e) {
        float av[4];
        #pragma unroll
        for (int i = 0; i < 4; ++i) av[i] = cs[ty * 4 + i][e];
        float4 b4 = *(const float4*)&aw[e][tx * 4];
        float bv[4] = {b4.x, b4.y, b4.z, b4.w};
        #pragma unroll
        for (int i = 0; i < 4; ++i)
            #pragma unroll
            for (int j = 0; j < 4; ++j)
                acc[i][j] = fmaf(av[i], bv[j], acc[i][j]);
    }
    #pragma unroll
    for (int i = 0; i < 4; ++i)
        #pragma unroll
        for (int j = 0; j < 4; ++j)
            caw[(size_t)b * DIMC * DIMC + (size_t)(hd * 64 + ty * 4 + i) * DIMC + nt * 64 + tx * 4 + j]
                = acc[i][j];
}

// ---------------- pos head ----------------
__global__ __launch_bounds__(256) void pos_kernel(
    const float* __restrict__ x, const float* __restrict__ w,
    const float* __restrict__ b2, float* __restrict__ out) {
    int lane = threadIdx.x & 63;
    size_t row = (size_t)blockIdx.x * 4 + (threadIdx.x >> 6);
    const float* xp = x + row * DIMC;
    float acc0 = 0.f, acc1 = 0.f;
    #pragma unroll
    for (int i = 0; i < 2; ++i) {
        float4 xv = *(const float4*)(xp + lane * 8 + i * 4);
        const float* wp = w + (size_t)(lane * 8 + i * 4) * 2;
        float4 w0 = *(const float4*)(wp);
        float4 w1 = *(const float4*)(wp + 4);
        acc0 += xv.x * w0.x + xv.y * w0.z + xv.z * w1.x + xv.w * w1.z;
        acc1 += xv.x * w0.y + xv.y * w0.w + xv.z * w1.y + xv.w * w1.w;
    }
    #pragma unroll
    for (int o = 32; o; o >>= 1) { acc0 += __shfl_down(acc0, o, 64); acc1 += __shfl_down(acc1, o, 64); }
    if (lane == 0) {
        out[row * 2] = acc0 + b2[0];
        out[row * 2 + 1] = acc1 + b2[1];
    }
}

// ---------------- launch ----------------
extern "C" void kernel_launch(void* const* d_in, const int* in_sizes, int n_in,
                              void* d_out, int out_size, void* d_ws, size_t ws_size,
                              hipStream_t stream) {
    (void)in_sizes; (void)n_in; (void)out_size; (void)ws_size;
    const float* nf  = (const float*)d_in[0];
    const float* dt  = (const float*)d_in[1];
    const float* pos = (const float*)d_in[2];
    const float* msk = (const float*)d_in[3];
    const float* yyw = (const float*)d_in[4];
    const float* yyb = (const float*)d_in[5];
    const float* p1w = (const float*)d_in[6];
    const float* p1b = (const float*)d_in[7];
    const float* p2w = (const float*)d_in[8];
    const float* p2b = (const float*)d_in[9];
    const float* lxw = (const float*)d_in[10];
    const float* lxb = (const float*)d_in[11];
    const float* cw  = (const float*)d_in[12];
    const float* cb  = (const float*)d_in[13];
    const float* l1g = (const float*)d_in[14];
    const float* l1b = (const float*)d_in[15];
    const float* qw  = (const float*)d_in[16];
    const float* kw  = (const float*)d_in[17];
    const float* vw  = (const float*)d_in[18];
    const float* aow = (const float*)d_in[19];
    const float* aob = (const float*)d_in[20];
    const float* l2g = (const float*)d_in[21];
    const float* l2b = (const float*)d_in[22];
    const float* f1w = (const float*)d_in[23];
    const float* f1b = (const float*)d_in[24];
    const float* f2w = (const float*)d_in[25];
    const float* f2b_ = (const float*)d_in[26];
    const float* hpw = (const float*)d_in[27];
    const float* hpb = (const float*)d_in[28];

    float* ws = (float*)d_ws;
    unsigned short* catA_u  = (unsigned short*)(ws + OFF_R0);
    unsigned short* hb_u    = (unsigned short*)(ws + OFF_R0);
    float*          caw     = ws + OFF_CAW;
    unsigned short* kb_u    = (unsigned short*)(ws + OFF_R1);
    unsigned short* qb_u    = (unsigned short*)(ws + OFF_R1);
    unsigned short* mid_u   = (unsigned short*)(ws + OFF_R1);   // [16384][2048] bf16 spans R1+R2
    unsigned short* vb_u    = (unsigned short*)(ws + OFF_R2);
    unsigned short* cawT_u  = (unsigned short*)(ws + OFF_R2);
    unsigned short* catWT_u = (unsigned short*)(ws + OFF_CATWT);
    unsigned short* kvT_u   = (unsigned short*)(ws + OFF_KVT);
    unsigned short* qwT_u   = (unsigned short*)(ws + OFF_QWT);
    unsigned short* f1wT_u  = (unsigned short*)(ws + OFF_F1WT);
    unsigned short* f2wT_u  = (unsigned short*)(ws + OFF_F2WT);
    unsigned short* lxwb_u  = (unsigned short*)(ws + OFF_LXWB);
    unsigned short* cw0T_u  = (unsigned short*)(ws + OFF_CW0T);
    float* yv   = ws + OFF_Y;
    float* bbf  = ws + OFF_BB;
    float* pm   = ws + OFF_PM;
    float* ps2  = ws + OFF_PS;
    float* Mst  = ws + OFF_M;
    float* Sinv = ws + OFF_SINV;
    float* ctx  = ws + OFF_CTX;

    float* xout = (float*)d_out;
    float* yout = xout + (size_t)ROWS * DIMC;
    float* pout = yout + NB * DT;

    // allow 72KB dynamic LDS for gemm256 instantiations
    hipFuncSetAttribute(reinterpret_cast<const void*>(&gemm256<1, 1>),
                        hipFuncAttributeMaxDynamicSharedMemorySize, 73728);
    hipFuncSetAttribute(reinterpret_cast<const void*>(&gemm256<2, 0>),
                        hipFuncAttributeMaxDynamicSharedMemorySize, 73728);
    hipFuncSetAttribute(reinterpret_cast<const void*>(&gemm256<3, 0>),
                        hipFuncAttributeMaxDynamicSharedMemorySize, 73728);
    hipFuncSetAttribute(reinterpret_cast<const void*>(&gemm256<6, 0>),
                        hipFuncAttributeMaxDynamicSharedMemorySize, 73728);
    hipFuncSetAttribute(reinterpret_cast<const void*>(&gemm256<7, 0>),
                        hipFuncAttributeMaxDynamicSharedMemorySize, 73728);

    // prologue scalars + weight conversions
    y_kernel<<<4, 128, 0, stream>>>(dt, yyw, yyb, yv, yout);
    bb_kernel<<<8, 256, 0, stream>>>(lxb, cw, cb, yv, bbf);
    conv_bf16<<<128, 256, 0, stream>>>(lxw, lxwb_u, 32768);
    transconv<<<dim3(16, 16), 256, 0, stream>>>(cw, cw0T_u, 512, 512, 512);
    transconv<<<dim3(16, 2), 256, 0, stream>>>(cw + (size_t)DIMC * DIMC, catWT_u + 512, 64, 512, KCATP);
    zcat_kernel<<<128, 256, 0, stream>>>(catWT_u);
    transconv<<<dim3(16, 16), 256, 0, stream>>>(kw, kvT_u, 512, 512, 512);
    transconv<<<dim3(16, 16), 256, 0, stream>>>(vw, kvT_u + (size_t)512 * 512, 512, 512, 512);
    transconv<<<dim3(16, 16), 256, 0, stream>>>(qw, qwT_u, 512, 512, 512);
    transconv<<<dim3(64, 16), 256, 0, stream>>>(f1w, f1wT_u, 512, 2048, 512);
    transconv<<<dim3(16, 64), 256, 0, stream>>>(f2w, f2wT_u, 2048, 512, 2048);
    conv_bf16_strided<<<8192, 256, 0, stream>>>(nf, catA_u, KCATP);
    delta_kernel<<<8192, 256, 0, stream>>>(pos, msk, p1w, p1b, p2w, p2b, catA_u);

    // catWT cols 0..511 = (lxw @ cw0)^T
    gemm_mfma<5><<<dim3(4, 4), 256, 0, stream>>>(
        lxwb_u, 512, cw0T_u, 512, catWT_u, 512, 512, 512, KCATP);

    // cat = catA @ catWT^T + bb[batch] -> xout (f32)
    gemm256<3, 0><<<dim3(4, 128), 512, 73728, stream>>>(
        catA_u, KCATP, catWT_u, KCATP, nullptr, bbf, NN,
        xout, nullptr, ROWS, 512, KCATP, 0, 0);

    // LN1: xout -> hb
    ln_kernel<<<ROWS, 128, 0, stream>>>(xout, hb_u, l1g, l1b);

    // fused k+v projection (N=1024, split store)
    gemm256<6, 0><<<dim3(8, 128), 512, 73728, stream>>>(
        hb_u, 512, kvT_u, 512, nullptr, nullptr, 0,
        kb_u, vb_u, ROWS, 1024, 512, 0, 0);

    // k sequence-softmax stats
    ksm_stats1<<<dim3(64, 4), 256, 0, stream>>>(kb_u, pm, ps2);
    ksm_stats2<<<8, 256, 0, stream>>>(pm, ps2, Mst, Sinv);

    // context (consumes kb, vb)
    hipMemsetAsync(ctx, 0, (size_t)NB * HEADS * 64 * 64 * sizeof(float), stream);
    context_kernel<<<dim3(16, HEADS, NB), 256, 0, stream>>>(kb_u, vb_u, Mst, Sinv, ctx);

    // q projection + fused feature-softmax epilogue -> qb (R1; kb dead)
    gemm256<7, 0><<<dim3(4, 128), 512, 73728, stream>>>(
        hb_u, 512, qwT_u, 512, nullptr, nullptr, 0,
        qb_u, nullptr, ROWS, 512, 512, 0, 0);

    // compose ctx with attn_out_w per batch; transpose into R2 (vb dead)
    caw_kernel<<<dim3(8, 8, 4), 256, 0, stream>>>(ctx, aow, caw);
    for (int b = 0; b < NB; ++b)
        transconv<<<dim3(16, 16), 256, 0, stream>>>(caw + (size_t)b * 262144,
                                                    cawT_u + (size_t)b * 262144, 512, 512, 512);

    // x += qsm @ caw[b]^T + aob
    gemm256<2, 0><<<dim3(4, 128), 512, 73728, stream>>>(
        qb_u, 512, cawT_u, 512, aob, nullptr, 0,
        xout, nullptr, ROWS, 512, 512, 262144, NN);

    // FF block: LN2 then per-2-batch {ff1 N=2048 (XCD-swizzled) -> mid; ff2 K=2048}
    ln_kernel<<<ROWS, 128, 0, stream>>>(xout, hb_u, l2g, l2b);
    for (int bp = 0; bp < 2; ++bp) {
        const unsigned short* hbp = hb_u + (size_t)bp * 16384 * DIMC;
        gemm256<1, 1><<<dim3(16, 64), 512, 73728, stream>>>(
            hbp, 512, f1wT_u, 512, f1b, nullptr, 0,
            mid_u, nullptr, 16384, FF, 512, 0, 0);
        gemm256<2, 0><<<dim3(4, 64), 512, 73728, stream>>>(
            mid_u, 2048, f2wT_u, 2048, f2b_, nullptr, 0,
            xout + (size_t)bp * 16384 * DIMC, nullptr, 16384, 512, 2048, 0, 0);
    }

    pos_kernel<<<8192, 256, 0, stream>>>(xout, hpw, hpb, pout);
}

// Round 17
// 636.497 us; speedup vs baseline: 1.4899x; 1.0105x over previous
//
#include <hip/hip_runtime.h>
#include <hip/hip_bf16.h>
#include <math.h>

// ---------------- constants ----------------
#define NB 4
#define NN 8192
#define ROWS (NB*NN)          // 32768
#define DIMC 512
#define HEADS 8
#define DT 128
#define DELTA 64
#define FF 2048
#define KCATP 640             // 576 padded to 640; pad cols zeroed on BOTH A and B sides every call

// ---------------- workspace layout (FLOAT units) ----------------
#define OFF_R0     ((size_t)0)          // catA [32768][640]bf16 -> hb [32768][512]bf16
#define OFF_CAW    ((size_t)8388608)    // caw f32 [4][512][512] (tail slack past hb)
#define OFF_R1     ((size_t)10485760)   // kbT [512][32768]bf16 -> qb -> mid(lo)
#define OFF_R2     ((size_t)18874368)   // vbT [512][32768]bf16 -> cawT -> mid(hi)
#define OFF_CATWT  ((size_t)27262976)   // bf16 [512][640]
#define OFF_KVT    ((size_t)27426816)   // bf16 [1024][512]
#define OFF_QWT    ((size_t)27688960)   // bf16 [512][512]
#define OFF_F1WT   ((size_t)27820032)   // bf16 [2048][512]
#define OFF_F2WT   ((size_t)28344320)   // bf16 [512][2048]
#define OFF_LXWB   ((size_t)28868608)   // bf16 [512][512]
#define OFF_CW0T   ((size_t)28999680)   // bf16 [512][512]
#define OFF_Y      ((size_t)29130752)
#define OFF_BB     ((size_t)29131264)
#define OFF_M      ((size_t)29395456)
#define OFF_SINV   ((size_t)29397504)
#define OFF_CTX    ((size_t)29399552)
// end = 29,530,624 floats = 118.1 MB

typedef __attribute__((ext_vector_type(8))) short bf16x8;
typedef __attribute__((ext_vector_type(4))) float f32x4;
typedef __attribute__((ext_vector_type(8))) unsigned short us8;

static __device__ __forceinline__ unsigned short f2b(float x) {
    __hip_bfloat16 h = __float2bfloat16(x);
    return __builtin_bit_cast(unsigned short, h);
}
static __device__ __forceinline__ float b2f(unsigned short u) {
    return __bfloat162float(__builtin_bit_cast(__hip_bfloat16, u));
}
// gelu(tanh approx) = x - x/(e^{2z}+1); overflow-safe, single v_exp_f32.
static __device__ __forceinline__ float gelu_tanh(float x) {
    float z2 = 1.5957691216057308f * (x + 0.044715f * x * x * x);
    float t = __expf(z2);
    return x - x / (t + 1.0f);
}

#define GLOAD16(g, l) __builtin_amdgcn_global_load_lds( \
    (const __attribute__((address_space(1))) void*)(g), \
    (__attribute__((address_space(3))) void*)(l), 16, 0, 0)

// ---------------- tiny prologue kernels ----------------
__global__ void y_kernel(const float* __restrict__ dt, const float* __restrict__ yyw,
                         const float* __restrict__ yyb, float* __restrict__ y_ws,
                         float* __restrict__ y_out) {
    int idx = blockIdx.x * 128 + threadIdx.x;   // 512
    int b = idx >> 7, j = idx & 127;
    float acc = yyb[j];
    for (int c = 0; c < DT; ++c) acc += dt[b * DT + c] * yyw[c * DT + j];
    y_ws[idx] = acc;
    y_out[idx] = acc;
}

__global__ void bb_kernel(const float* __restrict__ linxb, const float* __restrict__ catw,
                          const float* __restrict__ catb, const float* __restrict__ y,
                          float* __restrict__ bb) {
    int idx = blockIdx.x * 256 + threadIdx.x;   // 2048
    int b = idx >> 9, n = idx & 511;
    float acc = catb[n];
    for (int c = 0; c < DIMC; ++c) acc += linxb[c] * catw[(size_t)c * DIMC + n];
    const float* cw3 = catw + (size_t)(DIMC + DELTA) * DIMC;
    for (int j = 0; j < DT; ++j) acc += y[b * DT + j] * cw3[(size_t)j * DIMC + n];
    bb[idx] = acc;
}

// delta -> catA columns 512..575; ALSO zero pad cols 576..639 (replay safety)
__global__ __launch_bounds__(256) void delta_kernel(
    const float* __restrict__ pos, const float* __restrict__ mask,
    const float* __restrict__ w1, const float* __restrict__ b1,
    const float* __restrict__ w2, const float* __restrict__ b2,
    unsigned short* __restrict__ catA) {
    int lane = threadIdx.x & 63;
    size_t row = (size_t)blockIdx.x * 4 + (threadIdx.x >> 6);
    float mk = mask[row];
    float px = pos[row * 2] * mk, py = pos[row * 2 + 1] * mk;
    float nrm = sqrtf(px * px + py * py) + 1e-7f;
    float ux = px / nrm, uy = py / nrm;
    float t1 = fmaxf(ux * w1[lane] + uy * w1[64 + lane] + b1[lane], 0.0f);
    float acc = b2[lane];
    #pragma unroll
    for (int j = 0; j < 64; ++j) {
        float tv = __shfl(t1, j, 64);
        acc += tv * w2[j * 64 + lane];
    }
    catA[row * KCATP + DIMC + lane] = f2b(acc);
    catA[row * KCATP + 576 + lane] = 0;
}

// zero catWT pad cols 576..639 (B side)
__global__ void zcat_kernel(unsigned short* __restrict__ catWT) {
    int idx = blockIdx.x * 256 + threadIdx.x;   // 32768
    int n = idx >> 6, c = 576 + (idx & 63);
    catWT[(size_t)n * KCATP + c] = 0;
}

// f32 -> bf16 flat convert
__global__ void conv_bf16(const float* __restrict__ in, unsigned short* __restrict__ out, int n8) {
    int i = blockIdx.x * 256 + threadIdx.x;
    if (i >= n8) return;
    const float* p = in + (size_t)i * 8;
    us8 o;
    #pragma unroll
    for (int j = 0; j < 8; ++j) o[j] = f2b(p[j]);
    *(us8*)(out + (size_t)i * 8) = o;
}

// f32 [rows][512] -> bf16 out[row*ldo + c]
__global__ void conv_bf16_strided(const float* __restrict__ in, unsigned short* __restrict__ out,
                                  int ldo) {
    int i = blockIdx.x * 256 + threadIdx.x;
    int row = i >> 6, c8 = (i & 63) * 8;
    const float* p = in + (size_t)row * DIMC + c8;
    us8 o;
    #pragma unroll
    for (int j = 0; j < 8; ++j) o[j] = f2b(p[j]);
    *(us8*)(out + (size_t)row * ldo + c8) = o;
}

// f32 [R][C] -> bf16 out[c*ldo + r]
__global__ __launch_bounds__(256) void transconv(const float* __restrict__ in,
                                                 unsigned short* __restrict__ out,
                                                 int R, int C, int ldo) {
    __shared__ float tile[32][33];
    int bx = blockIdx.x * 32;
    int by = blockIdx.y * 32;
    int tx = threadIdx.x & 31, ty = threadIdx.x >> 5;
    #pragma unroll
    for (int i = 0; i < 4; ++i) {
        int r = ty + i * 8;
        tile[r][tx] = in[(size_t)(by + r) * C + bx + tx];
    }
    __syncthreads();
    #pragma unroll
    for (int i = 0; i < 4; ++i) {
        int r = ty + i * 8;
        out[(size_t)(bx + r) * ldo + by + tx] = f2b(tile[tx][r]);
    }
}

// LayerNorm: f32 in -> bf16 out
__global__ __launch_bounds__(128) void ln_kernel(
    const float* __restrict__ src, unsigned short* __restrict__ dst,
    const float* __restrict__ g, const float* __restrict__ bta) {
    size_t row = blockIdx.x;
    int t = threadIdx.x;
    const float* s = src + row * DIMC;
    float4 x = *(const float4*)(s + t * 4);
    float sum = x.x + x.y + x.z + x.w;
    float sq = x.x * x.x + x.y * x.y + x.z * x.z + x.w * x.w;
    #pragma unroll
    for (int o = 32; o; o >>= 1) { sum += __shfl_down(sum, o, 64); sq += __shfl_down(sq, o, 64); }
    __shared__ float sh[4];
    if ((t & 63) == 0) { sh[(t >> 6) * 2] = sum; sh[(t >> 6) * 2 + 1] = sq; }
    __syncthreads();
    sum = sh[0] + sh[2]; sq = sh[1] + sh[3];
    float mean = sum * (1.0f / DIMC);
    float var = sq * (1.0f / DIMC) - mean * mean;
    float rstd = rsqrtf(fmaxf(var, 0.0f) + 1e-5f);
    float4 gv = *(const float4*)(g + t * 4);
    float4 bv = *(const float4*)(bta + t * 4);
    ushort4 ov;
    ov.x = f2b((x.x - mean) * rstd * gv.x + bv.x);
    ov.y = f2b((x.y - mean) * rstd * gv.y + bv.y);
    ov.z = f2b((x.z - mean) * rstd * gv.z + bv.z);
    ov.w = f2b((x.w - mean) * rstd * gv.w + bv.w);
    *(ushort4*)(dst + row * DIMC + t * 4) = ov;
}

// ================= 256x128 MFMA GEMM, BK=32, 3-slot rotating LDS (72KB -> 2 blocks/CU) =================
// Schedule identical to r16 (replay-proven). SWZ=1: XCD-chunked remap (gridDim.y%8==0).
// EPI: 1 gelu->bf16; 2 f32 +=; 3 f32 +extra[batch]; 6 bf16 split store; 7 bf16 head-softmax;
//      8 bf16 TRANSPOSED split store (per-wave LDS transpose; Cv/Cv2 are [512][32768]).
template <int EPI, int SWZ>
__global__ __launch_bounds__(512, 4) void gemm256(
    const unsigned short* __restrict__ A, int lda,
    const unsigned short* __restrict__ Bt, int ldb,
    const float* __restrict__ bias,
    const float* __restrict__ extra, int batch_rows,
    void* __restrict__ Cv, void* __restrict__ Cv2,
    int M, int N, int K,
    size_t b_stride, int rows_per_batch) {
    extern __shared__ char lds[];
    const int tid = threadIdx.x;
    const int lane = tid & 63, wv = tid >> 6;
    const int wr = wv >> 1, wc = wv & 1;     // 4 x 2 waves
    const int lr = lane & 15, lch = lane >> 4;

    int bxi = blockIdx.x, byi = blockIdx.y;
    if constexpr (SWZ) {
        int l = byi * gridDim.x + bxi;
        int xcd = l & 7, j = l >> 3;
        byi = xcd * (gridDim.y >> 3) + j / gridDim.x;
        bxi = j % gridDim.x;
    }
    const int bm = byi * 256, bn = bxi * 128;

    const unsigned short* Bb = Bt;
    if (rows_per_batch) Bb = Bt + (size_t)(bm / rows_per_batch) * b_stride;

    const int srow = tid >> 2;
    const int schunk = tid & 3;

    auto stage = [&](int s, int kcol) {
        char* dstA = lds + (size_t)s * 24576;
        #pragma unroll
        for (int i = 0; i < 2; ++i) {
            int row = srow + 128 * i;
            int gc = schunk ^ ((row >> 1) & 3);
            GLOAD16((const char*)(A + (size_t)(bm + row) * lda + kcol) + gc * 16,
                    dstA + (size_t)(tid + 512 * i) * 16);
        }
        char* dstB = lds + (size_t)s * 24576 + 16384;
        {
            int row = srow;
            int gc = schunk ^ ((row >> 1) & 3);
            GLOAD16((const char*)(Bb + (size_t)(bn + row) * ldb + kcol) + gc * 16,
                    dstB + (size_t)tid * 16);
        }
    };

    f32x4 acc[4][4] = {};
    const int nt = K >> 5;

    stage(0, 0);
    stage(1, 32);
    __builtin_amdgcn_sched_barrier(0);
    asm volatile("s_waitcnt vmcnt(3)" ::: "memory");
    __builtin_amdgcn_sched_barrier(0);
    __builtin_amdgcn_s_barrier();

    int slot = 0;
    for (int t = 0; t < nt; ++t) {
        const char* base = lds + (size_t)slot * 24576;
        bf16x8 afr[4], bfr[4];
        #pragma unroll
        for (int n = 0; n < 4; ++n) {
            int bc = wc * 64 + n * 16 + lr;
            bfr[n] = *(const bf16x8*)(base + 16384 + bc * 64 + ((lch ^ ((bc >> 1) & 3)) << 4));
        }
        #pragma unroll
        for (int m = 0; m < 4; ++m) {
            int ar = wr * 64 + m * 16 + lr;
            afr[m] = *(const bf16x8*)(base + ar * 64 + ((lch ^ ((ar >> 1) & 3)) << 4));
        }
        const bool pf2 = (t + 2 < nt);
        if (pf2) {
            int s2 = slot >= 1 ? slot - 1 : 2;   // (t+2)%3
            stage(s2, (t + 2) << 5);
        }
        __builtin_amdgcn_sched_barrier(0);
        asm volatile("s_waitcnt lgkmcnt(0)" ::: "memory");
        __builtin_amdgcn_sched_barrier(0);
        __builtin_amdgcn_s_setprio(1);
        #pragma unroll
        for (int m = 0; m < 4; ++m)
            #pragma unroll
            for (int n = 0; n < 4; ++n)
                acc[m][n] = __builtin_amdgcn_mfma_f32_16x16x32_bf16(
                    afr[m], bfr[n], acc[m][n], 0, 0, 0);
        __builtin_amdgcn_s_setprio(0);
        if (t + 1 < nt) {
            if (pf2) asm volatile("s_waitcnt vmcnt(3)" ::: "memory");
            else     asm volatile("s_waitcnt vmcnt(0)" ::: "memory");
            __builtin_amdgcn_sched_barrier(0);
        }
        __builtin_amdgcn_s_barrier();
        slot = slot < 2 ? slot + 1 : 0;
    }

    const int g4 = lch * 4;
    if constexpr (EPI == 7) {
        #pragma unroll
        for (int m = 0; m < 4; ++m)
            #pragma unroll
            for (int r = 0; r < 4; ++r) {
                float v0 = acc[m][0][r], v1 = acc[m][1][r];
                float v2 = acc[m][2][r], v3 = acc[m][3][r];
                float mx = fmaxf(fmaxf(v0, v1), fmaxf(v2, v3));
                #pragma unroll
                for (int o = 1; o < 16; o <<= 1) mx = fmaxf(mx, __shfl_xor(mx, o, 64));
                float e0 = __expf(v0 - mx), e1 = __expf(v1 - mx);
                float e2 = __expf(v2 - mx), e3 = __expf(v3 - mx);
                float s = e0 + e1 + e2 + e3;
                #pragma unroll
                for (int o = 1; o < 16; o <<= 1) s += __shfl_xor(s, o, 64);
                float sc = 0.125f / s;
                int rr = bm + wr * 64 + m * 16 + g4 + r;
                unsigned short* dst = (unsigned short*)Cv + (size_t)rr * N + bn + wc * 64 + lr;
                dst[0]  = f2b(e0 * sc);
                dst[16] = f2b(e1 * sc);
                dst[32] = f2b(e2 * sc);
                dst[48] = f2b(e3 * sc);
            }
    } else if constexpr (EPI == 8) {
        // transposed split store: per-wave LDS transpose (64 cols x 68-u16 stride, 8.5KB/wave)
        unsigned short* tb = (unsigned short*)(lds + (size_t)wv * 8704);
        #pragma unroll
        for (int m = 0; m < 4; ++m)
            #pragma unroll
            for (int n = 0; n < 4; ++n)
                #pragma unroll
                for (int r = 0; r < 4; ++r) {
                    int row_l = m * 16 + g4 + r;
                    int col_l = n * 16 + lr;
                    tb[col_l * 68 + row_l] = f2b(acc[m][n][r]);
                }
        asm volatile("s_waitcnt lgkmcnt(0)" ::: "memory");
        __builtin_amdgcn_sched_barrier(0);
        #pragma unroll
        for (int q2 = 0; q2 < 8; ++q2) {
            int col_l = (lane >> 3) + q2 * 8;
            int row0 = (lane & 7) * 8;
            ushort4 lo = *(const ushort4*)(tb + col_l * 68 + row0);
            ushort4 hi = *(const ushort4*)(tb + col_l * 68 + row0 + 4);
            int colg = bn + wc * 64 + col_l;
            int rowg = bm + wr * 64 + row0;
            unsigned short* dstb = (colg < 512) ? (unsigned short*)Cv : (unsigned short*)Cv2;
            unsigned short* d = dstb + (size_t)(colg & 511) * ROWS + rowg;
            *(ushort4*)(d) = lo;
            *(ushort4*)(d + 4) = hi;
        }
    } else {
        #pragma unroll
        for (int m = 0; m < 4; ++m)
            #pragma unroll
            for (int n = 0; n < 4; ++n) {
                int col = bn + wc * 64 + n * 16 + lr;
                #pragma unroll
                for (int r = 0; r < 4; ++r) {
                    int rr = bm + wr * 64 + m * 16 + g4 + r;
                    float v = acc[m][n][r];
                    if (EPI == 1) {
                        ((unsigned short*)Cv)[(size_t)rr * N + col] = f2b(gelu_tanh(v + bias[col]));
                    } else if (EPI == 2) {
                        ((float*)Cv)[(size_t)rr * N + col] += v + bias[col];
                    } else if (EPI == 3) {
                        ((float*)Cv)[(size_t)rr * N + col] = v + extra[(size_t)(rr / batch_rows) * N + col];
                    } else if (EPI == 6) {
                        unsigned short* dst = (col >> 9) ? (unsigned short*)Cv2 : (unsigned short*)Cv;
                        dst[(size_t)rr * 512 + (col & 511)] = f2b(v);
                    }
                }
            }
    }
}

// ---------------- legacy 128x128 MFMA GEMM (tiny wcomp only) ----------------
#define BM 128
#define BN 128
#define BK 64

template <int EPI>
__global__ __launch_bounds__(256) void gemm_mfma(
    const unsigned short* __restrict__ A, int lda,
    const unsigned short* __restrict__ Bt, int ldb,
    void* __restrict__ Cv, int M, int N, int K, int ldo) {
    __shared__ unsigned short As[2][BM * BK];
    __shared__ unsigned short Bs[2][BN * BK];
    int bm = blockIdx.y * BM, bn = blockIdx.x * BN;
    int tid = threadIdx.x;
    int lane = tid & 63, wv = tid >> 6;
    int wr = (wv >> 1) * 64, wc = (wv & 1) * 64;
    int g16 = (lane >> 4) << 4;
    int lr = lane & 15;
    int sw = (lr & 7) << 4;

    int srow = tid >> 3;
    int skb = (tid & 7) * 16;
    int sxor = skb ^ ((srow & 7) << 4);

    auto stage = [&](int buf, int k0) {
        #pragma unroll
        for (int i = 0; i < 4; ++i) {
            int row = srow + 32 * i;
            GLOAD16((const char*)(A + (size_t)(bm + row) * lda + k0) + sxor,
                    (char*)As[buf] + (size_t)(tid + 256 * i) * 16);
        }
        #pragma unroll
        for (int i = 0; i < 4; ++i) {
            int row = srow + 32 * i;
            GLOAD16((const char*)(Bt + (size_t)(bn + row) * ldb + k0) + sxor,
                    (char*)Bs[buf] + (size_t)(tid + 256 * i) * 16);
        }
    };

    f32x4 acc[4][4] = {};
    int nt = K / BK;
    stage(0, 0);
    __syncthreads();
    for (int t = 0; t < nt; ++t) {
        int cur = t & 1;
        if (t + 1 < nt) stage(cur ^ 1, (t + 1) * BK);
        const char* Ab = (const char*)As[cur];
        const char* Bp = (const char*)Bs[cur];
        #pragma unroll
        for (int s = 0; s < 2; ++s) {
            int koff = s * 64 + g16;
            bf16x8 af[4], bw[4];
            #pragma unroll
            for (int f = 0; f < 4; ++f) {
                int ar = wr + f * 16 + lr;
                af[f] = *(const bf16x8*)(Ab + ar * 128 + (koff ^ sw));
                int br = wc + f * 16 + lr;
                bw[f] = *(const bf16x8*)(Bp + br * 128 + (koff ^ sw));
            }
            #pragma unroll
            for (int f = 0; f < 4; ++f)
                #pragma unroll
                for (int j = 0; j < 4; ++j)
                    acc[f][j] = __builtin_amdgcn_mfma_f32_16x16x32_bf16(
                        af[f], bw[j], acc[f][j], 0, 0, 0);
        }
        __syncthreads();
    }

    int g4 = (lane >> 4) * 4;
    #pragma unroll
    for (int f = 0; f < 4; ++f) {
        #pragma unroll
        for (int j = 0; j < 4; ++j) {
            int col = bn + wc + j * 16 + lr;
            #pragma unroll
            for (int r = 0; r < 4; ++r) {
                int rr = bm + wr + f * 16 + g4 + r;
                float v = acc[f][j][r];
                if (EPI == 4) {
                    ((unsigned short*)Cv)[(size_t)rr * N + col] = f2b(v);
                } else if (EPI == 5) {
                    ((unsigned short*)Cv)[(size_t)col * ldo + rr] = f2b(v);
                }
            }
        }
    }
}

// ---------------- k column-softmax stats, single pass on kbT rows ----------------
// segment = (b, feat): 8192 contiguous bf16. One wave per segment.
__global__ __launch_bounds__(256) void ksm_rows(
    const unsigned short* __restrict__ kbT, float* __restrict__ Mst, float* __restrict__ Sinv) {
    int seg = blockIdx.x * 4 + (threadIdx.x >> 6);   // 0..2047
    int lane = threadIdx.x & 63;
    int b = seg >> 9, f = seg & 511;
    const unsigned short* p = kbT + (size_t)f * ROWS + (size_t)b * NN;
    float m = -1e30f, s = 0.f;
    for (int it = 0; it < 16; ++it) {
        us8 v = *(const us8*)(p + (size_t)(it * 64 + lane) * 8);
        #pragma unroll
        for (int j = 0; j < 8; ++j) {
            float x = b2f(v[j]);
            float n = fmaxf(m, x);
            s = s * __expf(m - n) + __expf(x - n);
            m = n;
        }
    }
    #pragma unroll
    for (int o = 1; o < 64; o <<= 1) {
        float mo = __shfl_xor(m, o, 64), so = __shfl_xor(s, o, 64);
        float n = fmaxf(m, mo);
        s = s * __expf(m - n) + so * __expf(mo - n);
        m = n;
    }
    if (lane == 0) { Mst[seg] = m; Sinv[seg] = 1.f / s; }
}

// ---------------- context = sum_n kx[n,d]*v[n,e] via MFMA on transposed operands ----------------
// grid (16, HEADS, NB), 256 thr = 4 waves; wave w covers 128 n (4 chunks of 32).
// A-frag: kbT row d (exp applied inline; d is lane-constant -> scalar Mst/Sinv).
// B-frag: vbT row e, bit-cast. acc[i][j] covers ctx[16i..][16j..].
__global__ __launch_bounds__(256) void context_mfma(
    const unsigned short* __restrict__ kbT, const unsigned short* __restrict__ vbT,
    const float* __restrict__ Mst, const float* __restrict__ Sinv,
    float* __restrict__ ctx) {
    __shared__ float cbuf[4096];
    int b = blockIdx.z, hd = blockIdx.y, rb = blockIdx.x;
    int w = threadIdx.x >> 6, lane = threadIdx.x & 63;
    int lr = lane & 15, lch = lane >> 4;
    size_t nb = (size_t)b * NN + (size_t)rb * 512 + (size_t)w * 128;
    float mv[4], sv[4];
    #pragma unroll
    for (int i = 0; i < 4; ++i) {
        mv[i] = Mst[b * DIMC + hd * 64 + i * 16 + lr];
        sv[i] = Sinv[b * DIMC + hd * 64 + i * 16 + lr];
    }
    f32x4 acc[4][4] = {};
    for (int c = 0; c < 4; ++c) {
        size_t n0 = nb + c * 32 + lch * 8;
        bf16x8 af[4], bfv[4];
        #pragma unroll
        for (int i = 0; i < 4; ++i) {
            us8 kv = *(const us8*)(kbT + (size_t)(hd * 64 + i * 16 + lr) * ROWS + n0);
            bf16x8 a;
            #pragma unroll
            for (int j = 0; j < 8; ++j)
                a[j] = (short)f2b(__expf(b2f(kv[j]) - mv[i]) * sv[i]);
            af[i] = a;
            us8 vv = *(const us8*)(vbT + (size_t)(hd * 64 + i * 16 + lr) * ROWS + n0);
            bfv[i] = __builtin_bit_cast(bf16x8, vv);
        }
        #pragma unroll
        for (int i = 0; i < 4; ++i)
            #pragma unroll
            for (int j = 0; j < 4; ++j)
                acc[i][j] = __builtin_amdgcn_mfma_f32_16x16x32_bf16(
                    af[i], bfv[j], acc[i][j], 0, 0, 0);
    }
    // cross-wave reduce in LDS
    for (int w2 = 0; w2 < 4; ++w2) {
        if (w == w2) {
            #pragma unroll
            for (int i = 0; i < 4; ++i)
                #pragma unroll
                for (int j = 0; j < 4; ++j)
                    #pragma unroll
                    for (int r = 0; r < 4; ++r) {
                        int row = i * 16 + lch * 4 + r;
                        int col = j * 16 + lr;
                        int idx = row * 64 + col;
                        cbuf[idx] = (w2 == 0) ? acc[i][j][r] : cbuf[idx] + acc[i][j][r];
                    }
        }
        __syncthreads();
    }
    size_t cbase = (size_t)(b * HEADS + hd) * 4096;
    #pragma unroll
    for (int q = 0; q < 16; ++q) {
        int idx = threadIdx.x * 16 + q;
        atomicAdd(&ctx[cbase + idx], cbuf[idx]);
    }
}

// ---------------- caw = ctx @ aow (per batch) ----------------
__global__ __launch_bounds__(256) void caw_kernel(const float* __restrict__ ctx,
                                                  const float* __restrict__ aow,
                                                  float* __restrict__ caw) {
    int nt = blockIdx.x, hd = blockIdx.y, b = blockIdx.z;
    int tid = threadIdx.x, tx = tid & 15, ty = tid >> 4;
    __shared__ float cs[64][68];
    __shared__ float aw[64][68];
    #pragma unroll
    for (int i = 0; i < 4; ++i) {
        int idx = tid + 256 * i;
        int r = idx >> 4, c4 = (idx & 15) * 4;
        *(float4*)&cs[r][c4] = *(const float4*)(ctx + ((size_t)(b * HEADS + hd) * 64 + r) * 64 + c4);
        *(float4*)&aw[r][c4] = *(const float4*)(aow + (size_t)(hd * 64 + r) * DIMC + nt * 64 + c4);
    }
    __syncthreads();
    float acc[4][4] = {};
    for (int e = 0; e < 64; ++e) {
        float av[4];
        #pragma unroll
        for (int i = 0; i < 4; ++i) av[i] = cs[ty * 4 + i][e];
        float4 b4 = *(const float4*)&aw[e][tx * 4];
        float bv[4] = {b4.x, b4.y, b4.z, b4.w};
        #pragma unroll
        for (int i = 0; i < 4; ++i)
            #pragma unroll
            for (int j = 0; j < 4; ++j)
                acc[i][j] = fmaf(av[i], bv[j], acc[i][j]);
    }
    #pragma unroll
    for (int i = 0; i < 4; ++i)
        #pragma unroll
        for (int j = 0; j < 4; ++j)
            caw[(size_t)b * DIMC * DIMC + (size_t)(hd * 64 + ty * 4 + i) * DIMC + nt * 64 + tx * 4 + j]
                = acc[i][j];
}

// ---------------- pos head ----------------
__global__ __launch_bounds__(256) void pos_kernel(
    const float* __restrict__ x, const float* __restrict__ w,
    const float* __restrict__ b2, float* __restrict__ out) {
    int lane = threadIdx.x & 63;
    size_t row = (size_t)blockIdx.x * 4 + (threadIdx.x >> 6);
    const float* xp = x + row * DIMC;
    float acc0 = 0.f, acc1 = 0.f;
    #pragma unroll
    for (int i = 0; i < 2; ++i) {
        float4 xv = *(const float4*)(xp + lane * 8 + i * 4);
        const float* wp = w + (size_t)(lane * 8 + i * 4) * 2;
        float4 w0 = *(const float4*)(wp);
        float4 w1 = *(const float4*)(wp + 4);
        acc0 += xv.x * w0.x + xv.y * w0.z + xv.z * w1.x + xv.w * w1.z;
        acc1 += xv.x * w0.y + xv.y * w0.w + xv.z * w1.y + xv.w * w1.w;
    }
    #pragma unroll
    for (int o = 32; o; o >>= 1) { acc0 += __shfl_down(acc0, o, 64); acc1 += __shfl_down(acc1, o, 64); }
    if (lane == 0) {
        out[row * 2] = acc0 + b2[0];
        out[row * 2 + 1] = acc1 + b2[1];
    }
}

// ---------------- launch ----------------
extern "C" void kernel_launch(void* const* d_in, const int* in_sizes, int n_in,
                              void* d_out, int out_size, void* d_ws, size_t ws_size,
                              hipStream_t stream) {
    (void)in_sizes; (void)n_in; (void)out_size; (void)ws_size;
    const float* nf  = (const float*)d_in[0];
    const float* dt  = (const float*)d_in[1];
    const float* pos = (const float*)d_in[2];
    const float* msk = (const float*)d_in[3];
    const float* yyw = (const float*)d_in[4];
    const float* yyb = (const float*)d_in[5];
    const float* p1w = (const float*)d_in[6];
    const float* p1b = (const float*)d_in[7];
    const float* p2w = (const float*)d_in[8];
    const float* p2b = (const float*)d_in[9];
    const float* lxw = (const float*)d_in[10];
    const float* lxb = (const float*)d_in[11];
    const float* cw  = (const float*)d_in[12];
    const float* cb  = (const float*)d_in[13];
    const float* l1g = (const float*)d_in[14];
    const float* l1b = (const float*)d_in[15];
    const float* qw  = (const float*)d_in[16];
    const float* kw  = (const float*)d_in[17];
    const float* vw  = (const float*)d_in[18];
    const float* aow = (const float*)d_in[19];
    const float* aob = (const float*)d_in[20];
    const float* l2g = (const float*)d_in[21];
    const float* l2b = (const float*)d_in[22];
    const float* f1w = (const float*)d_in[23];
    const float* f1b = (const float*)d_in[24];
    const float* f2w = (const float*)d_in[25];
    const float* f2b_ = (const float*)d_in[26];
    const float* hpw = (const float*)d_in[27];
    const float* hpb = (const float*)d_in[28];

    float* ws = (float*)d_ws;
    unsigned short* catA_u  = (unsigned short*)(ws + OFF_R0);
    unsigned short* hb_u    = (unsigned short*)(ws + OFF_R0);
    float*          caw     = ws + OFF_CAW;
    unsigned short* kbT_u   = (unsigned short*)(ws + OFF_R1);
    unsigned short* qb_u    = (unsigned short*)(ws + OFF_R1);
    unsigned short* mid_u   = (unsigned short*)(ws + OFF_R1);   // [16384][2048] spans R1+R2
    unsigned short* vbT_u   = (unsigned short*)(ws + OFF_R2);
    unsigned short* cawT_u  = (unsigned short*)(ws + OFF_R2);
    unsigned short* catWT_u = (unsigned short*)(ws + OFF_CATWT);
    unsigned short* kvT_u   = (unsigned short*)(ws + OFF_KVT);
    unsigned short* qwT_u   = (unsigned short*)(ws + OFF_QWT);
    unsigned short* f1wT_u  = (unsigned short*)(ws + OFF_F1WT);
    unsigned short* f2wT_u  = (unsigned short*)(ws + OFF_F2WT);
    unsigned short* lxwb_u  = (unsigned short*)(ws + OFF_LXWB);
    unsigned short* cw0T_u  = (unsigned short*)(ws + OFF_CW0T);
    float* yv   = ws + OFF_Y;
    float* bbf  = ws + OFF_BB;
    float* Mst  = ws + OFF_M;
    float* Sinv = ws + OFF_SINV;
    float* ctx  = ws + OFF_CTX;

    float* xout = (float*)d_out;
    float* yout = xout + (size_t)ROWS * DIMC;
    float* pout = yout + NB * DT;

    // allow 72KB dynamic LDS for gemm256 instantiations
    hipFuncSetAttribute(reinterpret_cast<const void*>(&gemm256<1, 1>),
                        hipFuncAttributeMaxDynamicSharedMemorySize, 73728);
    hipFuncSetAttribute(reinterpret_cast<const void*>(&gemm256<2, 1>),
                        hipFuncAttributeMaxDynamicSharedMemorySize, 73728);
    hipFuncSetAttribute(reinterpret_cast<const void*>(&gemm256<3, 1>),
                        hipFuncAttributeMaxDynamicSharedMemorySize, 73728);
    hipFuncSetAttribute(reinterpret_cast<const void*>(&gemm256<7, 1>),
                        hipFuncAttributeMaxDynamicSharedMemorySize, 73728);
    hipFuncSetAttribute(reinterpret_cast<const void*>(&gemm256<8, 1>),
                        hipFuncAttributeMaxDynamicSharedMemorySize, 73728);

    // prologue scalars + weight conversions
    y_kernel<<<4, 128, 0, stream>>>(dt, yyw, yyb, yv, yout);
    bb_kernel<<<8, 256, 0, stream>>>(lxb, cw, cb, yv, bbf);
    conv_bf16<<<128, 256, 0, stream>>>(lxw, lxwb_u, 32768);
    transconv<<<dim3(16, 16), 256, 0, stream>>>(cw, cw0T_u, 512, 512, 512);
    transconv<<<dim3(16, 2), 256, 0, stream>>>(cw + (size_t)DIMC * DIMC, catWT_u + 512, 64, 512, KCATP);
    zcat_kernel<<<128, 256, 0, stream>>>(catWT_u);
    transconv<<<dim3(16, 16), 256, 0, stream>>>(kw, kvT_u, 512, 512, 512);
    transconv<<<dim3(16, 16), 256, 0, stream>>>(vw, kvT_u + (size_t)512 * 512, 512, 512, 512);
    transconv<<<dim3(16, 16), 256, 0, stream>>>(qw, qwT_u, 512, 512, 512);
    transconv<<<dim3(64, 16), 256, 0, stream>>>(f1w, f1wT_u, 512, 2048, 512);
    transconv<<<dim3(16, 64), 256, 0, stream>>>(f2w, f2wT_u, 2048, 512, 2048);
    conv_bf16_strided<<<8192, 256, 0, stream>>>(nf, catA_u, KCATP);
    delta_kernel<<<8192, 256, 0, stream>>>(pos, msk, p1w, p1b, p2w, p2b, catA_u);

    // catWT cols 0..511 = (lxw @ cw0)^T
    gemm_mfma<5><<<dim3(4, 4), 256, 0, stream>>>(
        lxwb_u, 512, cw0T_u, 512, catWT_u, 512, 512, 512, KCATP);

    // cat = catA @ catWT^T + bb[batch] -> xout (f32)
    gemm256<3, 1><<<dim3(4, 128), 512, 73728, stream>>>(
        catA_u, KCATP, catWT_u, KCATP, nullptr, bbf, NN,
        xout, nullptr, ROWS, 512, KCATP, 0, 0);

    // LN1: xout -> hb
    ln_kernel<<<ROWS, 128, 0, stream>>>(xout, hb_u, l1g, l1b);

    // fused k+v projection, TRANSPOSED split store -> kbT (R1), vbT (R2)
    gemm256<8, 1><<<dim3(8, 128), 512, 73728, stream>>>(
        hb_u, 512, kvT_u, 512, nullptr, nullptr, 0,
        kbT_u, vbT_u, ROWS, 1024, 512, 0, 0);

    // k sequence-softmax stats (single pass on kbT rows)
    ksm_rows<<<512, 256, 0, stream>>>(kbT_u, Mst, Sinv);

    // context via MFMA (consumes kbT, vbT)
    hipMemsetAsync(ctx, 0, (size_t)NB * HEADS * 64 * 64 * sizeof(float), stream);
    context_mfma<<<dim3(16, HEADS, NB), 256, 0, stream>>>(kbT_u, vbT_u, Mst, Sinv, ctx);

    // q projection + fused feature-softmax epilogue -> qb (R1; kbT dead)
    gemm256<7, 1><<<dim3(4, 128), 512, 73728, stream>>>(
        hb_u, 512, qwT_u, 512, nullptr, nullptr, 0,
        qb_u, nullptr, ROWS, 512, 512, 0, 0);

    // compose ctx with attn_out_w per batch; transpose into R2 (vbT dead)
    caw_kernel<<<dim3(8, 8, 4), 256, 0, stream>>>(ctx, aow, caw);
    for (int b = 0; b < NB; ++b)
        transconv<<<dim3(16, 16), 256, 0, stream>>>(caw + (size_t)b * 262144,
                                                    cawT_u + (size_t)b * 262144, 512, 512, 512);

    // x += qsm @ caw[b]^T + aob
    gemm256<2, 1><<<dim3(4, 128), 512, 73728, stream>>>(
        qb_u, 512, cawT_u, 512, aob, nullptr, 0,
        xout, nullptr, ROWS, 512, 512, 262144, NN);

    // FF block: LN2 then per-2-batch {ff1 N=2048 -> mid; ff2 K=2048}
    ln_kernel<<<ROWS, 128, 0, stream>>>(xout, hb_u, l2g, l2b);
    for (int bp = 0; bp < 2; ++bp) {
        const unsigned short* hbp = hb_u + (size_t)bp * 16384 * DIMC;
        gemm256<1, 1><<<dim3(16, 64), 512, 73728, stream>>>(
            hbp, 512, f1wT_u, 512, f1b, nullptr, 0,
            mid_u, nullptr, 16384, FF, 512, 0, 0);
        gemm256<2, 1><<<dim3(4, 64), 512, 73728, stream>>>(
            mid_u, 2048, f2wT_u, 2048, f2b_, nullptr, 0,
            xout + (size_t)bp * 16384 * DIMC, nullptr, 16384, 512, 2048, 0, 0);
    }

    pos_kernel<<<8192, 256, 0, stream>>>(xout, hpw, hpb, pout);
}

// Round 18
// 535.768 us; speedup vs baseline: 1.7700x; 1.1880x over previous
//
#include <hip/hip_runtime.h>
#include <hip/hip_bf16.h>
#include <math.h>

// ---------------- constants ----------------
#define NB 4
#define NN 8192
#define ROWS (NB*NN)          // 32768
#define DIMC 512
#define HEADS 8
#define DT 128
#define DELTA 64
#define FF 2048
#define KCATP 640             // 576 padded to 640; pad cols zeroed on BOTH A and B sides every call

// ---------------- workspace layout (FLOAT units) ----------------
#define OFF_R0     ((size_t)0)          // catA [32768][640]bf16 -> hb [32768][512]bf16
#define OFF_CAW    ((size_t)8388608)    // part f32 [16][32][4096] (8MB) -> caw f32 [4][512][512]
#define OFF_R1     ((size_t)10485760)   // kbT [512][32768]bf16 -> qb -> mid(lo)
#define OFF_R2     ((size_t)18874368)   // vbT [512][32768]bf16 -> cawT -> mid(hi)
#define OFF_CATWT  ((size_t)27262976)   // bf16 [512][640]
#define OFF_KVT    ((size_t)27426816)   // bf16 [1024][512]
#define OFF_QWT    ((size_t)27688960)   // bf16 [512][512]
#define OFF_F1WT   ((size_t)27820032)   // bf16 [2048][512]
#define OFF_F2WT   ((size_t)28344320)   // bf16 [512][2048]
#define OFF_LXWB   ((size_t)28868608)   // bf16 [512][512]
#define OFF_CW0T   ((size_t)28999680)   // bf16 [512][512]
#define OFF_Y      ((size_t)29130752)
#define OFF_BB     ((size_t)29131264)
#define OFF_M      ((size_t)29395456)
#define OFF_SINV   ((size_t)29397504)
#define OFF_CTX    ((size_t)29399552)
// end = 29,530,624 floats = 118.1 MB

typedef __attribute__((ext_vector_type(8))) short bf16x8;
typedef __attribute__((ext_vector_type(4))) float f32x4;
typedef __attribute__((ext_vector_type(8))) unsigned short us8;

static __device__ __forceinline__ unsigned short f2b(float x) {
    __hip_bfloat16 h = __float2bfloat16(x);
    return __builtin_bit_cast(unsigned short, h);
}
static __device__ __forceinline__ float b2f(unsigned short u) {
    return __bfloat162float(__builtin_bit_cast(__hip_bfloat16, u));
}
// gelu(tanh approx) = x - x/(e^{2z}+1); overflow-safe, single v_exp_f32.
static __device__ __forceinline__ float gelu_tanh(float x) {
    float z2 = 1.5957691216057308f * (x + 0.044715f * x * x * x);
    float t = __expf(z2);
    return x - x / (t + 1.0f);
}

#define GLOAD16(g, l) __builtin_amdgcn_global_load_lds( \
    (const __attribute__((address_space(1))) void*)(g), \
    (__attribute__((address_space(3))) void*)(l), 16, 0, 0)

// ---------------- tiny prologue kernels ----------------
__global__ void y_kernel(const float* __restrict__ dt, const float* __restrict__ yyw,
                         const float* __restrict__ yyb, float* __restrict__ y_ws,
                         float* __restrict__ y_out) {
    int idx = blockIdx.x * 128 + threadIdx.x;   // 512
    int b = idx >> 7, j = idx & 127;
    float acc = yyb[j];
    for (int c = 0; c < DT; ++c) acc += dt[b * DT + c] * yyw[c * DT + j];
    y_ws[idx] = acc;
    y_out[idx] = acc;
}

__global__ void bb_kernel(const float* __restrict__ linxb, const float* __restrict__ catw,
                          const float* __restrict__ catb, const float* __restrict__ y,
                          float* __restrict__ bb) {
    int idx = blockIdx.x * 256 + threadIdx.x;   // 2048
    int b = idx >> 9, n = idx & 511;
    float acc = catb[n];
    for (int c = 0; c < DIMC; ++c) acc += linxb[c] * catw[(size_t)c * DIMC + n];
    const float* cw3 = catw + (size_t)(DIMC + DELTA) * DIMC;
    for (int j = 0; j < DT; ++j) acc += y[b * DT + j] * cw3[(size_t)j * DIMC + n];
    bb[idx] = acc;
}

// delta -> catA columns 512..575; ALSO zero pad cols 576..639 (replay safety)
__global__ __launch_bounds__(256) void delta_kernel(
    const float* __restrict__ pos, const float* __restrict__ mask,
    const float* __restrict__ w1, const float* __restrict__ b1,
    const float* __restrict__ w2, const float* __restrict__ b2,
    unsigned short* __restrict__ catA) {
    int lane = threadIdx.x & 63;
    size_t row = (size_t)blockIdx.x * 4 + (threadIdx.x >> 6);
    float mk = mask[row];
    float px = pos[row * 2] * mk, py = pos[row * 2 + 1] * mk;
    float nrm = sqrtf(px * px + py * py) + 1e-7f;
    float ux = px / nrm, uy = py / nrm;
    float t1 = fmaxf(ux * w1[lane] + uy * w1[64 + lane] + b1[lane], 0.0f);
    float acc = b2[lane];
    #pragma unroll
    for (int j = 0; j < 64; ++j) {
        float tv = __shfl(t1, j, 64);
        acc += tv * w2[j * 64 + lane];
    }
    catA[row * KCATP + DIMC + lane] = f2b(acc);
    catA[row * KCATP + 576 + lane] = 0;
}

// zero catWT pad cols 576..639 (B side)
__global__ void zcat_kernel(unsigned short* __restrict__ catWT) {
    int idx = blockIdx.x * 256 + threadIdx.x;   // 32768
    int n = idx >> 6, c = 576 + (idx & 63);
    catWT[(size_t)n * KCATP + c] = 0;
}

// f32 -> bf16 flat convert
__global__ void conv_bf16(const float* __restrict__ in, unsigned short* __restrict__ out, int n8) {
    int i = blockIdx.x * 256 + threadIdx.x;
    if (i >= n8) return;
    const float* p = in + (size_t)i * 8;
    us8 o;
    #pragma unroll
    for (int j = 0; j < 8; ++j) o[j] = f2b(p[j]);
    *(us8*)(out + (size_t)i * 8) = o;
}

// f32 [rows][512] -> bf16 out[row*ldo + c]
__global__ void conv_bf16_strided(const float* __restrict__ in, unsigned short* __restrict__ out,
                                  int ldo) {
    int i = blockIdx.x * 256 + threadIdx.x;
    int row = i >> 6, c8 = (i & 63) * 8;
    const float* p = in + (size_t)row * DIMC + c8;
    us8 o;
    #pragma unroll
    for (int j = 0; j < 8; ++j) o[j] = f2b(p[j]);
    *(us8*)(out + (size_t)row * ldo + c8) = o;
}

// f32 [R][C] -> bf16 out[c*ldo + r]
__global__ __launch_bounds__(256) void transconv(const float* __restrict__ in,
                                                 unsigned short* __restrict__ out,
                                                 int R, int C, int ldo) {
    __shared__ float tile[32][33];
    int bx = blockIdx.x * 32;
    int by = blockIdx.y * 32;
    int tx = threadIdx.x & 31, ty = threadIdx.x >> 5;
    #pragma unroll
    for (int i = 0; i < 4; ++i) {
        int r = ty + i * 8;
        tile[r][tx] = in[(size_t)(by + r) * C + bx + tx];
    }
    __syncthreads();
    #pragma unroll
    for (int i = 0; i < 4; ++i) {
        int r = ty + i * 8;
        out[(size_t)(bx + r) * ldo + by + tx] = f2b(tile[tx][r]);
    }
}

// LayerNorm: f32 in -> bf16 out
__global__ __launch_bounds__(128) void ln_kernel(
    const float* __restrict__ src, unsigned short* __restrict__ dst,
    const float* __restrict__ g, const float* __restrict__ bta) {
    size_t row = blockIdx.x;
    int t = threadIdx.x;
    const float* s = src + row * DIMC;
    float4 x = *(const float4*)(s + t * 4);
    float sum = x.x + x.y + x.z + x.w;
    float sq = x.x * x.x + x.y * x.y + x.z * x.z + x.w * x.w;
    #pragma unroll
    for (int o = 32; o; o >>= 1) { sum += __shfl_down(sum, o, 64); sq += __shfl_down(sq, o, 64); }
    __shared__ float sh[4];
    if ((t & 63) == 0) { sh[(t >> 6) * 2] = sum; sh[(t >> 6) * 2 + 1] = sq; }
    __syncthreads();
    sum = sh[0] + sh[2]; sq = sh[1] + sh[3];
    float mean = sum * (1.0f / DIMC);
    float var = sq * (1.0f / DIMC) - mean * mean;
    float rstd = rsqrtf(fmaxf(var, 0.0f) + 1e-5f);
    float4 gv = *(const float4*)(g + t * 4);
    float4 bv = *(const float4*)(bta + t * 4);
    ushort4 ov;
    ov.x = f2b((x.x - mean) * rstd * gv.x + bv.x);
    ov.y = f2b((x.y - mean) * rstd * gv.y + bv.y);
    ov.z = f2b((x.z - mean) * rstd * gv.z + bv.z);
    ov.w = f2b((x.w - mean) * rstd * gv.w + bv.w);
    *(ushort4*)(dst + row * DIMC + t * 4) = ov;
}

// ================= 256x128 MFMA GEMM, BK=32, 3-slot rotating LDS (72KB -> 2 blocks/CU) =================
// Schedule identical to r16/r17 (replay-proven). SWZ=1: XCD-chunked remap (gridDim.y%8==0).
// EPI: 1 gelu->bf16; 2 f32 +=; 3 f32 +extra[batch]; 6 bf16 split store; 7 bf16 head-softmax;
//      8 bf16 TRANSPOSED split store (per-wave LDS transpose; Cv/Cv2 are [512][32768]).
template <int EPI, int SWZ>
__global__ __launch_bounds__(512, 4) void gemm256(
    const unsigned short* __restrict__ A, int lda,
    const unsigned short* __restrict__ Bt, int ldb,
    const float* __restrict__ bias,
    const float* __restrict__ extra, int batch_rows,
    void* __restrict__ Cv, void* __restrict__ Cv2,
    int M, int N, int K,
    size_t b_stride, int rows_per_batch) {
    extern __shared__ char lds[];
    const int tid = threadIdx.x;
    const int lane = tid & 63, wv = tid >> 6;
    const int wr = wv >> 1, wc = wv & 1;     // 4 x 2 waves
    const int lr = lane & 15, lch = lane >> 4;

    int bxi = blockIdx.x, byi = blockIdx.y;
    if constexpr (SWZ) {
        int l = byi * gridDim.x + bxi;
        int xcd = l & 7, j = l >> 3;
        byi = xcd * (gridDim.y >> 3) + j / gridDim.x;
        bxi = j % gridDim.x;
    }
    const int bm = byi * 256, bn = bxi * 128;

    const unsigned short* Bb = Bt;
    if (rows_per_batch) Bb = Bt + (size_t)(bm / rows_per_batch) * b_stride;

    const int srow = tid >> 2;
    const int schunk = tid & 3;

    auto stage = [&](int s, int kcol) {
        char* dstA = lds + (size_t)s * 24576;
        #pragma unroll
        for (int i = 0; i < 2; ++i) {
            int row = srow + 128 * i;
            int gc = schunk ^ ((row >> 1) & 3);
            GLOAD16((const char*)(A + (size_t)(bm + row) * lda + kcol) + gc * 16,
                    dstA + (size_t)(tid + 512 * i) * 16);
        }
        char* dstB = lds + (size_t)s * 24576 + 16384;
        {
            int row = srow;
            int gc = schunk ^ ((row >> 1) & 3);
            GLOAD16((const char*)(Bb + (size_t)(bn + row) * ldb + kcol) + gc * 16,
                    dstB + (size_t)tid * 16);
        }
    };

    f32x4 acc[4][4] = {};
    const int nt = K >> 5;

    stage(0, 0);
    stage(1, 32);
    __builtin_amdgcn_sched_barrier(0);
    asm volatile("s_waitcnt vmcnt(3)" ::: "memory");
    __builtin_amdgcn_sched_barrier(0);
    __builtin_amdgcn_s_barrier();

    int slot = 0;
    for (int t = 0; t < nt; ++t) {
        const char* base = lds + (size_t)slot * 24576;
        bf16x8 afr[4], bfr[4];
        #pragma unroll
        for (int n = 0; n < 4; ++n) {
            int bc = wc * 64 + n * 16 + lr;
            bfr[n] = *(const bf16x8*)(base + 16384 + bc * 64 + ((lch ^ ((bc >> 1) & 3)) << 4));
        }
        #pragma unroll
        for (int m = 0; m < 4; ++m) {
            int ar = wr * 64 + m * 16 + lr;
            afr[m] = *(const bf16x8*)(base + ar * 64 + ((lch ^ ((ar >> 1) & 3)) << 4));
        }
        const bool pf2 = (t + 2 < nt);
        if (pf2) {
            int s2 = slot >= 1 ? slot - 1 : 2;   // (t+2)%3
            stage(s2, (t + 2) << 5);
        }
        __builtin_amdgcn_sched_barrier(0);
        asm volatile("s_waitcnt lgkmcnt(0)" ::: "memory");
        __builtin_amdgcn_sched_barrier(0);
        __builtin_amdgcn_s_setprio(1);
        #pragma unroll
        for (int m = 0; m < 4; ++m)
            #pragma unroll
            for (int n = 0; n < 4; ++n)
                acc[m][n] = __builtin_amdgcn_mfma_f32_16x16x32_bf16(
                    afr[m], bfr[n], acc[m][n], 0, 0, 0);
        __builtin_amdgcn_s_setprio(0);
        if (t + 1 < nt) {
            if (pf2) asm volatile("s_waitcnt vmcnt(3)" ::: "memory");
            else     asm volatile("s_waitcnt vmcnt(0)" ::: "memory");
            __builtin_amdgcn_sched_barrier(0);
        }
        __builtin_amdgcn_s_barrier();
        slot = slot < 2 ? slot + 1 : 0;
    }

    const int g4 = lch * 4;
    if constexpr (EPI == 7) {
        #pragma unroll
        for (int m = 0; m < 4; ++m)
            #pragma unroll
            for (int r = 0; r < 4; ++r) {
                float v0 = acc[m][0][r], v1 = acc[m][1][r];
                float v2 = acc[m][2][r], v3 = acc[m][3][r];
                float mx = fmaxf(fmaxf(v0, v1), fmaxf(v2, v3));
                #pragma unroll
                for (int o = 1; o < 16; o <<= 1) mx = fmaxf(mx, __shfl_xor(mx, o, 64));
                float e0 = __expf(v0 - mx), e1 = __expf(v1 - mx);
                float e2 = __expf(v2 - mx), e3 = __expf(v3 - mx);
                float s = e0 + e1 + e2 + e3;
                #pragma unroll
                for (int o = 1; o < 16; o <<= 1) s += __shfl_xor(s, o, 64);
                float sc = 0.125f / s;
                int rr = bm + wr * 64 + m * 16 + g4 + r;
                unsigned short* dst = (unsigned short*)Cv + (size_t)rr * N + bn + wc * 64 + lr;
                dst[0]  = f2b(e0 * sc);
                dst[16] = f2b(e1 * sc);
                dst[32] = f2b(e2 * sc);
                dst[48] = f2b(e3 * sc);
            }
    } else if constexpr (EPI == 8) {
        // transposed split store: per-wave LDS transpose (64 cols x 68-u16 stride)
        unsigned short* tb = (unsigned short*)(lds + (size_t)wv * 8704);
        #pragma unroll
        for (int m = 0; m < 4; ++m)
            #pragma unroll
            for (int n = 0; n < 4; ++n)
                #pragma unroll
                for (int r = 0; r < 4; ++r) {
                    int row_l = m * 16 + g4 + r;
                    int col_l = n * 16 + lr;
                    tb[col_l * 68 + row_l] = f2b(acc[m][n][r]);
                }
        asm volatile("s_waitcnt lgkmcnt(0)" ::: "memory");
        __builtin_amdgcn_sched_barrier(0);
        #pragma unroll
        for (int q2 = 0; q2 < 8; ++q2) {
            int col_l = (lane >> 3) + q2 * 8;
            int row0 = (lane & 7) * 8;
            ushort4 lo = *(const ushort4*)(tb + col_l * 68 + row0);
            ushort4 hi = *(const ushort4*)(tb + col_l * 68 + row0 + 4);
            int colg = bn + wc * 64 + col_l;
            int rowg = bm + wr * 64 + row0;
            unsigned short* dstb = (colg < 512) ? (unsigned short*)Cv : (unsigned short*)Cv2;
            unsigned short* d = dstb + (size_t)(colg & 511) * ROWS + rowg;
            *(ushort4*)(d) = lo;
            *(ushort4*)(d + 4) = hi;
        }
    } else {
        #pragma unroll
        for (int m = 0; m < 4; ++m)
            #pragma unroll
            for (int n = 0; n < 4; ++n) {
                int col = bn + wc * 64 + n * 16 + lr;
                #pragma unroll
                for (int r = 0; r < 4; ++r) {
                    int rr = bm + wr * 64 + m * 16 + g4 + r;
                    float v = acc[m][n][r];
                    if (EPI == 1) {
                        ((unsigned short*)Cv)[(size_t)rr * N + col] = f2b(gelu_tanh(v + bias[col]));
                    } else if (EPI == 2) {
                        ((float*)Cv)[(size_t)rr * N + col] += v + bias[col];
                    } else if (EPI == 3) {
                        ((float*)Cv)[(size_t)rr * N + col] = v + extra[(size_t)(rr / batch_rows) * N + col];
                    } else if (EPI == 6) {
                        unsigned short* dst = (col >> 9) ? (unsigned short*)Cv2 : (unsigned short*)Cv;
                        dst[(size_t)rr * 512 + (col & 511)] = f2b(v);
                    }
                }
            }
    }
}

// ---------------- legacy 128x128 MFMA GEMM (tiny wcomp only) ----------------
#define BM 128
#define BN 128
#define BK 64

template <int EPI>
__global__ __launch_bounds__(256) void gemm_mfma(
    const unsigned short* __restrict__ A, int lda,
    const unsigned short* __restrict__ Bt, int ldb,
    void* __restrict__ Cv, int M, int N, int K, int ldo) {
    __shared__ unsigned short As[2][BM * BK];
    __shared__ unsigned short Bs[2][BN * BK];
    int bm = blockIdx.y * BM, bn = blockIdx.x * BN;
    int tid = threadIdx.x;
    int lane = tid & 63, wv = tid >> 6;
    int wr = (wv >> 1) * 64, wc = (wv & 1) * 64;
    int g16 = (lane >> 4) << 4;
    int lr = lane & 15;
    int sw = (lr & 7) << 4;

    int srow = tid >> 3;
    int skb = (tid & 7) * 16;
    int sxor = skb ^ ((srow & 7) << 4);

    auto stage = [&](int buf, int k0) {
        #pragma unroll
        for (int i = 0; i < 4; ++i) {
            int row = srow + 32 * i;
            GLOAD16((const char*)(A + (size_t)(bm + row) * lda + k0) + sxor,
                    (char*)As[buf] + (size_t)(tid + 256 * i) * 16);
        }
        #pragma unroll
        for (int i = 0; i < 4; ++i) {
            int row = srow + 32 * i;
            GLOAD16((const char*)(Bt + (size_t)(bn + row) * ldb + k0) + sxor,
                    (char*)Bs[buf] + (size_t)(tid + 256 * i) * 16);
        }
    };

    f32x4 acc[4][4] = {};
    int nt = K / BK;
    stage(0, 0);
    __syncthreads();
    for (int t = 0; t < nt; ++t) {
        int cur = t & 1;
        if (t + 1 < nt) stage(cur ^ 1, (t + 1) * BK);
        const char* Ab = (const char*)As[cur];
        const char* Bp = (const char*)Bs[cur];
        #pragma unroll
        for (int s = 0; s < 2; ++s) {
            int koff = s * 64 + g16;
            bf16x8 af[4], bw[4];
            #pragma unroll
            for (int f = 0; f < 4; ++f) {
                int ar = wr + f * 16 + lr;
                af[f] = *(const bf16x8*)(Ab + ar * 128 + (koff ^ sw));
                int br = wc + f * 16 + lr;
                bw[f] = *(const bf16x8*)(Bp + br * 128 + (koff ^ sw));
            }
            #pragma unroll
            for (int f = 0; f < 4; ++f)
                #pragma unroll
                for (int j = 0; j < 4; ++j)
                    acc[f][j] = __builtin_amdgcn_mfma_f32_16x16x32_bf16(
                        af[f], bw[j], acc[f][j], 0, 0, 0);
        }
        __syncthreads();
    }

    int g4 = (lane >> 4) * 4;
    #pragma unroll
    for (int f = 0; f < 4; ++f) {
        #pragma unroll
        for (int j = 0; j < 4; ++j) {
            int col = bn + wc + j * 16 + lr;
            #pragma unroll
            for (int r = 0; r < 4; ++r) {
                int rr = bm + wr + f * 16 + g4 + r;
                float v = acc[f][j][r];
                if (EPI == 4) {
                    ((unsigned short*)Cv)[(size_t)rr * N + col] = f2b(v);
                } else if (EPI == 5) {
                    ((unsigned short*)Cv)[(size_t)col * ldo + rr] = f2b(v);
                }
            }
        }
    }
}

// ---------------- k column-softmax stats, single pass on kbT rows ----------------
__global__ __launch_bounds__(256) void ksm_rows(
    const unsigned short* __restrict__ kbT, float* __restrict__ Mst, float* __restrict__ Sinv) {
    int seg = blockIdx.x * 4 + (threadIdx.x >> 6);   // 0..2047
    int lane = threadIdx.x & 63;
    int b = seg >> 9, f = seg & 511;
    const unsigned short* p = kbT + (size_t)f * ROWS + (size_t)b * NN;
    float m = -1e30f, s = 0.f;
    for (int it = 0; it < 16; ++it) {
        us8 v = *(const us8*)(p + (size_t)(it * 64 + lane) * 8);
        #pragma unroll
        for (int j = 0; j < 8; ++j) {
            float x = b2f(v[j]);
            float n = fmaxf(m, x);
            s = s * __expf(m - n) + __expf(x - n);
            m = n;
        }
    }
    #pragma unroll
    for (int o = 1; o < 64; o <<= 1) {
        float mo = __shfl_xor(m, o, 64), so = __shfl_xor(s, o, 64);
        float n = fmaxf(m, mo);
        s = s * __expf(m - n) + so * __expf(mo - n);
        m = n;
    }
    if (lane == 0) { Mst[seg] = m; Sinv[seg] = 1.f / s; }
}

// ---------------- context partials via MFMA, depth-2 register pipeline, no atomics ----------------
// grid (16, HEADS, NB), 256 thr = 4 waves; wave w covers 128 n (4 chunks of 32).
// part[rb][(b*HEADS+hd)][4096] <- per-block 64x64 partial (plain stores).
__global__ __launch_bounds__(256) void context_mfma(
    const unsigned short* __restrict__ kbT, const unsigned short* __restrict__ vbT,
    const float* __restrict__ Mst, const float* __restrict__ Sinv,
    float* __restrict__ part) {
    __shared__ float cbuf[4096];
    int b = blockIdx.z, hd = blockIdx.y, rb = blockIdx.x;
    int w = threadIdx.x >> 6, lane = threadIdx.x & 63;
    int lr = lane & 15, lch = lane >> 4;
    size_t nb = (size_t)b * NN + (size_t)rb * 512 + (size_t)w * 128 + (size_t)lch * 8;
    float mv[4], sv[4];
    const unsigned short* krow[4];
    const unsigned short* vrow[4];
    #pragma unroll
    for (int i = 0; i < 4; ++i) {
        int feat = hd * 64 + i * 16 + lr;
        mv[i] = Mst[b * DIMC + feat];
        sv[i] = Sinv[b * DIMC + feat];
        krow[i] = kbT + (size_t)feat * ROWS + nb;
        vrow[i] = vbT + (size_t)feat * ROWS + nb;
    }
    f32x4 acc[4][4] = {};
    us8 kc[4], vc[4];
    #pragma unroll
    for (int i = 0; i < 4; ++i) { kc[i] = *(const us8*)(krow[i]); vc[i] = *(const us8*)(vrow[i]); }
    #pragma unroll
    for (int c = 0; c < 4; ++c) {
        us8 kn[4], vn[4];
        if (c < 3) {
            #pragma unroll
            for (int i = 0; i < 4; ++i) {
                kn[i] = *(const us8*)(krow[i] + (c + 1) * 32);
                vn[i] = *(const us8*)(vrow[i] + (c + 1) * 32);
            }
        }
        bf16x8 af[4], bfv[4];
        #pragma unroll
        for (int i = 0; i < 4; ++i) {
            bf16x8 a;
            #pragma unroll
            for (int j = 0; j < 8; ++j)
                a[j] = (short)f2b(__expf(b2f(kc[i][j]) - mv[i]) * sv[i]);
            af[i] = a;
            bfv[i] = __builtin_bit_cast(bf16x8, vc[i]);
        }
        #pragma unroll
        for (int i = 0; i < 4; ++i)
            #pragma unroll
            for (int j = 0; j < 4; ++j)
                acc[i][j] = __builtin_amdgcn_mfma_f32_16x16x32_bf16(
                    af[i], bfv[j], acc[i][j], 0, 0, 0);
        if (c < 3) {
            #pragma unroll
            for (int i = 0; i < 4; ++i) { kc[i] = kn[i]; vc[i] = vn[i]; }
        }
    }
    // cross-wave reduce in LDS
    for (int w2 = 0; w2 < 4; ++w2) {
        if (w == w2) {
            #pragma unroll
            for (int i = 0; i < 4; ++i)
                #pragma unroll
                for (int j = 0; j < 4; ++j)
                    #pragma unroll
                    for (int r = 0; r < 4; ++r) {
                        int row = i * 16 + lch * 4 + r;
                        int col = j * 16 + lr;
                        int idx = row * 64 + col;
                        cbuf[idx] = (w2 == 0) ? acc[i][j][r] : cbuf[idx] + acc[i][j][r];
                    }
        }
        __syncthreads();
    }
    float* dst = part + ((size_t)rb * (NB * HEADS) + (size_t)(b * HEADS + hd)) * 4096;
    #pragma unroll
    for (int q = 0; q < 4; ++q)
        *(float4*)(dst + threadIdx.x * 16 + q * 4) = *(const float4*)(cbuf + threadIdx.x * 16 + q * 4);
}

// ctx[(b,hd)][e] = sum_rb part[rb][(b,hd)][e]
__global__ void ctx_reduce(const float* __restrict__ part, float* __restrict__ ctx) {
    int idx = blockIdx.x * 256 + threadIdx.x;   // 131072 total
    int grp = idx >> 12, e = idx & 4095;
    float s = 0.f;
    #pragma unroll 4
    for (int rb = 0; rb < 16; ++rb)
        s += part[((size_t)rb * (NB * HEADS) + grp) * 4096 + e];
    ctx[(size_t)grp * 4096 + e] = s;
}

// ---------------- caw = ctx @ aow (per batch) ----------------
__global__ __launch_bounds__(256) void caw_kernel(const float* __restrict__ ctx,
                                                  const float* __restrict__ aow,
                                                  float* __restrict__ caw) {
    int nt = blockIdx.x, hd = blockIdx.y, b = blockIdx.z;
    int tid = threadIdx.x, tx = tid & 15, ty = tid >> 4;
    __shared__ float cs[64][68];
    __shared__ float aw[64][68];
    #pragma unroll
    for (int i = 0; i < 4; ++i) {
        int idx = tid + 256 * i;
        int r = idx >> 4, c4 = (idx & 15) * 4;
        *(float4*)&cs[r][c4] = *(const float4*)(ctx + ((size_t)(b * HEADS + hd) * 64 + r) * 64 + c4);
        *(float4*)&aw[r][c4] = *(const float4*)(aow + (size_t)(hd * 64 + r) * DIMC + nt * 64 + c4);
    }
    __syncthreads();
    float acc[4][4] = {};
    for (int e = 0; e < 64; ++e) {
        float av[4];
        #pragma unroll
        for (int i = 0; i < 4; ++i) av[i] = cs[ty * 4 + i][e];
        float4 b4 = *(const float4*)&aw[e][tx * 4];
        float bv[4] = {b4.x, b4.y, b4.z, b4.w};
        #pragma unroll
        for (int i = 0; i < 4; ++i)
            #pragma unroll
            for (int j = 0; j < 4; ++j)
                acc[i][j] = fmaf(av[i], bv[j], acc[i][j]);
    }
    #pragma unroll
    for (int i = 0; i < 4; ++i)
        #pragma unroll
        for (int j = 0; j < 4; ++j)
            caw[(size_t)b * DIMC * DIMC + (size_t)(hd * 64 + ty * 4 + i) * DIMC + nt * 64 + tx * 4 + j]
                = acc[i][j];
}

// ---------------- pos head ----------------
__global__ __launch_bounds__(256) void pos_kernel(
    const float* __restrict__ x, const float* __restrict__ w,
    const float* __restrict__ b2, float* __restrict__ out) {
    int lane = threadIdx.x & 63;
    size_t row = (size_t)blockIdx.x * 4 + (threadIdx.x >> 6);
    const float* xp = x + row * DIMC;
    float acc0 = 0.f, acc1 = 0.f;
    #pragma unroll
    for (int i = 0; i < 2; ++i) {
        float4 xv = *(const float4*)(xp + lane * 8 + i * 4);
        const float* wp = w + (size_t)(lane * 8 + i * 4) * 2;
        float4 w0 = *(const float4*)(wp);
        float4 w1 = *(const float4*)(wp + 4);
        acc0 += xv.x * w0.x + xv.y * w0.z + xv.z * w1.x + xv.w * w1.z;
        acc1 += xv.x * w0.y + xv.y * w0.w + xv.z * w1.y + xv.w * w1.w;
    }
    #pragma unroll
    for (int o = 32; o; o >>= 1) { acc0 += __shfl_down(acc0, o, 64); acc1 += __shfl_down(acc1, o, 64); }
    if (lane == 0) {
        out[row * 2] = acc0 + b2[0];
        out[row * 2 + 1] = acc1 + b2[1];
    }
}

// ---------------- launch ----------------
extern "C" void kernel_launch(void* const* d_in, const int* in_sizes, int n_in,
                              void* d_out, int out_size, void* d_ws, size_t ws_size,
                              hipStream_t stream) {
    (void)in_sizes; (void)n_in; (void)out_size; (void)ws_size;
    const float* nf  = (const float*)d_in[0];
    const float* dt  = (const float*)d_in[1];
    const float* pos = (const float*)d_in[2];
    const float* msk = (const float*)d_in[3];
    const float* yyw = (const float*)d_in[4];
    const float* yyb = (const float*)d_in[5];
    const float* p1w = (const float*)d_in[6];
    const float* p1b = (const float*)d_in[7];
    const float* p2w = (const float*)d_in[8];
    const float* p2b = (const float*)d_in[9];
    const float* lxw = (const float*)d_in[10];
    const float* lxb = (const float*)d_in[11];
    const float* cw  = (const float*)d_in[12];
    const float* cb  = (const float*)d_in[13];
    const float* l1g = (const float*)d_in[14];
    const float* l1b = (const float*)d_in[15];
    const float* qw  = (const float*)d_in[16];
    const float* kw  = (const float*)d_in[17];
    const float* vw  = (const float*)d_in[18];
    const float* aow = (const float*)d_in[19];
    const float* aob = (const float*)d_in[20];
    const float* l2g = (const float*)d_in[21];
    const float* l2b = (const float*)d_in[22];
    const float* f1w = (const float*)d_in[23];
    const float* f1b = (const float*)d_in[24];
    const float* f2w = (const float*)d_in[25];
    const float* f2b_ = (const float*)d_in[26];
    const float* hpw = (const float*)d_in[27];
    const float* hpb = (const float*)d_in[28];

    float* ws = (float*)d_ws;
    unsigned short* catA_u  = (unsigned short*)(ws + OFF_R0);
    unsigned short* hb_u    = (unsigned short*)(ws + OFF_R0);
    float*          part    = ws + OFF_CAW;          // 2M floats (dead before caw written)
    float*          caw     = ws + OFF_CAW;          // 1M floats, written after ctx_reduce
    unsigned short* kbT_u   = (unsigned short*)(ws + OFF_R1);
    unsigned short* qb_u    = (unsigned short*)(ws + OFF_R1);
    unsigned short* mid_u   = (unsigned short*)(ws + OFF_R1);   // [16384][2048] spans R1+R2
    unsigned short* vbT_u   = (unsigned short*)(ws + OFF_R2);
    unsigned short* cawT_u  = (unsigned short*)(ws + OFF_R2);
    unsigned short* catWT_u = (unsigned short*)(ws + OFF_CATWT);
    unsigned short* kvT_u   = (unsigned short*)(ws + OFF_KVT);
    unsigned short* qwT_u   = (unsigned short*)(ws + OFF_QWT);
    unsigned short* f1wT_u  = (unsigned short*)(ws + OFF_F1WT);
    unsigned short* f2wT_u  = (unsigned short*)(ws + OFF_F2WT);
    unsigned short* lxwb_u  = (unsigned short*)(ws + OFF_LXWB);
    unsigned short* cw0T_u  = (unsigned short*)(ws + OFF_CW0T);
    float* yv   = ws + OFF_Y;
    float* bbf  = ws + OFF_BB;
    float* Mst  = ws + OFF_M;
    float* Sinv = ws + OFF_SINV;
    float* ctx  = ws + OFF_CTX;

    float* xout = (float*)d_out;
    float* yout = xout + (size_t)ROWS * DIMC;
    float* pout = yout + NB * DT;

    // allow 72KB dynamic LDS for gemm256 instantiations
    hipFuncSetAttribute(reinterpret_cast<const void*>(&gemm256<1, 1>),
                        hipFuncAttributeMaxDynamicSharedMemorySize, 73728);
    hipFuncSetAttribute(reinterpret_cast<const void*>(&gemm256<2, 1>),
                        hipFuncAttributeMaxDynamicSharedMemorySize, 73728);
    hipFuncSetAttribute(reinterpret_cast<const void*>(&gemm256<3, 1>),
                        hipFuncAttributeMaxDynamicSharedMemorySize, 73728);
    hipFuncSetAttribute(reinterpret_cast<const void*>(&gemm256<7, 1>),
                        hipFuncAttributeMaxDynamicSharedMemorySize, 73728);
    hipFuncSetAttribute(reinterpret_cast<const void*>(&gemm256<8, 1>),
                        hipFuncAttributeMaxDynamicSharedMemorySize, 73728);

    // prologue scalars + weight conversions
    y_kernel<<<4, 128, 0, stream>>>(dt, yyw, yyb, yv, yout);
    bb_kernel<<<8, 256, 0, stream>>>(lxb, cw, cb, yv, bbf);
    conv_bf16<<<128, 256, 0, stream>>>(lxw, lxwb_u, 32768);
    transconv<<<dim3(16, 16), 256, 0, stream>>>(cw, cw0T_u, 512, 512, 512);
    transconv<<<dim3(16, 2), 256, 0, stream>>>(cw + (size_t)DIMC * DIMC, catWT_u + 512, 64, 512, KCATP);
    zcat_kernel<<<128, 256, 0, stream>>>(catWT_u);
    transconv<<<dim3(16, 16), 256, 0, stream>>>(kw, kvT_u, 512, 512, 512);
    transconv<<<dim3(16, 16), 256, 0, stream>>>(vw, kvT_u + (size_t)512 * 512, 512, 512, 512);
    transconv<<<dim3(16, 16), 256, 0, stream>>>(qw, qwT_u, 512, 512, 512);
    transconv<<<dim3(64, 16), 256, 0, stream>>>(f1w, f1wT_u, 512, 2048, 512);
    transconv<<<dim3(16, 64), 256, 0, stream>>>(f2w, f2wT_u, 2048, 512, 2048);
    conv_bf16_strided<<<8192, 256, 0, stream>>>(nf, catA_u, KCATP);
    delta_kernel<<<8192, 256, 0, stream>>>(pos, msk, p1w, p1b, p2w, p2b, catA_u);

    // catWT cols 0..511 = (lxw @ cw0)^T
    gemm_mfma<5><<<dim3(4, 4), 256, 0, stream>>>(
        lxwb_u, 512, cw0T_u, 512, catWT_u, 512, 512, 512, KCATP);

    // cat = catA @ catWT^T + bb[batch] -> xout (f32)
    gemm256<3, 1><<<dim3(4, 128), 512, 73728, stream>>>(
        catA_u, KCATP, catWT_u, KCATP, nullptr, bbf, NN,
        xout, nullptr, ROWS, 512, KCATP, 0, 0);

    // LN1: xout -> hb
    ln_kernel<<<ROWS, 128, 0, stream>>>(xout, hb_u, l1g, l1b);

    // fused k+v projection, TRANSPOSED split store -> kbT (R1), vbT (R2)
    gemm256<8, 1><<<dim3(8, 128), 512, 73728, stream>>>(
        hb_u, 512, kvT_u, 512, nullptr, nullptr, 0,
        kbT_u, vbT_u, ROWS, 1024, 512, 0, 0);

    // k sequence-softmax stats (single pass on kbT rows)
    ksm_rows<<<512, 256, 0, stream>>>(kbT_u, Mst, Sinv);

    // context partials + reduction (consumes kbT, vbT; no atomics)
    context_mfma<<<dim3(16, HEADS, NB), 256, 0, stream>>>(kbT_u, vbT_u, Mst, Sinv, part);
    ctx_reduce<<<512, 256, 0, stream>>>(part, ctx);

    // q projection + fused feature-softmax epilogue -> qb (R1; kbT dead)
    gemm256<7, 1><<<dim3(4, 128), 512, 73728, stream>>>(
        hb_u, 512, qwT_u, 512, nullptr, nullptr, 0,
        qb_u, nullptr, ROWS, 512, 512, 0, 0);

    // compose ctx with attn_out_w per batch; transpose into R2 (vbT dead; part dead)
    caw_kernel<<<dim3(8, 8, 4), 256, 0, stream>>>(ctx, aow, caw);
    for (int b = 0; b < NB; ++b)
        transconv<<<dim3(16, 16), 256, 0, stream>>>(caw + (size_t)b * 262144,
                                                    cawT_u + (size_t)b * 262144, 512, 512, 512);

    // x += qsm @ caw[b]^T + aob
    gemm256<2, 1><<<dim3(4, 128), 512, 73728, stream>>>(
        qb_u, 512, cawT_u, 512, aob, nullptr, 0,
        xout, nullptr, ROWS, 512, 512, 262144, NN);

    // FF block: LN2 then per-2-batch {ff1 N=2048 -> mid; ff2 K=2048}
    ln_kernel<<<ROWS, 128, 0, stream>>>(xout, hb_u, l2g, l2b);
    for (int bp = 0; bp < 2; ++bp) {
        const unsigned short* hbp = hb_u + (size_t)bp * 16384 * DIMC;
        gemm256<1, 1><<<dim3(16, 64), 512, 73728, stream>>>(
            hbp, 512, f1wT_u, 512, f1b, nullptr, 0,
            mid_u, nullptr, 16384, FF, 512, 0, 0);
        gemm256<2, 1><<<dim3(4, 64), 512, 73728, stream>>>(
            mid_u, 2048, f2wT_u, 2048, f2b_, nullptr, 0,
            xout + (size_t)bp * 16384 * DIMC, nullptr, 16384, 512, 2048, 0, 0);
    }

    pos_kernel<<<8192, 256, 0, stream>>>(xout, hpw, hpb, pout);
}